// Round 3
// baseline (607.259 us; speedup 1.0000x reference)
//
#include <hip/hip_runtime.h>
#include <hip/hip_bf16.h>
#include <cstdint>
#include <cstddef>

// Problem constants
#define B_    2
#define L_    2048
#define HID_  2048
#define NH_   16
#define NKV_  4
#define HD_   128
#define LAT_  512
#define SCALE_ 0.08838834764831845f   // 1/sqrt(128)
#define SC2_   0.1275174365f          // SCALE * log2(e)

typedef unsigned short u16;
typedef unsigned int   u32;
typedef __attribute__((ext_vector_type(8))) short   short8;
typedef __attribute__((ext_vector_type(4))) float   floatx4;

typedef __attribute__((address_space(1))) const u32 gas_u32;
typedef __attribute__((address_space(3))) u32       las_u32;

__device__ __forceinline__ void gl_lds16(const u16* g, u16* l) {
    // async global->LDS, 16B per lane; LDS dest = wave-uniform base + lane*16
    __builtin_amdgcn_global_load_lds((gas_u32*)g, (las_u32*)l, 16, 0, 0);
}

__device__ __forceinline__ float bf2f(u16 u) {
    union { u32 i; float f; } v; v.i = ((u32)u) << 16; return v.f;
}
__device__ __forceinline__ u16 f2bf(float f) {
    union { float f; u32 u; } v; v.f = f;
    u32 u = v.u;
    u32 r = (u + 0x7fffu + ((u >> 16) & 1u)) >> 16;   // RNE
    return (u16)r;
}

// ---------------- fp32 -> bf16 elementwise ----------------
__global__ void cvt_kernel(const float* __restrict__ in, u16* __restrict__ out, int n) {
    int i = blockIdx.x * 256 + threadIdx.x;
    if (i < n) out[i] = f2bf(in[i]);
}

// ---------------- fp32 [R][C] -> bf16 [C][R] (transpose) ----------------
__global__ void cvt_transpose_kernel(const float* __restrict__ in, u16* __restrict__ out,
                                     int R, int C) {
    __shared__ u16 tile[32][33];
    int c0 = blockIdx.x * 32, r0 = blockIdx.y * 32;
    int tx = threadIdx.x & 31, ty = threadIdx.x >> 5;   // ty in 0..7
    for (int i = ty; i < 32; i += 8)
        tile[tx][i] = f2bf(in[(size_t)(r0 + i) * C + c0 + tx]);
    __syncthreads();
    for (int i = ty; i < 32; i += 8)
        out[(size_t)(c0 + i) * R + r0 + tx] = tile[i][tx];
}

// ---------------- bf16 [b,l,kvh,d] -> bf16 [b,kvh,d,l] (V transpose) ------
__global__ void transpose_v_kernel(const u16* __restrict__ in, u16* __restrict__ out) {
    __shared__ u16 t[32][33];
    int lt = blockIdx.x, dt = blockIdx.y, bh = blockIdx.z;   // bh = b*NKV + kvh
    int b = bh >> 2, kvh = bh & 3;
    int tx = threadIdx.x & 31, ty = threadIdx.x >> 5;
    for (int i = ty; i < 32; i += 8)
        t[i][tx] = in[(((size_t)b * L_ + lt * 32 + i) * NKV_ + kvh) * HD_ + dt * 32 + tx];
    __syncthreads();
    for (int i = ty; i < 32; i += 8)
        out[((size_t)bh * HD_ + dt * 32 + i) * L_ + lt * 32 + tx] = t[tx][i];
}

// ---------------- bf16 GEMM: C[M,N] = A[M,K] * BT[N,K]^T ----------------
// m97 structure: 128x128 tile, BK=32, global_load_lds width-16 staging.
template<int OUT_BF16>
__global__ __launch_bounds__(256)
void gemm_bt(const u16* __restrict__ A, const u16* __restrict__ BT,
             void* __restrict__ C, int M, int N, int K) {
    __shared__ __align__(16) u16 As[128][32];
    __shared__ __align__(16) u16 Bs[128][32];
    const int tid  = threadIdx.x;
    const int m0   = blockIdx.y * 128, n0 = blockIdx.x * 128;
    const int wave = tid >> 6, lane = tid & 63;
    const int wm   = (wave >> 1) * 64, wn = (wave & 1) * 64;
    const int quad = lane >> 4, l16 = lane & 15;

    const int srow = wave * 32 + (lane >> 2);
    const int scol = (lane & 3) * 8;
    const u16* aptr0 = A  + (size_t)(m0 + srow) * K + scol;
    const u16* bptr0 = BT + (size_t)(n0 + srow) * K + scol;
    const u16* aptr1 = aptr0 + (size_t)16 * K;
    const u16* bptr1 = bptr0 + (size_t)16 * K;
    u16* lA0 = &As[wave * 32][0];
    u16* lA1 = &As[wave * 32 + 16][0];
    u16* lB0 = &Bs[wave * 32][0];
    u16* lB1 = &Bs[wave * 32 + 16][0];

    floatx4 acc[4][4] = {};

    for (int k0 = 0; k0 < K; k0 += 32) {
        gl_lds16(aptr0 + k0, lA0);
        gl_lds16(aptr1 + k0, lA1);
        gl_lds16(bptr0 + k0, lB0);
        gl_lds16(bptr1 + k0, lB1);
        __syncthreads();

        short8 af[4], bfr[4];
        #pragma unroll
        for (int i = 0; i < 4; i++) af[i]  = *(const short8*)&As[wm + i * 16 + l16][quad * 8];
        #pragma unroll
        for (int i = 0; i < 4; i++) bfr[i] = *(const short8*)&Bs[wn + i * 16 + l16][quad * 8];
        #pragma unroll
        for (int mi = 0; mi < 4; mi++)
            #pragma unroll
            for (int ni = 0; ni < 4; ni++)
                acc[mi][ni] = __builtin_amdgcn_mfma_f32_16x16x32_bf16(
                    af[mi], bfr[ni], acc[mi][ni], 0, 0, 0);
        __syncthreads();
    }

    #pragma unroll
    for (int mi = 0; mi < 4; mi++) {
        #pragma unroll
        for (int ni = 0; ni < 4; ni++) {
            #pragma unroll
            for (int r = 0; r < 4; r++) {
                int row = m0 + wm + mi * 16 + quad * 4 + r;
                int col = n0 + wn + ni * 16 + l16;
                float v = acc[mi][ni][r];
                if (OUT_BF16) ((u16*)C)[(size_t)row * N + col] = f2bf(v);
                else          ((float*)C)[(size_t)row * N + col] = v;
            }
        }
    }
}

// ---- same GEMM, bf16 out, but N is a fused [B0|B1] stack: cols < Nsplit
// go to C0 (row stride N0), the rest to C1 (row stride N1). Nsplit % 128 == 0
// so the branch is block-uniform. Lets skinny-N projections ride one launch.
__global__ __launch_bounds__(256)
void gemm_bt_split(const u16* __restrict__ A, const u16* __restrict__ BT,
                   u16* __restrict__ C0, u16* __restrict__ C1,
                   int M, int N, int K, int Nsplit, int N0, int N1) {
    __shared__ __align__(16) u16 As[128][32];
    __shared__ __align__(16) u16 Bs[128][32];
    const int tid  = threadIdx.x;
    const int m0   = blockIdx.y * 128, n0 = blockIdx.x * 128;
    const int wave = tid >> 6, lane = tid & 63;
    const int wm   = (wave >> 1) * 64, wn = (wave & 1) * 64;
    const int quad = lane >> 4, l16 = lane & 15;

    const int srow = wave * 32 + (lane >> 2);
    const int scol = (lane & 3) * 8;
    const u16* aptr0 = A  + (size_t)(m0 + srow) * K + scol;
    const u16* bptr0 = BT + (size_t)(n0 + srow) * K + scol;
    const u16* aptr1 = aptr0 + (size_t)16 * K;
    const u16* bptr1 = bptr0 + (size_t)16 * K;
    u16* lA0 = &As[wave * 32][0];
    u16* lA1 = &As[wave * 32 + 16][0];
    u16* lB0 = &Bs[wave * 32][0];
    u16* lB1 = &Bs[wave * 32 + 16][0];

    floatx4 acc[4][4] = {};

    for (int k0 = 0; k0 < K; k0 += 32) {
        gl_lds16(aptr0 + k0, lA0);
        gl_lds16(aptr1 + k0, lA1);
        gl_lds16(bptr0 + k0, lB0);
        gl_lds16(bptr1 + k0, lB1);
        __syncthreads();

        short8 af[4], bfr[4];
        #pragma unroll
        for (int i = 0; i < 4; i++) af[i]  = *(const short8*)&As[wm + i * 16 + l16][quad * 8];
        #pragma unroll
        for (int i = 0; i < 4; i++) bfr[i] = *(const short8*)&Bs[wn + i * 16 + l16][quad * 8];
        #pragma unroll
        for (int mi = 0; mi < 4; mi++)
            #pragma unroll
            for (int ni = 0; ni < 4; ni++)
                acc[mi][ni] = __builtin_amdgcn_mfma_f32_16x16x32_bf16(
                    af[mi], bfr[ni], acc[mi][ni], 0, 0, 0);
        __syncthreads();
    }

    const int side = (n0 >= Nsplit);
    u16* Cw = side ? C1 : C0;
    const int nw = side ? N1 : N0;
    const int cbase = side ? Nsplit : 0;

    #pragma unroll
    for (int mi = 0; mi < 4; mi++) {
        #pragma unroll
        for (int ni = 0; ni < 4; ni++) {
            #pragma unroll
            for (int r = 0; r < 4; r++) {
                int row = m0 + wm + mi * 16 + quad * 4 + r;
                int col = n0 + wn + ni * 16 + l16 - cbase;
                Cw[(size_t)row * nw + col] = f2bf(acc[mi][ni][r]);
            }
        }
    }
}

// ---------------- RoPE + head-major permute ----------------
__global__ void rope_perm(const u16* __restrict__ in, u16* __restrict__ out,
                          int nh, int nhbits) {
    int idx = blockIdx.x * 256 + threadIdx.x;   // one thread per (b,h,l,d<64)
    int d = idx & 63;
    int l = (idx >> 6) & (L_ - 1);
    int h = (idx >> 17) & (nh - 1);
    int b = idx >> (17 + nhbits);
    const u16* src = &in[(((size_t)b * L_ + l) * nh + h) * HD_];
    u16* dst = &out[(((size_t)b * nh + h) * L_ + l) * HD_];
    float t1 = bf2f(src[d]), t2 = bf2f(src[d + 64]);
    float inv = expf(-(float)d * 0.14391156831212787f);  // ln(10000)/64
    float fr = (float)l * inv;
    float c = cosf(fr), sn = sinf(fr);
    dst[d]      = f2bf(t1 * c - t2 * sn);
    dst[d + 64] = f2bf(t2 * c + t1 * sn);
}

// ---------------- MFMA flash attention (GQA head-merged waves) -----------
// Block = 4 waves = 4 HEADS of one kv-group, all on the SAME 32 q-rows.
// LDS diet (33 KB -> 4 blocks/CU resident):
//   Ks linear [64][128] + XOR chunk swizzle (chunk ^= row&7) -> conflict-free
//   Vs linear [128][64] + same swizzle
//   Ps OVERLAYS Ks (Ks dead after QK^T; extra barrier between QK and the
//   softmax P-writes makes the overlay safe).
// Work split: grid 1280 = 5 blocks per c=(bkvh,j); every block <= 8.3 k-tile
// iterations (heavy tile split 3 or 4 ways, light tile 2 or 1), all blocks
// write fp32 partial (O,l); combine kernel sums + normalizes.
//   c&7 -> (b,kvh): XCD-affine K/V in L2.  4 resident + 1 backfill per CU.
// Max-free softmax: p = exp2(s*SCALE*log2e - 8); shift cancels in O/l, and
// partial (O,l) combine by pure addition (no max bookkeeping).
__global__ __launch_bounds__(256, 4)
void attn_mfma(const u16* __restrict__ Q, const u16* __restrict__ K,
               const u16* __restrict__ Vt, const int* __restrict__ amask,
               float* __restrict__ Opart, float* __restrict__ lpart) {
    __shared__ __align__(16) u16 Ks[64][128];    // 16 KB, also Ps after QK^T
    __shared__ __align__(16) u16 Vs[128][64];    // 16 KB
    __shared__ int smask[64];

    const int tid  = threadIdx.x;
    const int wave = tid >> 6, lane = tid & 63;
    const int quad = lane >> 4, l16 = lane & 15;

    const int bid = blockIdx.x;
    const int s   = bid >> 8;                // 0..4 chunk slot
    const int c   = bid & 255;
    const int bkvh = c & 7;                  // XCD-affine: bid%8 -> XCD
    const int j   = c >> 3;                  // 0..31
    const int b   = bkvh >> 2, kvh = bkvh & 3;

    const int H  = ((32 + j) >> 1) + 1;      // heavy tile key-tiles (17..32)
    const int Lg = ((31 - j) >> 1) + 1;      // light tile key-tiles (1..16)
    const int nh = (j < 16) ? 3 : 4;         // heavy chunk count (all <= 8)
    int t, kt0, kt1;
    if (s < nh) { t = 32 + j; kt0 = (H * s) / nh; kt1 = (H * (s + 1)) / nh; }
    else {
        const int ls = s - nh, nl = 5 - nh;  // light chunk count (2 or 1)
        t = 31 - j; kt0 = (Lg * ls) / nl; kt1 = (Lg * (ls + 1)) / nl;
    }

    const int h   = kvh * 4 + wave;          // wave = head
    const int q0  = t * 32;

    const u16* Qbase = Q  + ((size_t)b * NH_  + h)   * L_ * HD_;
    const u16* Kbase = K  + ((size_t)b * NKV_ + kvh) * L_ * HD_;
    const u16* Vbase = Vt + ((size_t)b * NKV_ + kvh) * (size_t)HD_ * L_;
    const int* mbase = amask + b * L_;

    // Q fragments in registers for the whole kernel
    short8 qa[2][4];
    #pragma unroll
    for (int mi = 0; mi < 2; ++mi)
        #pragma unroll
        for (int ks = 0; ks < 4; ++ks)
            qa[mi][ks] = *(const short8*)&Qbase[(size_t)(q0 + mi * 16 + l16) * HD_ + ks * 32 + quad * 8];

    floatx4 Oacc[2][8] = {};
    float lsum[2][4] = {};

    // staging coords (256 threads cooperate across the block)
    const int krow = tid >> 2, kq0 = (tid & 3) * 4;   // K: 4 16B-chunks/thread
    const int vrow = tid >> 1, vc0 = (tid & 1) * 4;   // V: 4 16B-chunks/thread
    const int kr7  = krow & 7, vr7 = vrow & 7;

    // Ps overlay on Ks: per-wave 4 KB slice
    u16* Psb = &Ks[0][0] + wave * 2048;

    // Ps swizzle helper for reads
    const int fr_rd = ((l16 >> 2) & 3) ^ ((l16 & 3) << 1);

    // ---- prologue: prefetch tile kt0 into registers ----
    uint4 kr0, kr1, kr2, kr3, vr0, vr1, vr2, vr3;
    int mreg;
    {
        const int kb = kt0 * 64;
        const u16* ksrc = Kbase + (size_t)(kb + krow) * HD_ + kq0 * 8;
        kr0 = *(const uint4*)(ksrc);
        kr1 = *(const uint4*)(ksrc + 8);
        kr2 = *(const uint4*)(ksrc + 16);
        kr3 = *(const uint4*)(ksrc + 24);
        const u16* vsrc = Vbase + (size_t)vrow * L_ + kb + vc0 * 8;
        vr0 = *(const uint4*)(vsrc);
        vr1 = *(const uint4*)(vsrc + 8);
        vr2 = *(const uint4*)(vsrc + 16);
        vr3 = *(const uint4*)(vsrc + 24);
        mreg = (tid < 64) ? mbase[kb + tid] : 0;
    }

    for (int kt = kt0; kt < kt1; ++kt) {
        const int kbase = kt * 64;

        // ---- commit prefetched regs to LDS (XOR chunk swizzle) ----
        *(uint4*)&Ks[krow][((kq0 + 0) ^ kr7) * 8] = kr0;
        *(uint4*)&Ks[krow][((kq0 + 1) ^ kr7) * 8] = kr1;
        *(uint4*)&Ks[krow][((kq0 + 2) ^ kr7) * 8] = kr2;
        *(uint4*)&Ks[krow][((kq0 + 3) ^ kr7) * 8] = kr3;
        *(uint4*)&Vs[vrow][((vc0 + 0) ^ vr7) * 8] = vr0;
        *(uint4*)&Vs[vrow][((vc0 + 1) ^ vr7) * 8] = vr1;
        *(uint4*)&Vs[vrow][((vc0 + 2) ^ vr7) * 8] = vr2;
        *(uint4*)&Vs[vrow][((vc0 + 3) ^ vr7) * 8] = vr3;
        if (tid < 64) smask[tid] = mreg;
        __syncthreads();

        // ---- issue next-tile loads; results not needed until next iter ----
        if (kt + 1 < kt1) {
            const int kb = (kt + 1) * 64;
            const u16* ksrc = Kbase + (size_t)(kb + krow) * HD_ + kq0 * 8;
            kr0 = *(const uint4*)(ksrc);
            kr1 = *(const uint4*)(ksrc + 8);
            kr2 = *(const uint4*)(ksrc + 16);
            kr3 = *(const uint4*)(ksrc + 24);
            const u16* vsrc = Vbase + (size_t)vrow * L_ + kb + vc0 * 8;
            vr0 = *(const uint4*)(vsrc);
            vr1 = *(const uint4*)(vsrc + 8);
            vr2 = *(const uint4*)(vsrc + 16);
            vr3 = *(const uint4*)(vsrc + 24);
            mreg = (tid < 64) ? mbase[kb + tid] : 0;
        }

        // ---- S = Q K^T : 2 m-tiles x 4 n-tiles x 4 k-steps (K from LDS) ----
        floatx4 sfr[2][4] = {};
        __builtin_amdgcn_s_setprio(1);
        #pragma unroll
        for (int ni = 0; ni < 4; ++ni) {
            #pragma unroll
            for (int ks = 0; ks < 4; ++ks) {
                short8 kf = *(const short8*)&Ks[ni * 16 + l16][((ks * 4 + quad) ^ (l16 & 7)) * 8];
                sfr[0][ni] = __builtin_amdgcn_mfma_f32_16x16x32_bf16(qa[0][ks], kf, sfr[0][ni], 0, 0, 0);
                sfr[1][ni] = __builtin_amdgcn_mfma_f32_16x16x32_bf16(qa[1][ks], kf, sfr[1][ni], 0, 0, 0);
            }
        }
        __builtin_amdgcn_s_setprio(0);

        int am[4];
        #pragma unroll
        for (int ni = 0; ni < 4; ++ni) am[ni] = smask[ni * 16 + l16];

        __syncthreads();   // all waves done reading Ks -> Ps overlay is safe

        // ---- p = exp2(s*SC2 - 8), masked; per-lane l; swizzled pack ----
        #pragma unroll
        for (int mi = 0; mi < 2; ++mi) {
            #pragma unroll
            for (int ni = 0; ni < 4; ++ni) {
                const int kpos = kbase + ni * 16 + l16;
                const bool okm = am[ni] > 0;
                const int blk_log = ni * 2 + (l16 >> 3);
                const int off = l16 & 7;
                #pragma unroll
                for (int r = 0; r < 4; ++r) {
                    const int qrow = q0 + mi * 16 + quad * 4 + r;
                    const bool ok = (kpos <= qrow) & okm;
                    float p = ok ? exp2f(fmaf(sfr[mi][ni][r], SC2_, -8.0f)) : 0.0f;
                    lsum[mi][r] += p;
                    const int pblk = blk_log ^ quad ^ (r << 1);
                    Psb[(mi * 16 + quad * 4 + r) * 64 + pblk * 8 + off] = f2bf(p);
                }
            }
        }

        // ---- P: D-layout -> A-layout (per-wave slice, swizzled read) ----
        short8 pf[2][2];
        #pragma unroll
        for (int mi = 0; mi < 2; ++mi)
            #pragma unroll
            for (int kc = 0; kc < 2; ++kc)
                pf[mi][kc] = *(const short8*)&Psb[(mi * 16 + l16) * 64 + ((kc * 4 + quad) ^ fr_rd) * 8];

        // ---- O += P V (V from LDS, swizzled) ----
        __builtin_amdgcn_s_setprio(1);
        #pragma unroll
        for (int kc = 0; kc < 2; ++kc) {
            #pragma unroll
            for (int dn = 0; dn < 8; ++dn) {
                short8 vf = *(const short8*)&Vs[dn * 16 + l16][((kc * 4 + quad) ^ (l16 & 7)) * 8];
                Oacc[0][dn] = __builtin_amdgcn_mfma_f32_16x16x32_bf16(pf[0][kc], vf, Oacc[0][dn], 0, 0, 0);
                Oacc[1][dn] = __builtin_amdgcn_mfma_f32_16x16x32_bf16(pf[1][kc], vf, Oacc[1][dn], 0, 0, 0);
            }
        }
        __builtin_amdgcn_s_setprio(0);
        __syncthreads();   // Ks(Ps)/Vs consumed; safe to overwrite next iter
    }

    // ---- epilogue: every block writes fp32 partial (O, l) ----
    float* od = Opart + ((size_t)bid * 4 + wave) * 32 * 128;
    float* lp = lpart + ((size_t)bid * 4 + wave) * 32;
    #pragma unroll
    for (int mi = 0; mi < 2; ++mi) {
        #pragma unroll
        for (int r = 0; r < 4; ++r) {
            float v = lsum[mi][r];
            v += __shfl_xor(v, 1);
            v += __shfl_xor(v, 2);
            v += __shfl_xor(v, 4);
            v += __shfl_xor(v, 8);
            const int qi = mi * 16 + quad * 4 + r;
            if (l16 == 0) lp[qi] = v;
            #pragma unroll
            for (int dn = 0; dn < 8; ++dn)
                od[(size_t)qi * 128 + dn * 16 + l16] = Oacc[mi][dn][r];
        }
    }
}

// ---------------- combine split-tile partials -> final bf16 Y ------------
// Grid 2048 = 8 z * 256 c, XCD-affine (cb%8 == c%8). z = (tile, head):
// tile 0 = heavy t=32+j (nh partials), tile 1 = light t=31-j (5-nh partials).
__global__ __launch_bounds__(256)
void attn_combine(const float* __restrict__ Opart, const float* __restrict__ lpart,
                  u16* __restrict__ Y) {
    const int cb = blockIdx.x;
    const int c  = cb & 255, z = cb >> 8;
    const int tile = z >> 2, hw = z & 3;
    const int bkvh = c & 7, j = c >> 3;
    const int b = bkvh >> 2, kvh = bkvh & 3;
    const int h = kvh * 4 + hw;
    const int nh = (j < 16) ? 3 : 4;
    const int s0 = tile ? nh : 0;
    const int ns = tile ? (5 - nh) : nh;
    const int t  = tile ? (31 - j) : (32 + j);
    const int tid = threadIdx.x;
    const int q = tid >> 3, dg = tid & 7;    // q 0..31, d-block 0..7 (16 floats)

    float4 a0 = {0,0,0,0}, a1 = {0,0,0,0}, a2 = {0,0,0,0}, a3 = {0,0,0,0};
    float lacc = 0.0f;
    for (int i = 0; i < ns; ++i) {
        const size_t rowb = ((size_t)((s0 + i) * 256 + c) * 4 + hw) * 32 + q;
        lacc += lpart[rowb];
        const float4* op = (const float4*)(Opart + rowb * 128 + dg * 16);
        float4 v0 = op[0], v1 = op[1], v2 = op[2], v3 = op[3];
        a0.x += v0.x; a0.y += v0.y; a0.z += v0.z; a0.w += v0.w;
        a1.x += v1.x; a1.y += v1.y; a1.z += v1.z; a1.w += v1.w;
        a2.x += v2.x; a2.y += v2.y; a2.z += v2.z; a2.w += v2.w;
        a3.x += v3.x; a3.y += v3.y; a3.z += v3.z; a3.w += v3.w;
    }
    const float linv = 1.0f / lacc;
    const int qrow = t * 32 + q;
    u16* dst = &Y[(((size_t)b * L_ + qrow) * NH_ + h) * HD_ + dg * 16];

    u16 tmp[16];
    tmp[0]  = f2bf(a0.x * linv); tmp[1]  = f2bf(a0.y * linv);
    tmp[2]  = f2bf(a0.z * linv); tmp[3]  = f2bf(a0.w * linv);
    tmp[4]  = f2bf(a1.x * linv); tmp[5]  = f2bf(a1.y * linv);
    tmp[6]  = f2bf(a1.z * linv); tmp[7]  = f2bf(a1.w * linv);
    tmp[8]  = f2bf(a2.x * linv); tmp[9]  = f2bf(a2.y * linv);
    tmp[10] = f2bf(a2.z * linv); tmp[11] = f2bf(a2.w * linv);
    tmp[12] = f2bf(a3.x * linv); tmp[13] = f2bf(a3.y * linv);
    tmp[14] = f2bf(a3.z * linv); tmp[15] = f2bf(a3.w * linv);
    *(uint4*)(dst)     = *(const uint4*)(&tmp[0]);
    *(uint4*)(dst + 8) = *(const uint4*)(&tmp[8]);
}

// ---------------- launch ----------------
extern "C" void kernel_launch(void* const* d_in, const int* in_sizes, int n_in,
                              void* d_out, int out_size, void* d_ws, size_t ws_size,
                              hipStream_t stream) {
    const float* x  = (const float*)d_in[0];
    const float* Wq = (const float*)d_in[1];
    const float* Wc = (const float*)d_in[2];
    const float* Wk = (const float*)d_in[3];
    const float* Wv = (const float*)d_in[4];
    const float* Wo = (const float*)d_in[5];
    const int* amask = (const int*)d_in[6];
    float* out = (float*)d_out;

    char* p = (char*)d_ws;
    auto alloc = [&](size_t elems) {
        u16* r = (u16*)p;
        p += ((elems * 2 + 255) / 256) * 256;
        return r;
    };
    // --- alive through attention ---
    u16* WoT  = alloc((size_t)2048 * 2048);
    u16* qbuf = alloc((size_t)4096 * 2048);   // pre-rope q; reused as Y
    u16* Qr   = alloc((size_t)4096 * 2048);
    u16* Kr   = alloc((size_t)4096 * 512);
    u16* Vt   = alloc((size_t)4096 * 512);    // [B, NKV, HD, L]
    // --- dead once attention starts (Opart overlays this region) ---
    char* pdead = p;
    u16* Xb   = alloc((size_t)4096 * 2048);
    u16* WqT  = alloc((size_t)2048 * 2048);   // NOTE: WqT|WcT adjacent (fused)
    u16* WcT  = alloc((size_t)512 * 2048);
    u16* WkT  = alloc((size_t)512 * 512);     // NOTE: WkT|WvT adjacent (fused)
    u16* WvT  = alloc((size_t)512 * 512);
    u16* cbuf = alloc((size_t)4096 * 512);
    u16* kbuf = alloc((size_t)4096 * 512);
    u16* vbuf = alloc((size_t)4096 * 512);
    // partials: 1280 blocks x 4 heads x 32 q x 128 d fp32 (~84 MB, overlays)
    float* Opart = (float*)pdead;
    float* lpart = (float*)(pdead + (size_t)1280 * 4 * 32 * 128 * 4);

    // converts
    cvt_kernel<<<8388608 / 256, 256, 0, stream>>>(x, Xb, 8388608);
    cvt_transpose_kernel<<<dim3(2048 / 32, 2048 / 32), 256, 0, stream>>>(Wq, WqT, 2048, 2048);
    cvt_transpose_kernel<<<dim3(512 / 32, 2048 / 32), 256, 0, stream>>>(Wc, WcT, 2048, 512);
    cvt_transpose_kernel<<<dim3(512 / 32, 512 / 32), 256, 0, stream>>>(Wk, WkT, 512, 512);
    cvt_transpose_kernel<<<dim3(512 / 32, 512 / 32), 256, 0, stream>>>(Wv, WvT, 512, 512);
    cvt_transpose_kernel<<<dim3(2048 / 32, 2048 / 32), 256, 0, stream>>>(Wo, WoT, 2048, 2048);

    // projections: fused [Wq|Wc] (N=2560) and [Wk|Wv] (N=1024)
    gemm_bt_split<<<dim3(20, 32), 256, 0, stream>>>(Xb, WqT, qbuf, cbuf,
                                                    4096, 2560, 2048, 2048, 2048, 512);
    gemm_bt_split<<<dim3(8, 32), 256, 0, stream>>>(cbuf, WkT, kbuf, vbuf,
                                                   4096, 1024, 512, 512, 512, 512);

    // rope + permute to head-major; V -> [b,kvh,d,l]
    rope_perm<<<(2 * 16 * 2048 * 64) / 256, 256, 0, stream>>>(qbuf, Qr, 16, 4);
    rope_perm<<<(2 * 4 * 2048 * 64) / 256, 256, 0, stream>>>(kbuf, Kr, 4, 2);
    transpose_v_kernel<<<dim3(64, 4, 8), 256, 0, stream>>>(vbuf, Vt);

    // attention partials + combine (Y into qbuf, dead after rope)
    attn_mfma<<<dim3(1280), 256, 0, stream>>>(Qr, Kr, Vt, amask, Opart, lpart);
    attn_combine<<<dim3(2048), 256, 0, stream>>>(Opart, lpart, qbuf);

    // output projection (fp32 out)
    gemm_bt<0><<<dim3(16, 32), 256, 0, stream>>>(qbuf, WoT, out, 4096, 2048, 2048);
}

// Round 4
// 528.166 us; speedup vs baseline: 1.1498x; 1.1498x over previous
//
#include <hip/hip_runtime.h>
#include <hip/hip_bf16.h>
#include <cstdint>
#include <cstddef>

// Problem constants
#define B_    2
#define L_    2048
#define HID_  2048
#define NH_   16
#define NKV_  4
#define HD_   128
#define LAT_  512
#define SCALE_ 0.08838834764831845f   // 1/sqrt(128)
#define SC2_   0.1275174365f          // SCALE * log2(e)

typedef unsigned short u16;
typedef unsigned int   u32;
typedef __attribute__((ext_vector_type(8))) short   short8;
typedef __attribute__((ext_vector_type(4))) float   floatx4;

typedef __attribute__((address_space(1))) const u32 gas_u32;
typedef __attribute__((address_space(3))) u32       las_u32;

__device__ __forceinline__ void gl_lds16(const u16* g, u16* l) {
    // async global->LDS, 16B per lane; LDS dest = wave-uniform base + lane*16
    __builtin_amdgcn_global_load_lds((gas_u32*)g, (las_u32*)l, 16, 0, 0);
}

__device__ __forceinline__ float bf2f(u16 u) {
    union { u32 i; float f; } v; v.i = ((u32)u) << 16; return v.f;
}
__device__ __forceinline__ u16 f2bf(float f) {
    union { float f; u32 u; } v; v.f = f;
    u32 u = v.u;
    u32 r = (u + 0x7fffu + ((u >> 16) & 1u)) >> 16;   // RNE
    return (u16)r;
}

// ---------------- fp32 -> bf16 elementwise ----------------
__global__ void cvt_kernel(const float* __restrict__ in, u16* __restrict__ out, int n) {
    int i = blockIdx.x * 256 + threadIdx.x;
    if (i < n) out[i] = f2bf(in[i]);
}

// ---------------- fp32 [R][C] -> bf16 [C][R] (transpose) ----------------
__global__ void cvt_transpose_kernel(const float* __restrict__ in, u16* __restrict__ out,
                                     int R, int C) {
    __shared__ u16 tile[32][33];
    int c0 = blockIdx.x * 32, r0 = blockIdx.y * 32;
    int tx = threadIdx.x & 31, ty = threadIdx.x >> 5;   // ty in 0..7
    for (int i = ty; i < 32; i += 8)
        tile[tx][i] = f2bf(in[(size_t)(r0 + i) * C + c0 + tx]);
    __syncthreads();
    for (int i = ty; i < 32; i += 8)
        out[(size_t)(c0 + i) * R + r0 + tx] = tile[i][tx];
}

// ---------------- bf16 [b,l,kvh,d] -> bf16 [b,kvh,d,l] (V transpose) ------
__global__ void transpose_v_kernel(const u16* __restrict__ in, u16* __restrict__ out) {
    __shared__ u16 t[32][33];
    int lt = blockIdx.x, dt = blockIdx.y, bh = blockIdx.z;   // bh = b*NKV + kvh
    int b = bh >> 2, kvh = bh & 3;
    int tx = threadIdx.x & 31, ty = threadIdx.x >> 5;
    for (int i = ty; i < 32; i += 8)
        t[i][tx] = in[(((size_t)b * L_ + lt * 32 + i) * NKV_ + kvh) * HD_ + dt * 32 + tx];
    __syncthreads();
    for (int i = ty; i < 32; i += 8)
        out[((size_t)bh * HD_ + dt * 32 + i) * L_ + lt * 32 + tx] = t[tx][i];
}

// ---------------- bf16 GEMM: C[M,N] = A[M,K] * BT[N,K]^T ----------------
// m97 structure: 128x128 tile, BK=32, global_load_lds width-16 staging.
template<int OUT_BF16>
__global__ __launch_bounds__(256)
void gemm_bt(const u16* __restrict__ A, const u16* __restrict__ BT,
             void* __restrict__ C, int M, int N, int K) {
    __shared__ __align__(16) u16 As[128][32];
    __shared__ __align__(16) u16 Bs[128][32];
    const int tid  = threadIdx.x;
    const int m0   = blockIdx.y * 128, n0 = blockIdx.x * 128;
    const int wave = tid >> 6, lane = tid & 63;
    const int wm   = (wave >> 1) * 64, wn = (wave & 1) * 64;
    const int quad = lane >> 4, l16 = lane & 15;

    const int srow = wave * 32 + (lane >> 2);
    const int scol = (lane & 3) * 8;
    const u16* aptr0 = A  + (size_t)(m0 + srow) * K + scol;
    const u16* bptr0 = BT + (size_t)(n0 + srow) * K + scol;
    const u16* aptr1 = aptr0 + (size_t)16 * K;
    const u16* bptr1 = bptr0 + (size_t)16 * K;
    u16* lA0 = &As[wave * 32][0];
    u16* lA1 = &As[wave * 32 + 16][0];
    u16* lB0 = &Bs[wave * 32][0];
    u16* lB1 = &Bs[wave * 32 + 16][0];

    floatx4 acc[4][4] = {};

    for (int k0 = 0; k0 < K; k0 += 32) {
        gl_lds16(aptr0 + k0, lA0);
        gl_lds16(aptr1 + k0, lA1);
        gl_lds16(bptr0 + k0, lB0);
        gl_lds16(bptr1 + k0, lB1);
        __syncthreads();

        short8 af[4], bfr[4];
        #pragma unroll
        for (int i = 0; i < 4; i++) af[i]  = *(const short8*)&As[wm + i * 16 + l16][quad * 8];
        #pragma unroll
        for (int i = 0; i < 4; i++) bfr[i] = *(const short8*)&Bs[wn + i * 16 + l16][quad * 8];
        #pragma unroll
        for (int mi = 0; mi < 4; mi++)
            #pragma unroll
            for (int ni = 0; ni < 4; ni++)
                acc[mi][ni] = __builtin_amdgcn_mfma_f32_16x16x32_bf16(
                    af[mi], bfr[ni], acc[mi][ni], 0, 0, 0);
        __syncthreads();
    }

    #pragma unroll
    for (int mi = 0; mi < 4; mi++) {
        #pragma unroll
        for (int ni = 0; ni < 4; ni++) {
            #pragma unroll
            for (int r = 0; r < 4; r++) {
                int row = m0 + wm + mi * 16 + quad * 4 + r;
                int col = n0 + wn + ni * 16 + l16;
                float v = acc[mi][ni][r];
                if (OUT_BF16) ((u16*)C)[(size_t)row * N + col] = f2bf(v);
                else          ((float*)C)[(size_t)row * N + col] = v;
            }
        }
    }
}

// ---- same GEMM, bf16 out, but N is a fused [B0|B1] stack: cols < Nsplit
// go to C0 (row stride N0), the rest to C1 (row stride N1). Nsplit % 128 == 0
// so the branch is block-uniform. Lets skinny-N projections ride one launch.
__global__ __launch_bounds__(256)
void gemm_bt_split(const u16* __restrict__ A, const u16* __restrict__ BT,
                   u16* __restrict__ C0, u16* __restrict__ C1,
                   int M, int N, int K, int Nsplit, int N0, int N1) {
    __shared__ __align__(16) u16 As[128][32];
    __shared__ __align__(16) u16 Bs[128][32];
    const int tid  = threadIdx.x;
    const int m0   = blockIdx.y * 128, n0 = blockIdx.x * 128;
    const int wave = tid >> 6, lane = tid & 63;
    const int wm   = (wave >> 1) * 64, wn = (wave & 1) * 64;
    const int quad = lane >> 4, l16 = lane & 15;

    const int srow = wave * 32 + (lane >> 2);
    const int scol = (lane & 3) * 8;
    const u16* aptr0 = A  + (size_t)(m0 + srow) * K + scol;
    const u16* bptr0 = BT + (size_t)(n0 + srow) * K + scol;
    const u16* aptr1 = aptr0 + (size_t)16 * K;
    const u16* bptr1 = bptr0 + (size_t)16 * K;
    u16* lA0 = &As[wave * 32][0];
    u16* lA1 = &As[wave * 32 + 16][0];
    u16* lB0 = &Bs[wave * 32][0];
    u16* lB1 = &Bs[wave * 32 + 16][0];

    floatx4 acc[4][4] = {};

    for (int k0 = 0; k0 < K; k0 += 32) {
        gl_lds16(aptr0 + k0, lA0);
        gl_lds16(aptr1 + k0, lA1);
        gl_lds16(bptr0 + k0, lB0);
        gl_lds16(bptr1 + k0, lB1);
        __syncthreads();

        short8 af[4], bfr[4];
        #pragma unroll
        for (int i = 0; i < 4; i++) af[i]  = *(const short8*)&As[wm + i * 16 + l16][quad * 8];
        #pragma unroll
        for (int i = 0; i < 4; i++) bfr[i] = *(const short8*)&Bs[wn + i * 16 + l16][quad * 8];
        #pragma unroll
        for (int mi = 0; mi < 4; mi++)
            #pragma unroll
            for (int ni = 0; ni < 4; ni++)
                acc[mi][ni] = __builtin_amdgcn_mfma_f32_16x16x32_bf16(
                    af[mi], bfr[ni], acc[mi][ni], 0, 0, 0);
        __syncthreads();
    }

    const int side = (n0 >= Nsplit);
    u16* Cw = side ? C1 : C0;
    const int nw = side ? N1 : N0;
    const int cbase = side ? Nsplit : 0;

    #pragma unroll
    for (int mi = 0; mi < 4; mi++) {
        #pragma unroll
        for (int ni = 0; ni < 4; ni++) {
            #pragma unroll
            for (int r = 0; r < 4; r++) {
                int row = m0 + wm + mi * 16 + quad * 4 + r;
                int col = n0 + wn + ni * 16 + l16 - cbase;
                Cw[(size_t)row * nw + col] = f2bf(acc[mi][ni][r]);
            }
        }
    }
}

// ---------------- RoPE + head-major permute ----------------
__global__ void rope_perm(const u16* __restrict__ in, u16* __restrict__ out,
                          int nh, int nhbits) {
    int idx = blockIdx.x * 256 + threadIdx.x;   // one thread per (b,h,l,d<64)
    int d = idx & 63;
    int l = (idx >> 6) & (L_ - 1);
    int h = (idx >> 17) & (nh - 1);
    int b = idx >> (17 + nhbits);
    const u16* src = &in[(((size_t)b * L_ + l) * nh + h) * HD_];
    u16* dst = &out[(((size_t)b * nh + h) * L_ + l) * HD_];
    float t1 = bf2f(src[d]), t2 = bf2f(src[d + 64]);
    float inv = expf(-(float)d * 0.14391156831212787f);  // ln(10000)/64
    float fr = (float)l * inv;
    float c = cosf(fr), sn = sinf(fr);
    dst[d]      = f2bf(t1 * c - t2 * sn);
    dst[d + 64] = f2bf(t2 * c + t1 * sn);
}

// ---------------- MFMA flash attention (GQA head-merged waves) -----------
// Block = 4 waves = 4 HEADS of one kv-group, all on the SAME 32 q-rows.
// LDS 33 KB + VGPR <= 128  ->  4 blocks/CU resident (launch_bounds(256,4)).
// R3 lesson: register prefetch (+33 VGPR) broke the 128 cap -> scratch
// spills -> 1.1 GB HBM traffic. Direct stage (R1-style, 104 VGPR) fits.
//   Ks linear [64][128] + XOR chunk swizzle (chunk ^= row&7) -> conflict-free
//   Vs linear [128][64] + same swizzle
//   Ps OVERLAYS Ks (Ks dead after QK^T; barrier between QK and P-writes).
// Work split: grid 1280 = 5 blocks per c=(bkvh,j); every block <= 8.3 k-tile
// iterations; all blocks write fp32 partial (O,l) NON-TEMPORALLY (keeps the
// XCD-resident K/V in L2); combine kernel sums + normalizes.
//   c&7 -> (b,kvh): XCD-affine K/V in L2.  4 resident + 1 backfill per CU.
// Max-free softmax: p = exp2(s*SCALE*log2e - 8); shift cancels in O/l, and
// partial (O,l) combine by pure addition (no max bookkeeping).
__global__ __launch_bounds__(256, 4)
void attn_mfma(const u16* __restrict__ Q, const u16* __restrict__ K,
               const u16* __restrict__ Vt, const int* __restrict__ amask,
               float* __restrict__ Opart, float* __restrict__ lpart) {
    __shared__ __align__(16) u16 Ks[64][128];    // 16 KB, also Ps after QK^T
    __shared__ __align__(16) u16 Vs[128][64];    // 16 KB
    __shared__ int smask[64];

    const int tid  = threadIdx.x;
    const int wave = tid >> 6, lane = tid & 63;
    const int quad = lane >> 4, l16 = lane & 15;

    const int bid = blockIdx.x;
    const int s   = bid >> 8;                // 0..4 chunk slot
    const int c   = bid & 255;
    const int bkvh = c & 7;                  // XCD-affine: bid%8 -> XCD
    const int j   = c >> 3;                  // 0..31
    const int b   = bkvh >> 2, kvh = bkvh & 3;

    const int H  = ((32 + j) >> 1) + 1;      // heavy tile key-tiles (17..32)
    const int Lg = ((31 - j) >> 1) + 1;      // light tile key-tiles (1..16)
    const int nh = (j < 16) ? 3 : 4;         // heavy chunk count (all <= 8)
    int t, kt0, kt1;
    if (s < nh) { t = 32 + j; kt0 = (H * s) / nh; kt1 = (H * (s + 1)) / nh; }
    else {
        const int ls = s - nh, nl = 5 - nh;  // light chunk count (2 or 1)
        t = 31 - j; kt0 = (Lg * ls) / nl; kt1 = (Lg * (ls + 1)) / nl;
    }

    const int h   = kvh * 4 + wave;          // wave = head
    const int q0  = t * 32;

    const u16* Qbase = Q  + ((size_t)b * NH_  + h)   * L_ * HD_;
    const u16* Kbase = K  + ((size_t)b * NKV_ + kvh) * L_ * HD_;
    const u16* Vbase = Vt + ((size_t)b * NKV_ + kvh) * (size_t)HD_ * L_;
    const int* mbase = amask + b * L_;

    // Q fragments in registers for the whole kernel
    short8 qa[2][4];
    #pragma unroll
    for (int mi = 0; mi < 2; ++mi)
        #pragma unroll
        for (int ks = 0; ks < 4; ++ks)
            qa[mi][ks] = *(const short8*)&Qbase[(size_t)(q0 + mi * 16 + l16) * HD_ + ks * 32 + quad * 8];

    floatx4 Oacc[2][8] = {};
    float lsum[2][4] = {};

    // staging coords (256 threads cooperate across the block); swizzled LDS
    // column offsets are loop-invariant -> precompute pointers.
    const int krow = tid >> 2, kq0 = (tid & 3) * 4;   // K: 4 16B-chunks/thread
    const int vrow = tid >> 1, vc0 = (tid & 1) * 4;   // V: 4 16B-chunks/thread
    const int kr7  = krow & 7, vr7 = vrow & 7;
    u16* kdst0 = &Ks[krow][((kq0 + 0) ^ kr7) * 8];
    u16* kdst1 = &Ks[krow][((kq0 + 1) ^ kr7) * 8];
    u16* kdst2 = &Ks[krow][((kq0 + 2) ^ kr7) * 8];
    u16* kdst3 = &Ks[krow][((kq0 + 3) ^ kr7) * 8];
    u16* vdst0 = &Vs[vrow][((vc0 + 0) ^ vr7) * 8];
    u16* vdst1 = &Vs[vrow][((vc0 + 1) ^ vr7) * 8];
    u16* vdst2 = &Vs[vrow][((vc0 + 2) ^ vr7) * 8];
    u16* vdst3 = &Vs[vrow][((vc0 + 3) ^ vr7) * 8];
    const u16* ksrc = Kbase + ((size_t)(kt0 * 64 + krow)) * HD_ + kq0 * 8;
    const u16* vsrc = Vbase + (size_t)vrow * L_ + kt0 * 64 + vc0 * 8;

    // Ps overlay on Ks: per-wave 4 KB slice
    u16* Psb = &Ks[0][0] + wave * 2048;

    // Ps swizzle helper for reads
    const int fr_rd = ((l16 >> 2) & 3) ^ ((l16 & 3) << 1);

    for (int kt = kt0; kt < kt1; ++kt) {
        const int kbase = kt * 64;

        // ---- stage K/V tile (direct global -> LDS, swizzled store) ----
        *(uint4*)kdst0 = *(const uint4*)(ksrc);
        *(uint4*)kdst1 = *(const uint4*)(ksrc + 8);
        *(uint4*)kdst2 = *(const uint4*)(ksrc + 16);
        *(uint4*)kdst3 = *(const uint4*)(ksrc + 24);
        *(uint4*)vdst0 = *(const uint4*)(vsrc);
        *(uint4*)vdst1 = *(const uint4*)(vsrc + 8);
        *(uint4*)vdst2 = *(const uint4*)(vsrc + 16);
        *(uint4*)vdst3 = *(const uint4*)(vsrc + 24);
        if (tid < 64) smask[tid] = mbase[kbase + tid];
        ksrc += (size_t)64 * HD_;
        vsrc += 64;
        __syncthreads();

        // ---- S = Q K^T : 2 m-tiles x 4 n-tiles x 4 k-steps (K from LDS) ----
        floatx4 sfr[2][4] = {};
        __builtin_amdgcn_s_setprio(1);
        #pragma unroll
        for (int ni = 0; ni < 4; ++ni) {
            #pragma unroll
            for (int ks = 0; ks < 4; ++ks) {
                short8 kf = *(const short8*)&Ks[ni * 16 + l16][((ks * 4 + quad) ^ (l16 & 7)) * 8];
                sfr[0][ni] = __builtin_amdgcn_mfma_f32_16x16x32_bf16(qa[0][ks], kf, sfr[0][ni], 0, 0, 0);
                sfr[1][ni] = __builtin_amdgcn_mfma_f32_16x16x32_bf16(qa[1][ks], kf, sfr[1][ni], 0, 0, 0);
            }
        }
        __builtin_amdgcn_s_setprio(0);

        int am[4];
        #pragma unroll
        for (int ni = 0; ni < 4; ++ni) am[ni] = smask[ni * 16 + l16];

        __syncthreads();   // all waves done reading Ks -> Ps overlay is safe

        // ---- p = exp2(s*SC2 - 8), masked; per-lane l; swizzled pack ----
        #pragma unroll
        for (int mi = 0; mi < 2; ++mi) {
            #pragma unroll
            for (int ni = 0; ni < 4; ++ni) {
                const int kpos = kbase + ni * 16 + l16;
                const bool okm = am[ni] > 0;
                const int blk_log = ni * 2 + (l16 >> 3);
                const int off = l16 & 7;
                #pragma unroll
                for (int r = 0; r < 4; ++r) {
                    const int qrow = q0 + mi * 16 + quad * 4 + r;
                    const bool ok = (kpos <= qrow) & okm;
                    float p = ok ? exp2f(fmaf(sfr[mi][ni][r], SC2_, -8.0f)) : 0.0f;
                    lsum[mi][r] += p;
                    const int pblk = blk_log ^ quad ^ (r << 1);
                    Psb[(mi * 16 + quad * 4 + r) * 64 + pblk * 8 + off] = f2bf(p);
                }
            }
        }

        // ---- P: D-layout -> A-layout (per-wave slice, swizzled read) ----
        short8 pf[2][2];
        #pragma unroll
        for (int mi = 0; mi < 2; ++mi)
            #pragma unroll
            for (int kc = 0; kc < 2; ++kc)
                pf[mi][kc] = *(const short8*)&Psb[(mi * 16 + l16) * 64 + ((kc * 4 + quad) ^ fr_rd) * 8];

        // ---- O += P V (V from LDS, swizzled) ----
        __builtin_amdgcn_s_setprio(1);
        #pragma unroll
        for (int kc = 0; kc < 2; ++kc) {
            #pragma unroll
            for (int dn = 0; dn < 8; ++dn) {
                short8 vf = *(const short8*)&Vs[dn * 16 + l16][((kc * 4 + quad) ^ (l16 & 7)) * 8];
                Oacc[0][dn] = __builtin_amdgcn_mfma_f32_16x16x32_bf16(pf[0][kc], vf, Oacc[0][dn], 0, 0, 0);
                Oacc[1][dn] = __builtin_amdgcn_mfma_f32_16x16x32_bf16(pf[1][kc], vf, Oacc[1][dn], 0, 0, 0);
            }
        }
        __builtin_amdgcn_s_setprio(0);
        __syncthreads();   // Ks(Ps)/Vs consumed; safe to overwrite next iter
    }

    // ---- epilogue: every block writes fp32 partial (O, l), non-temporal ----
    float* od = Opart + ((size_t)bid * 4 + wave) * 32 * 128;
    float* lp = lpart + ((size_t)bid * 4 + wave) * 32;
    #pragma unroll
    for (int mi = 0; mi < 2; ++mi) {
        #pragma unroll
        for (int r = 0; r < 4; ++r) {
            float v = lsum[mi][r];
            v += __shfl_xor(v, 1);
            v += __shfl_xor(v, 2);
            v += __shfl_xor(v, 4);
            v += __shfl_xor(v, 8);
            const int qi = mi * 16 + quad * 4 + r;
            if (l16 == 0) __builtin_nontemporal_store(v, &lp[qi]);
            #pragma unroll
            for (int dn = 0; dn < 8; ++dn)
                __builtin_nontemporal_store(Oacc[mi][dn][r],
                                            &od[(size_t)qi * 128 + dn * 16 + l16]);
        }
    }
}

// ---------------- combine split-tile partials -> final bf16 Y ------------
// Grid 2048 = 8 z * 256 c, XCD-affine (cb%8 == c%8). z = (tile, head):
// tile 0 = heavy t=32+j (nh partials), tile 1 = light t=31-j (5-nh partials).
__global__ __launch_bounds__(256)
void attn_combine(const float* __restrict__ Opart, const float* __restrict__ lpart,
                  u16* __restrict__ Y) {
    const int cb = blockIdx.x;
    const int c  = cb & 255, z = cb >> 8;
    const int tile = z >> 2, hw = z & 3;
    const int bkvh = c & 7, j = c >> 3;
    const int b = bkvh >> 2, kvh = bkvh & 3;
    const int h = kvh * 4 + hw;
    const int nh = (j < 16) ? 3 : 4;
    const int s0 = tile ? nh : 0;
    const int ns = tile ? (5 - nh) : nh;
    const int t  = tile ? (31 - j) : (32 + j);
    const int tid = threadIdx.x;
    const int q = tid >> 3, dg = tid & 7;    // q 0..31, d-block 0..7 (16 floats)

    float4 a0 = {0,0,0,0}, a1 = {0,0,0,0}, a2 = {0,0,0,0}, a3 = {0,0,0,0};
    float lacc = 0.0f;
    for (int i = 0; i < ns; ++i) {
        const size_t rowb = ((size_t)((s0 + i) * 256 + c) * 4 + hw) * 32 + q;
        lacc += lpart[rowb];
        const float4* op = (const float4*)(Opart + rowb * 128 + dg * 16);
        float4 v0 = op[0], v1 = op[1], v2 = op[2], v3 = op[3];
        a0.x += v0.x; a0.y += v0.y; a0.z += v0.z; a0.w += v0.w;
        a1.x += v1.x; a1.y += v1.y; a1.z += v1.z; a1.w += v1.w;
        a2.x += v2.x; a2.y += v2.y; a2.z += v2.z; a2.w += v2.w;
        a3.x += v3.x; a3.y += v3.y; a3.z += v3.z; a3.w += v3.w;
    }
    const float linv = 1.0f / lacc;
    const int qrow = t * 32 + q;
    u16* dst = &Y[(((size_t)b * L_ + qrow) * NH_ + h) * HD_ + dg * 16];

    u16 tmp[16];
    tmp[0]  = f2bf(a0.x * linv); tmp[1]  = f2bf(a0.y * linv);
    tmp[2]  = f2bf(a0.z * linv); tmp[3]  = f2bf(a0.w * linv);
    tmp[4]  = f2bf(a1.x * linv); tmp[5]  = f2bf(a1.y * linv);
    tmp[6]  = f2bf(a1.z * linv); tmp[7]  = f2bf(a1.w * linv);
    tmp[8]  = f2bf(a2.x * linv); tmp[9]  = f2bf(a2.y * linv);
    tmp[10] = f2bf(a2.z * linv); tmp[11] = f2bf(a2.w * linv);
    tmp[12] = f2bf(a3.x * linv); tmp[13] = f2bf(a3.y * linv);
    tmp[14] = f2bf(a3.z * linv); tmp[15] = f2bf(a3.w * linv);
    *(uint4*)(dst)     = *(const uint4*)(&tmp[0]);
    *(uint4*)(dst + 8) = *(const uint4*)(&tmp[8]);
}

// ---------------- launch ----------------
extern "C" void kernel_launch(void* const* d_in, const int* in_sizes, int n_in,
                              void* d_out, int out_size, void* d_ws, size_t ws_size,
                              hipStream_t stream) {
    const float* x  = (const float*)d_in[0];
    const float* Wq = (const float*)d_in[1];
    const float* Wc = (const float*)d_in[2];
    const float* Wk = (const float*)d_in[3];
    const float* Wv = (const float*)d_in[4];
    const float* Wo = (const float*)d_in[5];
    const int* amask = (const int*)d_in[6];
    float* out = (float*)d_out;

    char* p = (char*)d_ws;
    auto alloc = [&](size_t elems) {
        u16* r = (u16*)p;
        p += ((elems * 2 + 255) / 256) * 256;
        return r;
    };
    // --- alive through attention ---
    u16* WoT  = alloc((size_t)2048 * 2048);
    u16* qbuf = alloc((size_t)4096 * 2048);   // pre-rope q; reused as Y
    u16* Qr   = alloc((size_t)4096 * 2048);
    u16* Kr   = alloc((size_t)4096 * 512);
    u16* Vt   = alloc((size_t)4096 * 512);    // [B, NKV, HD, L]
    // --- dead once attention starts (Opart overlays this region) ---
    char* pdead = p;
    u16* Xb   = alloc((size_t)4096 * 2048);
    u16* WqT  = alloc((size_t)2048 * 2048);   // NOTE: WqT|WcT adjacent (fused)
    u16* WcT  = alloc((size_t)512 * 2048);
    u16* WkT  = alloc((size_t)512 * 512);     // NOTE: WkT|WvT adjacent (fused)
    u16* WvT  = alloc((size_t)512 * 512);
    u16* cbuf = alloc((size_t)4096 * 512);
    u16* kbuf = alloc((size_t)4096 * 512);
    u16* vbuf = alloc((size_t)4096 * 512);
    // partials: 1280 blocks x 4 heads x 32 q x 128 d fp32 (~84 MB, overlays)
    float* Opart = (float*)pdead;
    float* lpart = (float*)(pdead + (size_t)1280 * 4 * 32 * 128 * 4);

    // converts
    cvt_kernel<<<8388608 / 256, 256, 0, stream>>>(x, Xb, 8388608);
    cvt_transpose_kernel<<<dim3(2048 / 32, 2048 / 32), 256, 0, stream>>>(Wq, WqT, 2048, 2048);
    cvt_transpose_kernel<<<dim3(512 / 32, 2048 / 32), 256, 0, stream>>>(Wc, WcT, 2048, 512);
    cvt_transpose_kernel<<<dim3(512 / 32, 512 / 32), 256, 0, stream>>>(Wk, WkT, 512, 512);
    cvt_transpose_kernel<<<dim3(512 / 32, 512 / 32), 256, 0, stream>>>(Wv, WvT, 512, 512);
    cvt_transpose_kernel<<<dim3(2048 / 32, 2048 / 32), 256, 0, stream>>>(Wo, WoT, 2048, 2048);

    // projections: fused [Wq|Wc] (N=2560) and [Wk|Wv] (N=1024)
    gemm_bt_split<<<dim3(20, 32), 256, 0, stream>>>(Xb, WqT, qbuf, cbuf,
                                                    4096, 2560, 2048, 2048, 2048, 512);
    gemm_bt_split<<<dim3(8, 32), 256, 0, stream>>>(cbuf, WkT, kbuf, vbuf,
                                                   4096, 1024, 512, 512, 512, 512);

    // rope + permute to head-major; V -> [b,kvh,d,l]
    rope_perm<<<(2 * 16 * 2048 * 64) / 256, 256, 0, stream>>>(qbuf, Qr, 16, 4);
    rope_perm<<<(2 * 4 * 2048 * 64) / 256, 256, 0, stream>>>(kbuf, Kr, 4, 2);
    transpose_v_kernel<<<dim3(64, 4, 8), 256, 0, stream>>>(vbuf, Vt);

    // attention partials + combine (Y into qbuf, dead after rope)
    attn_mfma<<<dim3(1280), 256, 0, stream>>>(Qr, Kr, Vt, amask, Opart, lpart);
    attn_combine<<<dim3(2048), 256, 0, stream>>>(Opart, lpart, qbuf);

    // output projection (fp32 out)
    gemm_bt<0><<<dim3(16, 32), 256, 0, stream>>>(qbuf, WoT, out, 4096, 2048, 2048);
}

// Round 5
// 388.863 us; speedup vs baseline: 1.5616x; 1.3582x over previous
//
#include <hip/hip_runtime.h>
#include <hip/hip_bf16.h>
#include <cstdint>
#include <cstddef>

// Problem constants
#define B_    2
#define L_    2048
#define HID_  2048
#define NH_   16
#define NKV_  4
#define HD_   128
#define LAT_  512
#define SCALE_ 0.08838834764831845f   // 1/sqrt(128)
#define SC2_   0.1275174365f          // SCALE * log2(e)

typedef unsigned short u16;
typedef unsigned int   u32;
typedef __attribute__((ext_vector_type(8))) short   short8;
typedef __attribute__((ext_vector_type(4))) float   floatx4;

typedef __attribute__((address_space(1))) const u32 gas_u32;
typedef __attribute__((address_space(3))) u32       las_u32;

__device__ __forceinline__ void gl_lds16(const u16* g, u16* l) {
    // async global->LDS, 16B per lane; LDS dest = wave-uniform base + lane*16
    __builtin_amdgcn_global_load_lds((gas_u32*)g, (las_u32*)l, 16, 0, 0);
}

__device__ __forceinline__ float bf2f(u16 u) {
    union { u32 i; float f; } v; v.i = ((u32)u) << 16; return v.f;
}
__device__ __forceinline__ u16 f2bf(float f) {
    union { float f; u32 u; } v; v.f = f;
    u32 u = v.u;
    u32 r = (u + 0x7fffu + ((u >> 16) & 1u)) >> 16;   // RNE
    return (u16)r;
}

// ---------------- fp32 -> bf16 elementwise ----------------
__global__ void cvt_kernel(const float* __restrict__ in, u16* __restrict__ out, int n) {
    int i = blockIdx.x * 256 + threadIdx.x;
    if (i < n) out[i] = f2bf(in[i]);
}

// ---------------- fp32 [R][C] -> bf16 [C][R] (transpose) ----------------
__global__ void cvt_transpose_kernel(const float* __restrict__ in, u16* __restrict__ out,
                                     int R, int C) {
    __shared__ u16 tile[32][33];
    int c0 = blockIdx.x * 32, r0 = blockIdx.y * 32;
    int tx = threadIdx.x & 31, ty = threadIdx.x >> 5;   // ty in 0..7
    for (int i = ty; i < 32; i += 8)
        tile[tx][i] = f2bf(in[(size_t)(r0 + i) * C + c0 + tx]);
    __syncthreads();
    for (int i = ty; i < 32; i += 8)
        out[(size_t)(c0 + i) * R + r0 + tx] = tile[i][tx];
}

// ---------------- bf16 [b,l,kvh,d] -> bf16 [b,kvh,d,l] (V transpose) ------
__global__ void transpose_v_kernel(const u16* __restrict__ in, u16* __restrict__ out) {
    __shared__ u16 t[32][33];
    int lt = blockIdx.x, dt = blockIdx.y, bh = blockIdx.z;   // bh = b*NKV + kvh
    int b = bh >> 2, kvh = bh & 3;
    int tx = threadIdx.x & 31, ty = threadIdx.x >> 5;
    for (int i = ty; i < 32; i += 8)
        t[i][tx] = in[(((size_t)b * L_ + lt * 32 + i) * NKV_ + kvh) * HD_ + dt * 32 + tx];
    __syncthreads();
    for (int i = ty; i < 32; i += 8)
        out[((size_t)bh * HD_ + dt * 32 + i) * L_ + lt * 32 + tx] = t[tx][i];
}

// ---------------- bf16 GEMM: C[M,N] = A[M,K] * BT[N,K]^T ----------------
// m97 structure: 128x128 tile, BK=32, global_load_lds width-16 staging.
template<int OUT_BF16>
__global__ __launch_bounds__(256)
void gemm_bt(const u16* __restrict__ A, const u16* __restrict__ BT,
             void* __restrict__ C, int M, int N, int K) {
    __shared__ __align__(16) u16 As[128][32];
    __shared__ __align__(16) u16 Bs[128][32];
    const int tid  = threadIdx.x;
    const int m0   = blockIdx.y * 128, n0 = blockIdx.x * 128;
    const int wave = tid >> 6, lane = tid & 63;
    const int wm   = (wave >> 1) * 64, wn = (wave & 1) * 64;
    const int quad = lane >> 4, l16 = lane & 15;

    const int srow = wave * 32 + (lane >> 2);
    const int scol = (lane & 3) * 8;
    const u16* aptr0 = A  + (size_t)(m0 + srow) * K + scol;
    const u16* bptr0 = BT + (size_t)(n0 + srow) * K + scol;
    const u16* aptr1 = aptr0 + (size_t)16 * K;
    const u16* bptr1 = bptr0 + (size_t)16 * K;
    u16* lA0 = &As[wave * 32][0];
    u16* lA1 = &As[wave * 32 + 16][0];
    u16* lB0 = &Bs[wave * 32][0];
    u16* lB1 = &Bs[wave * 32 + 16][0];

    floatx4 acc[4][4] = {};

    for (int k0 = 0; k0 < K; k0 += 32) {
        gl_lds16(aptr0 + k0, lA0);
        gl_lds16(aptr1 + k0, lA1);
        gl_lds16(bptr0 + k0, lB0);
        gl_lds16(bptr1 + k0, lB1);
        __syncthreads();

        short8 af[4], bfr[4];
        #pragma unroll
        for (int i = 0; i < 4; i++) af[i]  = *(const short8*)&As[wm + i * 16 + l16][quad * 8];
        #pragma unroll
        for (int i = 0; i < 4; i++) bfr[i] = *(const short8*)&Bs[wn + i * 16 + l16][quad * 8];
        #pragma unroll
        for (int mi = 0; mi < 4; mi++)
            #pragma unroll
            for (int ni = 0; ni < 4; ni++)
                acc[mi][ni] = __builtin_amdgcn_mfma_f32_16x16x32_bf16(
                    af[mi], bfr[ni], acc[mi][ni], 0, 0, 0);
        __syncthreads();
    }

    #pragma unroll
    for (int mi = 0; mi < 4; mi++) {
        #pragma unroll
        for (int ni = 0; ni < 4; ni++) {
            #pragma unroll
            for (int r = 0; r < 4; r++) {
                int row = m0 + wm + mi * 16 + quad * 4 + r;
                int col = n0 + wn + ni * 16 + l16;
                float v = acc[mi][ni][r];
                if (OUT_BF16) ((u16*)C)[(size_t)row * N + col] = f2bf(v);
                else          ((float*)C)[(size_t)row * N + col] = v;
            }
        }
    }
}

// ---- same GEMM, bf16 out, but N is a fused [B0|B1] stack: cols < Nsplit
// go to C0 (row stride N0), the rest to C1 (row stride N1). Nsplit % 128 == 0
// so the branch is block-uniform. Lets skinny-N projections ride one launch.
__global__ __launch_bounds__(256)
void gemm_bt_split(const u16* __restrict__ A, const u16* __restrict__ BT,
                   u16* __restrict__ C0, u16* __restrict__ C1,
                   int M, int N, int K, int Nsplit, int N0, int N1) {
    __shared__ __align__(16) u16 As[128][32];
    __shared__ __align__(16) u16 Bs[128][32];
    const int tid  = threadIdx.x;
    const int m0   = blockIdx.y * 128, n0 = blockIdx.x * 128;
    const int wave = tid >> 6, lane = tid & 63;
    const int wm   = (wave >> 1) * 64, wn = (wave & 1) * 64;
    const int quad = lane >> 4, l16 = lane & 15;

    const int srow = wave * 32 + (lane >> 2);
    const int scol = (lane & 3) * 8;
    const u16* aptr0 = A  + (size_t)(m0 + srow) * K + scol;
    const u16* bptr0 = BT + (size_t)(n0 + srow) * K + scol;
    const u16* aptr1 = aptr0 + (size_t)16 * K;
    const u16* bptr1 = bptr0 + (size_t)16 * K;
    u16* lA0 = &As[wave * 32][0];
    u16* lA1 = &As[wave * 32 + 16][0];
    u16* lB0 = &Bs[wave * 32][0];
    u16* lB1 = &Bs[wave * 32 + 16][0];

    floatx4 acc[4][4] = {};

    for (int k0 = 0; k0 < K; k0 += 32) {
        gl_lds16(aptr0 + k0, lA0);
        gl_lds16(aptr1 + k0, lA1);
        gl_lds16(bptr0 + k0, lB0);
        gl_lds16(bptr1 + k0, lB1);
        __syncthreads();

        short8 af[4], bfr[4];
        #pragma unroll
        for (int i = 0; i < 4; i++) af[i]  = *(const short8*)&As[wm + i * 16 + l16][quad * 8];
        #pragma unroll
        for (int i = 0; i < 4; i++) bfr[i] = *(const short8*)&Bs[wn + i * 16 + l16][quad * 8];
        #pragma unroll
        for (int mi = 0; mi < 4; mi++)
            #pragma unroll
            for (int ni = 0; ni < 4; ni++)
                acc[mi][ni] = __builtin_amdgcn_mfma_f32_16x16x32_bf16(
                    af[mi], bfr[ni], acc[mi][ni], 0, 0, 0);
        __syncthreads();
    }

    const int side = (n0 >= Nsplit);
    u16* Cw = side ? C1 : C0;
    const int nw = side ? N1 : N0;
    const int cbase = side ? Nsplit : 0;

    #pragma unroll
    for (int mi = 0; mi < 4; mi++) {
        #pragma unroll
        for (int ni = 0; ni < 4; ni++) {
            #pragma unroll
            for (int r = 0; r < 4; r++) {
                int row = m0 + wm + mi * 16 + quad * 4 + r;
                int col = n0 + wn + ni * 16 + l16 - cbase;
                Cw[(size_t)row * nw + col] = f2bf(acc[mi][ni][r]);
            }
        }
    }
}

// ---------------- RoPE + head-major permute ----------------
__global__ void rope_perm(const u16* __restrict__ in, u16* __restrict__ out,
                          int nh, int nhbits) {
    int idx = blockIdx.x * 256 + threadIdx.x;   // one thread per (b,h,l,d<64)
    int d = idx & 63;
    int l = (idx >> 6) & (L_ - 1);
    int h = (idx >> 17) & (nh - 1);
    int b = idx >> (17 + nhbits);
    const u16* src = &in[(((size_t)b * L_ + l) * nh + h) * HD_];
    u16* dst = &out[(((size_t)b * nh + h) * L_ + l) * HD_];
    float t1 = bf2f(src[d]), t2 = bf2f(src[d + 64]);
    float inv = expf(-(float)d * 0.14391156831212787f);  // ln(10000)/64
    float fr = (float)l * inv;
    float c = cosf(fr), sn = sinf(fr);
    dst[d]      = f2bf(t1 * c - t2 * sn);
    dst[d + 64] = f2bf(t2 * c + t1 * sn);
}

// ---------------- MFMA flash attention (GQA head-merged waves) -----------
// Block = 4 waves = 4 HEADS of one kv-group, all on the SAME 32 q-rows.
// LDS 33 KB; NO min-waves clamp: __launch_bounds__(256,4) made the
// allocator split the unified file 64 VGPR + 64 AGPR -> permanent spill
// (R3/R4: 64 VGPR_Count, 630 MB scratch traffic). Plain (256) allocates
// ~110 unified regs -> 4 waves/SIMD naturally -> 4 blocks/CU via LDS.
//   Ks linear [64][128] + XOR chunk swizzle (chunk ^= row&7) -> conflict-free
//   Vs linear [128][64] + same swizzle
//   Ps OVERLAYS Ks (Ks dead after QK^T; barrier between QK and P-writes).
// Work split: grid 1024 = EXACTLY 4 chunks per c=(bkvh,j); per-c work is
// always 33 k-tiles (H+Lg=33), so consecutive bids {c,256+c,512+c,768+c}
// co-resident on one CU give a perfectly balanced 33-iter CU load with no
// backfill wave. Heavy tile -> nh=2|3 chunks (partial, fp32 NT); light tile
// -> 4-nh chunks; when the light tile is a single chunk it direct-writes
// bf16 (no partial, no combine).
//   c&7 -> (b,kvh): XCD-affine K/V in L2.
// Max-free softmax: p = exp2(s*SCALE*log2e - 8); shift cancels in O/l, and
// partial (O,l) combine by pure addition (no max bookkeeping).
__global__ __launch_bounds__(256)
void attn_mfma(const u16* __restrict__ Q, const u16* __restrict__ K,
               const u16* __restrict__ Vt, const int* __restrict__ amask,
               u16* __restrict__ Y, float* __restrict__ Opart,
               float* __restrict__ lpart) {
    __shared__ __align__(16) u16 Ks[64][128];    // 16 KB, also Ps after QK^T
    __shared__ __align__(16) u16 Vs[128][64];    // 16 KB
    __shared__ int smask[64];

    const int tid  = threadIdx.x;
    const int wave = tid >> 6, lane = tid & 63;
    const int quad = lane >> 4, l16 = lane & 15;

    const int bid = blockIdx.x;
    const int s   = bid >> 8;                // 0..3 chunk slot
    const int c   = bid & 255;
    const int bkvh = c & 7;                  // XCD-affine: bid%8 -> XCD
    const int j   = c >> 3;                  // 0..31
    const int b   = bkvh >> 2, kvh = bkvh & 3;

    const int H  = ((32 + j) >> 1) + 1;      // heavy tile key-tiles (17..32)
    const int Lg = ((31 - j) >> 1) + 1;      // light tile key-tiles (1..16)
    // pick heavy chunk count minimizing the max chunk length
    const int m2 = max((H + 1) >> 1, (Lg + 1) >> 1);
    const int m3 = max((H + 2) / 3, Lg);
    const int nh = (m2 <= m3) ? 2 : 3;
    const int nl = 4 - nh;
    int t, kt0, kt1, pi;
    if (s < nh) {
        t = 32 + j; kt0 = (H * s) / nh; kt1 = (H * (s + 1)) / nh; pi = bid;
    } else {
        t = 31 - j;
        const int ls = s - nh;
        kt0 = (Lg * ls) / nl; kt1 = (Lg * (ls + 1)) / nl;
        pi = (nl == 1) ? -1 : bid;           // whole light tile -> direct write
    }

    const int h   = kvh * 4 + wave;          // wave = head
    const int q0  = t * 32;

    const u16* Qbase = Q  + ((size_t)b * NH_  + h)   * L_ * HD_;
    const u16* Kbase = K  + ((size_t)b * NKV_ + kvh) * L_ * HD_;
    const u16* Vbase = Vt + ((size_t)b * NKV_ + kvh) * (size_t)HD_ * L_;
    const int* mbase = amask + b * L_;

    // Q fragments in registers for the whole kernel
    short8 qa[2][4];
    #pragma unroll
    for (int mi = 0; mi < 2; ++mi)
        #pragma unroll
        for (int ks = 0; ks < 4; ++ks)
            qa[mi][ks] = *(const short8*)&Qbase[(size_t)(q0 + mi * 16 + l16) * HD_ + ks * 32 + quad * 8];

    floatx4 Oacc[2][8] = {};
    float lsum[2][4] = {};

    // staging coords (256 threads cooperate across the block); swizzled LDS
    // column offsets are loop-invariant -> precompute pointers.
    const int krow = tid >> 2, kq0 = (tid & 3) * 4;   // K: 4 16B-chunks/thread
    const int vrow = tid >> 1, vc0 = (tid & 1) * 4;   // V: 4 16B-chunks/thread
    const int kr7  = krow & 7, vr7 = vrow & 7;
    u16* kdst0 = &Ks[krow][((kq0 + 0) ^ kr7) * 8];
    u16* kdst1 = &Ks[krow][((kq0 + 1) ^ kr7) * 8];
    u16* kdst2 = &Ks[krow][((kq0 + 2) ^ kr7) * 8];
    u16* kdst3 = &Ks[krow][((kq0 + 3) ^ kr7) * 8];
    u16* vdst0 = &Vs[vrow][((vc0 + 0) ^ vr7) * 8];
    u16* vdst1 = &Vs[vrow][((vc0 + 1) ^ vr7) * 8];
    u16* vdst2 = &Vs[vrow][((vc0 + 2) ^ vr7) * 8];
    u16* vdst3 = &Vs[vrow][((vc0 + 3) ^ vr7) * 8];
    const u16* ksrc = Kbase + ((size_t)(kt0 * 64 + krow)) * HD_ + kq0 * 8;
    const u16* vsrc = Vbase + (size_t)vrow * L_ + kt0 * 64 + vc0 * 8;

    // Ps overlay on Ks: per-wave 4 KB slice
    u16* Psb = &Ks[0][0] + wave * 2048;

    // Ps swizzle helper for reads
    const int fr_rd = ((l16 >> 2) & 3) ^ ((l16 & 3) << 1);

    for (int kt = kt0; kt < kt1; ++kt) {
        const int kbase = kt * 64;

        // ---- stage K/V tile (direct global -> LDS, swizzled store) ----
        *(uint4*)kdst0 = *(const uint4*)(ksrc);
        *(uint4*)kdst1 = *(const uint4*)(ksrc + 8);
        *(uint4*)kdst2 = *(const uint4*)(ksrc + 16);
        *(uint4*)kdst3 = *(const uint4*)(ksrc + 24);
        *(uint4*)vdst0 = *(const uint4*)(vsrc);
        *(uint4*)vdst1 = *(const uint4*)(vsrc + 8);
        *(uint4*)vdst2 = *(const uint4*)(vsrc + 16);
        *(uint4*)vdst3 = *(const uint4*)(vsrc + 24);
        if (tid < 64) smask[tid] = mbase[kbase + tid];
        ksrc += (size_t)64 * HD_;
        vsrc += 64;
        __syncthreads();

        // ---- S = Q K^T : 2 m-tiles x 4 n-tiles x 4 k-steps (K from LDS) ----
        floatx4 sfr[2][4] = {};
        __builtin_amdgcn_s_setprio(1);
        #pragma unroll
        for (int ni = 0; ni < 4; ++ni) {
            #pragma unroll
            for (int ks = 0; ks < 4; ++ks) {
                short8 kf = *(const short8*)&Ks[ni * 16 + l16][((ks * 4 + quad) ^ (l16 & 7)) * 8];
                sfr[0][ni] = __builtin_amdgcn_mfma_f32_16x16x32_bf16(qa[0][ks], kf, sfr[0][ni], 0, 0, 0);
                sfr[1][ni] = __builtin_amdgcn_mfma_f32_16x16x32_bf16(qa[1][ks], kf, sfr[1][ni], 0, 0, 0);
            }
        }
        __builtin_amdgcn_s_setprio(0);

        int am[4];
        #pragma unroll
        for (int ni = 0; ni < 4; ++ni) am[ni] = smask[ni * 16 + l16];

        __syncthreads();   // all waves done reading Ks -> Ps overlay is safe

        // ---- p = exp2(s*SC2 - 8), masked; per-lane l; swizzled pack ----
        #pragma unroll
        for (int mi = 0; mi < 2; ++mi) {
            #pragma unroll
            for (int ni = 0; ni < 4; ++ni) {
                const int kpos = kbase + ni * 16 + l16;
                const bool okm = am[ni] > 0;
                const int blk_log = ni * 2 + (l16 >> 3);
                const int off = l16 & 7;
                #pragma unroll
                for (int r = 0; r < 4; ++r) {
                    const int qrow = q0 + mi * 16 + quad * 4 + r;
                    const bool ok = (kpos <= qrow) & okm;
                    float p = ok ? exp2f(fmaf(sfr[mi][ni][r], SC2_, -8.0f)) : 0.0f;
                    lsum[mi][r] += p;
                    const int pblk = blk_log ^ quad ^ (r << 1);
                    Psb[(mi * 16 + quad * 4 + r) * 64 + pblk * 8 + off] = f2bf(p);
                }
            }
        }

        // ---- P: D-layout -> A-layout (per-wave slice, swizzled read) ----
        short8 pf[2][2];
        #pragma unroll
        for (int mi = 0; mi < 2; ++mi)
            #pragma unroll
            for (int kc = 0; kc < 2; ++kc)
                pf[mi][kc] = *(const short8*)&Psb[(mi * 16 + l16) * 64 + ((kc * 4 + quad) ^ fr_rd) * 8];

        // ---- O += P V (V from LDS, swizzled) ----
        __builtin_amdgcn_s_setprio(1);
        #pragma unroll
        for (int kc = 0; kc < 2; ++kc) {
            #pragma unroll
            for (int dn = 0; dn < 8; ++dn) {
                short8 vf = *(const short8*)&Vs[dn * 16 + l16][((kc * 4 + quad) ^ (l16 & 7)) * 8];
                Oacc[0][dn] = __builtin_amdgcn_mfma_f32_16x16x32_bf16(pf[0][kc], vf, Oacc[0][dn], 0, 0, 0);
                Oacc[1][dn] = __builtin_amdgcn_mfma_f32_16x16x32_bf16(pf[1][kc], vf, Oacc[1][dn], 0, 0, 0);
            }
        }
        __builtin_amdgcn_s_setprio(0);
        __syncthreads();   // Ks(Ps)/Vs consumed; safe to overwrite next iter
    }

    // ---- epilogue ----
    if (pi < 0) {
        // whole light tile in this block: reduce l, write bf16 Y directly
        #pragma unroll
        for (int mi = 0; mi < 2; ++mi) {
            #pragma unroll
            for (int r = 0; r < 4; ++r) {
                float v = lsum[mi][r];
                v += __shfl_xor(v, 1);
                v += __shfl_xor(v, 2);
                v += __shfl_xor(v, 4);
                v += __shfl_xor(v, 8);
                const float linv = 1.0f / v;
                const int qrow = q0 + mi * 16 + quad * 4 + r;
                u16* dst = &Y[(((size_t)b * L_ + qrow) * NH_ + h) * HD_];
                #pragma unroll
                for (int dn = 0; dn < 8; ++dn)
                    dst[dn * 16 + l16] = f2bf(Oacc[mi][dn][r] * linv);
            }
        }
    } else {
        // partial: write fp32 O and summed l, non-temporal
        float* od = Opart + ((size_t)pi * 4 + wave) * 32 * 128;
        float* lp = lpart + ((size_t)pi * 4 + wave) * 32;
        #pragma unroll
        for (int mi = 0; mi < 2; ++mi) {
            #pragma unroll
            for (int r = 0; r < 4; ++r) {
                float v = lsum[mi][r];
                v += __shfl_xor(v, 1);
                v += __shfl_xor(v, 2);
                v += __shfl_xor(v, 4);
                v += __shfl_xor(v, 8);
                const int qi = mi * 16 + quad * 4 + r;
                if (l16 == 0) __builtin_nontemporal_store(v, &lp[qi]);
                #pragma unroll
                for (int dn = 0; dn < 8; ++dn)
                    __builtin_nontemporal_store(Oacc[mi][dn][r],
                                                &od[(size_t)qi * 128 + dn * 16 + l16]);
            }
        }
    }
}

// ---------------- combine split-tile partials -> final bf16 Y ------------
// Grid 2048 = 8 z * 256 c, XCD-affine (cb%8 == c%8). z = (tile, head):
// tile 0 = heavy t=32+j (nh partials); tile 1 = light t=31-j (nl partials,
// but nl==1 means the attn block direct-wrote -> early exit).
__global__ __launch_bounds__(256)
void attn_combine(const float* __restrict__ Opart, const float* __restrict__ lpart,
                  u16* __restrict__ Y) {
    const int cb = blockIdx.x;
    const int c  = cb & 255, z = cb >> 8;
    const int tile = z >> 2, hw = z & 3;
    const int bkvh = c & 7, j = c >> 3;
    const int b = bkvh >> 2, kvh = bkvh & 3;
    const int h = kvh * 4 + hw;
    const int H  = ((32 + j) >> 1) + 1;
    const int Lg = ((31 - j) >> 1) + 1;
    const int m2 = max((H + 1) >> 1, (Lg + 1) >> 1);
    const int m3 = max((H + 2) / 3, Lg);
    const int nh = (m2 <= m3) ? 2 : 3;
    const int nl = 4 - nh;
    if (tile == 1 && nl == 1) return;        // direct-written by attn block
    const int s0 = tile ? nh : 0;
    const int ns = tile ? nl : nh;
    const int t  = tile ? (31 - j) : (32 + j);
    const int tid = threadIdx.x;
    const int q = tid >> 3, dg = tid & 7;    // q 0..31, d-block 0..7 (16 floats)

    float4 a0 = {0,0,0,0}, a1 = {0,0,0,0}, a2 = {0,0,0,0}, a3 = {0,0,0,0};
    float lacc = 0.0f;
    for (int i = 0; i < ns; ++i) {
        const size_t rowb = ((size_t)((s0 + i) * 256 + c) * 4 + hw) * 32 + q;
        lacc += lpart[rowb];
        const float4* op = (const float4*)(Opart + rowb * 128 + dg * 16);
        float4 v0 = op[0], v1 = op[1], v2 = op[2], v3 = op[3];
        a0.x += v0.x; a0.y += v0.y; a0.z += v0.z; a0.w += v0.w;
        a1.x += v1.x; a1.y += v1.y; a1.z += v1.z; a1.w += v1.w;
        a2.x += v2.x; a2.y += v2.y; a2.z += v2.z; a2.w += v2.w;
        a3.x += v3.x; a3.y += v3.y; a3.z += v3.z; a3.w += v3.w;
    }
    const float linv = 1.0f / lacc;
    const int qrow = t * 32 + q;
    u16* dst = &Y[(((size_t)b * L_ + qrow) * NH_ + h) * HD_ + dg * 16];

    u16 tmp[16];
    tmp[0]  = f2bf(a0.x * linv); tmp[1]  = f2bf(a0.y * linv);
    tmp[2]  = f2bf(a0.z * linv); tmp[3]  = f2bf(a0.w * linv);
    tmp[4]  = f2bf(a1.x * linv); tmp[5]  = f2bf(a1.y * linv);
    tmp[6]  = f2bf(a1.z * linv); tmp[7]  = f2bf(a1.w * linv);
    tmp[8]  = f2bf(a2.x * linv); tmp[9]  = f2bf(a2.y * linv);
    tmp[10] = f2bf(a2.z * linv); tmp[11] = f2bf(a2.w * linv);
    tmp[12] = f2bf(a3.x * linv); tmp[13] = f2bf(a3.y * linv);
    tmp[14] = f2bf(a3.z * linv); tmp[15] = f2bf(a3.w * linv);
    *(uint4*)(dst)     = *(const uint4*)(&tmp[0]);
    *(uint4*)(dst + 8) = *(const uint4*)(&tmp[8]);
}

// ---------------- launch ----------------
extern "C" void kernel_launch(void* const* d_in, const int* in_sizes, int n_in,
                              void* d_out, int out_size, void* d_ws, size_t ws_size,
                              hipStream_t stream) {
    const float* x  = (const float*)d_in[0];
    const float* Wq = (const float*)d_in[1];
    const float* Wc = (const float*)d_in[2];
    const float* Wk = (const float*)d_in[3];
    const float* Wv = (const float*)d_in[4];
    const float* Wo = (const float*)d_in[5];
    const int* amask = (const int*)d_in[6];
    float* out = (float*)d_out;

    char* p = (char*)d_ws;
    auto alloc = [&](size_t elems) {
        u16* r = (u16*)p;
        p += ((elems * 2 + 255) / 256) * 256;
        return r;
    };
    // --- alive through attention ---
    u16* WoT  = alloc((size_t)2048 * 2048);
    u16* qbuf = alloc((size_t)4096 * 2048);   // pre-rope q; reused as Y
    u16* Qr   = alloc((size_t)4096 * 2048);
    u16* Kr   = alloc((size_t)4096 * 512);
    u16* Vt   = alloc((size_t)4096 * 512);    // [B, NKV, HD, L]
    // --- dead once attention starts (Opart overlays this region) ---
    char* pdead = p;
    u16* Xb   = alloc((size_t)4096 * 2048);
    u16* WqT  = alloc((size_t)2048 * 2048);   // NOTE: WqT|WcT adjacent (fused)
    u16* WcT  = alloc((size_t)512 * 2048);
    u16* WkT  = alloc((size_t)512 * 512);     // NOTE: WkT|WvT adjacent (fused)
    u16* WvT  = alloc((size_t)512 * 512);
    u16* cbuf = alloc((size_t)4096 * 512);
    u16* kbuf = alloc((size_t)4096 * 512);
    u16* vbuf = alloc((size_t)4096 * 512);
    // partials: 1024 blocks x 4 heads x 32 q x 128 d fp32 (~67 MB, overlays)
    float* Opart = (float*)pdead;
    float* lpart = (float*)(pdead + (size_t)1024 * 4 * 32 * 128 * 4);

    // converts
    cvt_kernel<<<8388608 / 256, 256, 0, stream>>>(x, Xb, 8388608);
    cvt_transpose_kernel<<<dim3(2048 / 32, 2048 / 32), 256, 0, stream>>>(Wq, WqT, 2048, 2048);
    cvt_transpose_kernel<<<dim3(512 / 32, 2048 / 32), 256, 0, stream>>>(Wc, WcT, 2048, 512);
    cvt_transpose_kernel<<<dim3(512 / 32, 512 / 32), 256, 0, stream>>>(Wk, WkT, 512, 512);
    cvt_transpose_kernel<<<dim3(512 / 32, 512 / 32), 256, 0, stream>>>(Wv, WvT, 512, 512);
    cvt_transpose_kernel<<<dim3(2048 / 32, 2048 / 32), 256, 0, stream>>>(Wo, WoT, 2048, 2048);

    // projections: fused [Wq|Wc] (N=2560) and [Wk|Wv] (N=1024)
    gemm_bt_split<<<dim3(20, 32), 256, 0, stream>>>(Xb, WqT, qbuf, cbuf,
                                                    4096, 2560, 2048, 2048, 2048, 512);
    gemm_bt_split<<<dim3(8, 32), 256, 0, stream>>>(cbuf, WkT, kbuf, vbuf,
                                                   4096, 1024, 512, 512, 512, 512);

    // rope + permute to head-major; V -> [b,kvh,d,l]
    rope_perm<<<(2 * 16 * 2048 * 64) / 256, 256, 0, stream>>>(qbuf, Qr, 16, 4);
    rope_perm<<<(2 * 4 * 2048 * 64) / 256, 256, 0, stream>>>(kbuf, Kr, 4, 2);
    transpose_v_kernel<<<dim3(64, 4, 8), 256, 0, stream>>>(vbuf, Vt);

    // attention partials + combine (Y into qbuf, dead after rope)
    attn_mfma<<<dim3(1024), 256, 0, stream>>>(Qr, Kr, Vt, amask, qbuf, Opart, lpart);
    attn_combine<<<dim3(2048), 256, 0, stream>>>(Opart, lpart, qbuf);

    // output projection (fp32 out)
    gemm_bt<0><<<dim3(16, 32), 256, 0, stream>>>(qbuf, WoT, out, 4096, 2048, 2048);
}

// Round 7
// 374.206 us; speedup vs baseline: 1.6228x; 1.0392x over previous
//
#include <hip/hip_runtime.h>
#include <hip/hip_bf16.h>
#include <cstdint>
#include <cstddef>

// Problem constants
#define B_    2
#define L_    2048
#define HID_  2048
#define NH_   16
#define NKV_  4
#define HD_   128
#define LAT_  512
#define SCALE_ 0.08838834764831845f   // 1/sqrt(128)
#define SC2_   0.1275174365f          // SCALE * log2(e)

typedef unsigned short u16;
typedef unsigned int   u32;
typedef __attribute__((ext_vector_type(8))) short   short8;
typedef __attribute__((ext_vector_type(4))) float   floatx4;

typedef __attribute__((address_space(1))) const u32 gas_u32;
typedef __attribute__((address_space(3))) u32       las_u32;

__device__ __forceinline__ void gl_lds16(const u16* g, u16* l) {
    __builtin_amdgcn_global_load_lds((gas_u32*)g, (las_u32*)l, 16, 0, 0);
}

__device__ __forceinline__ float bf2f(u16 u) {
    union { u32 i; float f; } v; v.i = ((u32)u) << 16; return v.f;
}
__device__ __forceinline__ u16 f2bf(float f) {
    union { float f; u32 u; } v; v.f = f;
    u32 u = v.u;
    u32 r = (u + 0x7fffu + ((u >> 16) & 1u)) >> 16;   // RNE
    return (u16)r;
}
// HW bf16 cast (compiler fuses pairs into v_cvt_pk_bf16_f32, RNE)
__device__ __forceinline__ u16 f2bf_hw(float f) {
    union { __hip_bfloat16 h; u16 u; } c;
    c.h = __float2bfloat16(f);
    return c.u;
}

// ---------------- fp32 -> bf16 elementwise (x4 vectorized) ----------------
__global__ void cvt_kernel(const float* __restrict__ in, u16* __restrict__ out, int n4) {
    int i = blockIdx.x * 256 + threadIdx.x;
    if (i < n4) {
        float4 v = ((const float4*)in)[i];
        union { u16 w[4]; uint2 v; } o;
        o.w[0] = f2bf(v.x); o.w[1] = f2bf(v.y);
        o.w[2] = f2bf(v.z); o.w[3] = f2bf(v.w);
        ((uint2*)out)[i] = o.v;
    }
}

// ---------------- fp32 [R][C] -> bf16 [C][R] (transpose) ----------------
__global__ void cvt_transpose_kernel(const float* __restrict__ in, u16* __restrict__ out,
                                     int R, int C) {
    __shared__ u16 tile[32][33];
    int c0 = blockIdx.x * 32, r0 = blockIdx.y * 32;
    int tx = threadIdx.x & 31, ty = threadIdx.x >> 5;   // ty in 0..7
    for (int i = ty; i < 32; i += 8)
        tile[tx][i] = f2bf(in[(size_t)(r0 + i) * C + c0 + tx]);
    __syncthreads();
    for (int i = ty; i < 32; i += 8)
        out[(size_t)(c0 + i) * R + r0 + tx] = tile[i][tx];
}

// ---------------- bf16 [b,l,kvh,d] -> bf16 [b,kvh,d,sigma(l)] -------------
// V transpose with sigma-permuted columns within each 64-key block:
// sigma(k) = (k&15)*4 + ((k>>4)&3). This makes the attention P-repack a
// contiguous b64 write per lane while PV's V-fragment read address stays
// the plain contiguous b128 (A and B operands see the same k order; MFMA's
// k-sum is order-agnostic).
__global__ void transpose_v_kernel(const u16* __restrict__ in, u16* __restrict__ out) {
    __shared__ u16 t[32][33];
    int lt = blockIdx.x, dt = blockIdx.y, bh = blockIdx.z;   // bh = b*NKV + kvh
    int b = bh >> 2, kvh = bh & 3;
    int tx = threadIdx.x & 31, ty = threadIdx.x >> 5;
    for (int i = ty; i < 32; i += 8)
        t[i][tx] = in[(((size_t)b * L_ + lt * 32 + i) * NKV_ + kvh) * HD_ + dt * 32 + tx];
    __syncthreads();
    const int lcol = lt * 32 + tx;
    const int csig = (lcol & ~63) | ((lcol & 15) << 2) | ((lcol >> 4) & 3);
    for (int i = ty; i < 32; i += 8)
        out[((size_t)bh * HD_ + dt * 32 + i) * L_ + csig] = t[tx][i];
}

// ---------------- bf16 GEMM: C[M,N] = A[M,K] * BT[N,K]^T ----------------
template<int OUT_BF16>
__global__ __launch_bounds__(256)
void gemm_bt(const u16* __restrict__ A, const u16* __restrict__ BT,
             void* __restrict__ C, int M, int N, int K) {
    __shared__ __align__(16) u16 As[128][32];
    __shared__ __align__(16) u16 Bs[128][32];
    const int tid  = threadIdx.x;
    const int m0   = blockIdx.y * 128, n0 = blockIdx.x * 128;
    const int wave = tid >> 6, lane = tid & 63;
    const int wm   = (wave >> 1) * 64, wn = (wave & 1) * 64;
    const int quad = lane >> 4, l16 = lane & 15;

    const int srow = wave * 32 + (lane >> 2);
    const int scol = (lane & 3) * 8;
    const u16* aptr0 = A  + (size_t)(m0 + srow) * K + scol;
    const u16* bptr0 = BT + (size_t)(n0 + srow) * K + scol;
    const u16* aptr1 = aptr0 + (size_t)16 * K;
    const u16* bptr1 = bptr0 + (size_t)16 * K;
    u16* lA0 = &As[wave * 32][0];
    u16* lA1 = &As[wave * 32 + 16][0];
    u16* lB0 = &Bs[wave * 32][0];
    u16* lB1 = &Bs[wave * 32 + 16][0];

    floatx4 acc[4][4] = {};

    for (int k0 = 0; k0 < K; k0 += 32) {
        gl_lds16(aptr0 + k0, lA0);
        gl_lds16(aptr1 + k0, lA1);
        gl_lds16(bptr0 + k0, lB0);
        gl_lds16(bptr1 + k0, lB1);
        __syncthreads();

        short8 af[4], bfr[4];
        #pragma unroll
        for (int i = 0; i < 4; i++) af[i]  = *(const short8*)&As[wm + i * 16 + l16][quad * 8];
        #pragma unroll
        for (int i = 0; i < 4; i++) bfr[i] = *(const short8*)&Bs[wn + i * 16 + l16][quad * 8];
        #pragma unroll
        for (int mi = 0; mi < 4; mi++)
            #pragma unroll
            for (int ni = 0; ni < 4; ni++)
                acc[mi][ni] = __builtin_amdgcn_mfma_f32_16x16x32_bf16(
                    af[mi], bfr[ni], acc[mi][ni], 0, 0, 0);
        __syncthreads();
    }

    #pragma unroll
    for (int mi = 0; mi < 4; mi++) {
        #pragma unroll
        for (int ni = 0; ni < 4; ni++) {
            #pragma unroll
            for (int r = 0; r < 4; r++) {
                int row = m0 + wm + mi * 16 + quad * 4 + r;
                int col = n0 + wn + ni * 16 + l16;
                float v = acc[mi][ni][r];
                if (OUT_BF16) ((u16*)C)[(size_t)row * N + col] = f2bf(v);
                else          ((float*)C)[(size_t)row * N + col] = v;
            }
        }
    }
}

// ---- same GEMM, bf16 out, fused [B0|B1] N-stack (Nsplit % 128 == 0) ----
__global__ __launch_bounds__(256)
void gemm_bt_split(const u16* __restrict__ A, const u16* __restrict__ BT,
                   u16* __restrict__ C0, u16* __restrict__ C1,
                   int M, int N, int K, int Nsplit, int N0, int N1) {
    __shared__ __align__(16) u16 As[128][32];
    __shared__ __align__(16) u16 Bs[128][32];
    const int tid  = threadIdx.x;
    const int m0   = blockIdx.y * 128, n0 = blockIdx.x * 128;
    const int wave = tid >> 6, lane = tid & 63;
    const int wm   = (wave >> 1) * 64, wn = (wave & 1) * 64;
    const int quad = lane >> 4, l16 = lane & 15;

    const int srow = wave * 32 + (lane >> 2);
    const int scol = (lane & 3) * 8;
    const u16* aptr0 = A  + (size_t)(m0 + srow) * K + scol;
    const u16* bptr0 = BT + (size_t)(n0 + srow) * K + scol;
    const u16* aptr1 = aptr0 + (size_t)16 * K;
    const u16* bptr1 = bptr0 + (size_t)16 * K;
    u16* lA0 = &As[wave * 32][0];
    u16* lA1 = &As[wave * 32 + 16][0];
    u16* lB0 = &Bs[wave * 32][0];
    u16* lB1 = &Bs[wave * 32 + 16][0];

    floatx4 acc[4][4] = {};

    for (int k0 = 0; k0 < K; k0 += 32) {
        gl_lds16(aptr0 + k0, lA0);
        gl_lds16(aptr1 + k0, lA1);
        gl_lds16(bptr0 + k0, lB0);
        gl_lds16(bptr1 + k0, lB1);
        __syncthreads();

        short8 af[4], bfr[4];
        #pragma unroll
        for (int i = 0; i < 4; i++) af[i]  = *(const short8*)&As[wm + i * 16 + l16][quad * 8];
        #pragma unroll
        for (int i = 0; i < 4; i++) bfr[i] = *(const short8*)&Bs[wn + i * 16 + l16][quad * 8];
        #pragma unroll
        for (int mi = 0; mi < 4; mi++)
            #pragma unroll
            for (int ni = 0; ni < 4; ni++)
                acc[mi][ni] = __builtin_amdgcn_mfma_f32_16x16x32_bf16(
                    af[mi], bfr[ni], acc[mi][ni], 0, 0, 0);
        __syncthreads();
    }

    const int side = (n0 >= Nsplit);
    u16* Cw = side ? C1 : C0;
    const int nw = side ? N1 : N0;
    const int cbase = side ? Nsplit : 0;

    #pragma unroll
    for (int mi = 0; mi < 4; mi++) {
        #pragma unroll
        for (int ni = 0; ni < 4; ni++) {
            #pragma unroll
            for (int r = 0; r < 4; r++) {
                int row = m0 + wm + mi * 16 + quad * 4 + r;
                int col = n0 + wn + ni * 16 + l16 - cbase;
                Cw[(size_t)row * nw + col] = f2bf(acc[mi][ni][r]);
            }
        }
    }
}

// ---------------- RoPE + head-major permute ----------------
__global__ void rope_perm(const u16* __restrict__ in, u16* __restrict__ out,
                          int nh, int nhbits) {
    int idx = blockIdx.x * 256 + threadIdx.x;   // one thread per (b,h,l,d<64)
    int d = idx & 63;
    int l = (idx >> 6) & (L_ - 1);
    int h = (idx >> 17) & (nh - 1);
    int b = idx >> (17 + nhbits);
    const u16* src = &in[(((size_t)b * L_ + l) * nh + h) * HD_];
    u16* dst = &out[(((size_t)b * nh + h) * L_ + l) * HD_];
    float t1 = bf2f(src[d]), t2 = bf2f(src[d + 64]);
    float inv = expf(-(float)d * 0.14391156831212787f);  // ln(10000)/64
    float fr = (float)l * inv;
    float c = cosf(fr), sn = sinf(fr);
    dst[d]      = f2bf(t1 * c - t2 * sn);
    dst[d + 64] = f2bf(t2 * c + t1 * sn);
}

// ---------------- MFMA flash attention (GQA head-merged waves) -----------
// Block = 4 waves = 4 HEADS of one kv-group, same 32 q-rows. LDS 33 KB,
// plain __launch_bounds__(256) (R4/R5 lesson: the min-waves clamp forces a
// 64/64 VGPR/AGPR split -> spills).
// P-repack: P stored per row in sigma-order (sigma(k)=(k&15)*4+(k>>4)), so
// each lane writes its 4 ni-values as ONE b64 (was 32 scalar b16 scatters +
// ~130 VALU addr ops). V was sigma-permuted at transpose time, so the PV
// B-fragment read address is unchanged and k-orders agree. bf16 conversion
// via HW cast (cvt_pk pairs).
// Work split: grid 1024 = 4 chunks per c=(bkvh,j); per-c work = 33 k-tiles;
// heavy tile -> nh=2|3 partial chunks (fp32 NT), light tile -> rest; single
// light chunk direct-writes bf16.  c&7 -> XCD-affine K/V in L2.
// Max-free softmax: p = exp2(s*SCALE*log2e - 8); partials add linearly.
__global__ __launch_bounds__(256)
void attn_mfma(const u16* __restrict__ Q, const u16* __restrict__ K,
               const u16* __restrict__ Vt, const int* __restrict__ amask,
               u16* __restrict__ Y, float* __restrict__ Opart,
               float* __restrict__ lpart) {
    __shared__ __align__(16) u16 Ks[64][128];    // 16 KB, also Ps after QK^T
    __shared__ __align__(16) u16 Vs[128][64];    // 16 KB (sigma-ordered k)
    __shared__ int smask[64];

    const int tid  = threadIdx.x;
    const int wave = tid >> 6, lane = tid & 63;
    const int quad = lane >> 4, l16 = lane & 15;

    const int bid = blockIdx.x;
    const int s   = bid >> 8;                // 0..3 chunk slot
    const int c   = bid & 255;
    const int bkvh = c & 7;                  // XCD-affine: bid%8 -> XCD
    const int j   = c >> 3;                  // 0..31
    const int b   = bkvh >> 2, kvh = bkvh & 3;

    const int H  = ((32 + j) >> 1) + 1;      // heavy tile key-tiles (17..32)
    const int Lg = ((31 - j) >> 1) + 1;      // light tile key-tiles (1..16)
    const int m2 = max((H + 1) >> 1, (Lg + 1) >> 1);
    const int m3 = max((H + 2) / 3, Lg);
    const int nh = (m2 <= m3) ? 2 : 3;
    const int nl = 4 - nh;
    int t, kt0, kt1, pi;
    if (s < nh) {
        t = 32 + j; kt0 = (H * s) / nh; kt1 = (H * (s + 1)) / nh; pi = bid;
    } else {
        t = 31 - j;
        const int ls = s - nh;
        kt0 = (Lg * ls) / nl; kt1 = (Lg * (ls + 1)) / nl;
        pi = (nl == 1) ? -1 : bid;           // whole light tile -> direct write
    }

    const int h   = kvh * 4 + wave;          // wave = head
    const int q0  = t * 32;

    const u16* Qbase = Q  + ((size_t)b * NH_  + h)   * L_ * HD_;
    const u16* Kbase = K  + ((size_t)b * NKV_ + kvh) * L_ * HD_;
    const u16* Vbase = Vt + ((size_t)b * NKV_ + kvh) * (size_t)HD_ * L_;
    const int* mbase = amask + b * L_;

    // Q fragments in registers for the whole kernel
    short8 qa[2][4];
    #pragma unroll
    for (int mi = 0; mi < 2; ++mi)
        #pragma unroll
        for (int ks = 0; ks < 4; ++ks)
            qa[mi][ks] = *(const short8*)&Qbase[(size_t)(q0 + mi * 16 + l16) * HD_ + ks * 32 + quad * 8];

    floatx4 Oacc[2][8] = {};
    float lsum[2][4] = {};

    // staging coords; swizzled LDS dests are loop-invariant
    const int krow = tid >> 2, kq0 = (tid & 3) * 4;   // K: 4 16B-chunks/thread
    const int vrow = tid >> 1, vc0 = (tid & 1) * 4;   // V: 4 16B-chunks/thread
    const int kr7  = krow & 7, vr7 = vrow & 7;
    u16* kdst0 = &Ks[krow][((kq0 + 0) ^ kr7) * 8];
    u16* kdst1 = &Ks[krow][((kq0 + 1) ^ kr7) * 8];
    u16* kdst2 = &Ks[krow][((kq0 + 2) ^ kr7) * 8];
    u16* kdst3 = &Ks[krow][((kq0 + 3) ^ kr7) * 8];
    u16* vdst0 = &Vs[vrow][((vc0 + 0) ^ vr7) * 8];
    u16* vdst1 = &Vs[vrow][((vc0 + 1) ^ vr7) * 8];
    u16* vdst2 = &Vs[vrow][((vc0 + 2) ^ vr7) * 8];
    u16* vdst3 = &Vs[vrow][((vc0 + 3) ^ vr7) * 8];
    const u16* ksrc = Kbase + ((size_t)(kt0 * 64 + krow)) * HD_ + kq0 * 8;
    const u16* vsrc = Vbase + (size_t)vrow * L_ + kt0 * 64 + vc0 * 8;

    // Ps overlay on Ks: per-wave 4 KB slice; row = 64 u16 in sigma-order,
    // b64 slots XOR-swizzled by ((row&7)<<1) to kill write/read conflicts.
    u16* Psb = &Ks[0][0] + wave * 2048;

    for (int kt = kt0; kt < kt1; ++kt) {
        const int kbase = kt * 64;

        // ---- stage K/V tile (direct global -> LDS, swizzled store) ----
        *(uint4*)kdst0 = *(const uint4*)(ksrc);
        *(uint4*)kdst1 = *(const uint4*)(ksrc + 8);
        *(uint4*)kdst2 = *(const uint4*)(ksrc + 16);
        *(uint4*)kdst3 = *(const uint4*)(ksrc + 24);
        *(uint4*)vdst0 = *(const uint4*)(vsrc);
        *(uint4*)vdst1 = *(const uint4*)(vsrc + 8);
        *(uint4*)vdst2 = *(const uint4*)(vsrc + 16);
        *(uint4*)vdst3 = *(const uint4*)(vsrc + 24);
        if (tid < 64) smask[tid] = mbase[kbase + tid];
        ksrc += (size_t)64 * HD_;
        vsrc += 64;
        __syncthreads();

        // ---- S = Q K^T ----
        floatx4 sfr[2][4] = {};
        __builtin_amdgcn_s_setprio(1);
        #pragma unroll
        for (int ni = 0; ni < 4; ++ni) {
            #pragma unroll
            for (int ks = 0; ks < 4; ++ks) {
                short8 kf = *(const short8*)&Ks[ni * 16 + l16][((ks * 4 + quad) ^ (l16 & 7)) * 8];
                sfr[0][ni] = __builtin_amdgcn_mfma_f32_16x16x32_bf16(qa[0][ks], kf, sfr[0][ni], 0, 0, 0);
                sfr[1][ni] = __builtin_amdgcn_mfma_f32_16x16x32_bf16(qa[1][ks], kf, sfr[1][ni], 0, 0, 0);
            }
        }
        __builtin_amdgcn_s_setprio(0);

        int am[4];
        #pragma unroll
        for (int ni = 0; ni < 4; ++ni) am[ni] = smask[ni * 16 + l16];

        __syncthreads();   // all waves done reading Ks -> Ps overlay is safe

        // ---- p = exp2(s*SC2 - 8), masked; b64 sigma-packed store ----
        #pragma unroll
        for (int mi = 0; mi < 2; ++mi) {
            #pragma unroll
            for (int r = 0; r < 4; ++r) {
                const int qrow = q0 + mi * 16 + quad * 4 + r;
                union { u16 w[4]; uint2 v; } pb;
                #pragma unroll
                for (int ni = 0; ni < 4; ++ni) {
                    const int kpos = kbase + ni * 16 + l16;
                    const bool ok = (kpos <= qrow) & (am[ni] > 0);
                    float p = ok ? exp2f(fmaf(sfr[mi][ni][r], SC2_, -8.0f)) : 0.0f;
                    lsum[mi][r] += p;
                    pb.w[ni] = f2bf_hw(p);
                }
                const int row = mi * 16 + quad * 4 + r;
                *(uint2*)&Psb[row * 64 + ((l16 ^ ((row & 7) << 1)) << 2)] = pb.v;
            }
        }

        // ---- P fragments: contiguous b128 (slot-XOR by this row's key) ----
        short8 pf[2][2];
        #pragma unroll
        for (int mi = 0; mi < 2; ++mi)
            #pragma unroll
            for (int kc = 0; kc < 2; ++kc) {
                const int row = mi * 16 + l16;
                const int p0 = (kc * 8 + quad * 2) ^ ((l16 & 7) << 1);
                pf[mi][kc] = *(const short8*)&Psb[row * 64 + p0 * 4];
            }

        // ---- O += P V (V sigma-ordered; same read address as before) ----
        __builtin_amdgcn_s_setprio(1);
        #pragma unroll
        for (int kc = 0; kc < 2; ++kc) {
            #pragma unroll
            for (int dn = 0; dn < 8; ++dn) {
                short8 vf = *(const short8*)&Vs[dn * 16 + l16][((kc * 4 + quad) ^ (l16 & 7)) * 8];
                Oacc[0][dn] = __builtin_amdgcn_mfma_f32_16x16x32_bf16(pf[0][kc], vf, Oacc[0][dn], 0, 0, 0);
                Oacc[1][dn] = __builtin_amdgcn_mfma_f32_16x16x32_bf16(pf[1][kc], vf, Oacc[1][dn], 0, 0, 0);
            }
        }
        __builtin_amdgcn_s_setprio(0);
        __syncthreads();   // Ks(Ps)/Vs consumed; safe to overwrite next iter
    }

    // ---- epilogue ----
    if (pi < 0) {
        #pragma unroll
        for (int mi = 0; mi < 2; ++mi) {
            #pragma unroll
            for (int r = 0; r < 4; ++r) {
                float v = lsum[mi][r];
                v += __shfl_xor(v, 1);
                v += __shfl_xor(v, 2);
                v += __shfl_xor(v, 4);
                v += __shfl_xor(v, 8);
                const float linv = 1.0f / v;
                const int qrow = q0 + mi * 16 + quad * 4 + r;
                u16* dst = &Y[(((size_t)b * L_ + qrow) * NH_ + h) * HD_];
                #pragma unroll
                for (int dn = 0; dn < 8; ++dn)
                    dst[dn * 16 + l16] = f2bf(Oacc[mi][dn][r] * linv);
            }
        }
    } else {
        float* od = Opart + ((size_t)pi * 4 + wave) * 32 * 128;
        float* lp = lpart + ((size_t)pi * 4 + wave) * 32;
        #pragma unroll
        for (int mi = 0; mi < 2; ++mi) {
            #pragma unroll
            for (int r = 0; r < 4; ++r) {
                float v = lsum[mi][r];
                v += __shfl_xor(v, 1);
                v += __shfl_xor(v, 2);
                v += __shfl_xor(v, 4);
                v += __shfl_xor(v, 8);
                const int qi = mi * 16 + quad * 4 + r;
                if (l16 == 0) __builtin_nontemporal_store(v, &lp[qi]);
                #pragma unroll
                for (int dn = 0; dn < 8; ++dn)
                    __builtin_nontemporal_store(Oacc[mi][dn][r],
                                                &od[(size_t)qi * 128 + dn * 16 + l16]);
            }
        }
    }
}

// ---------------- combine split-tile partials -> final bf16 Y ------------
__global__ __launch_bounds__(256)
void attn_combine(const float* __restrict__ Opart, const float* __restrict__ lpart,
                  u16* __restrict__ Y) {
    const int cb = blockIdx.x;
    const int c  = cb & 255, z = cb >> 8;
    const int tile = z >> 2, hw = z & 3;
    const int bkvh = c & 7, j = c >> 3;
    const int b = bkvh >> 2, kvh = bkvh & 3;
    const int h = kvh * 4 + hw;
    const int H  = ((32 + j) >> 1) + 1;
    const int Lg = ((31 - j) >> 1) + 1;
    const int m2 = max((H + 1) >> 1, (Lg + 1) >> 1);
    const int m3 = max((H + 2) / 3, Lg);
    const int nh = (m2 <= m3) ? 2 : 3;
    const int nl = 4 - nh;
    if (tile == 1 && nl == 1) return;        // direct-written by attn block
    const int s0 = tile ? nh : 0;
    const int ns = tile ? nl : nh;
    const int t  = tile ? (31 - j) : (32 + j);
    const int tid = threadIdx.x;
    const int q = tid >> 3, dg = tid & 7;    // q 0..31, d-block 0..7 (16 floats)

    float4 a0 = {0,0,0,0}, a1 = {0,0,0,0}, a2 = {0,0,0,0}, a3 = {0,0,0,0};
    float lacc = 0.0f;
    for (int i = 0; i < ns; ++i) {
        const size_t rowb = ((size_t)((s0 + i) * 256 + c) * 4 + hw) * 32 + q;
        lacc += lpart[rowb];
        const float4* op = (const float4*)(Opart + rowb * 128 + dg * 16);
        float4 v0 = op[0], v1 = op[1], v2 = op[2], v3 = op[3];
        a0.x += v0.x; a0.y += v0.y; a0.z += v0.z; a0.w += v0.w;
        a1.x += v1.x; a1.y += v1.y; a1.z += v1.z; a1.w += v1.w;
        a2.x += v2.x; a2.y += v2.y; a2.z += v2.z; a2.w += v2.w;
        a3.x += v3.x; a3.y += v3.y; a3.z += v3.z; a3.w += v3.w;
    }
    const float linv = 1.0f / lacc;
    const int qrow = t * 32 + q;
    u16* dst = &Y[(((size_t)b * L_ + qrow) * NH_ + h) * HD_ + dg * 16];

    u16 tmp[16];
    tmp[0]  = f2bf(a0.x * linv); tmp[1]  = f2bf(a0.y * linv);
    tmp[2]  = f2bf(a0.z * linv); tmp[3]  = f2bf(a0.w * linv);
    tmp[4]  = f2bf(a1.x * linv); tmp[5]  = f2bf(a1.y * linv);
    tmp[6]  = f2bf(a1.z * linv); tmp[7]  = f2bf(a1.w * linv);
    tmp[8]  = f2bf(a2.x * linv); tmp[9]  = f2bf(a2.y * linv);
    tmp[10] = f2bf(a2.z * linv); tmp[11] = f2bf(a2.w * linv);
    tmp[12] = f2bf(a3.x * linv); tmp[13] = f2bf(a3.y * linv);
    tmp[14] = f2bf(a3.z * linv); tmp[15] = f2bf(a3.w * linv);
    *(uint4*)(dst)     = *(const uint4*)(&tmp[0]);
    *(uint4*)(dst + 8) = *(const uint4*)(&tmp[8]);
}

// ---------------- launch ----------------
extern "C" void kernel_launch(void* const* d_in, const int* in_sizes, int n_in,
                              void* d_out, int out_size, void* d_ws, size_t ws_size,
                              hipStream_t stream) {
    const float* x  = (const float*)d_in[0];
    const float* Wq = (const float*)d_in[1];
    const float* Wc = (const float*)d_in[2];
    const float* Wk = (const float*)d_in[3];
    const float* Wv = (const float*)d_in[4];
    const float* Wo = (const float*)d_in[5];
    const int* amask = (const int*)d_in[6];
    float* out = (float*)d_out;

    char* p = (char*)d_ws;
    auto alloc = [&](size_t elems) {
        u16* r = (u16*)p;
        p += ((elems * 2 + 255) / 256) * 256;
        return r;
    };
    // --- alive through attention ---
    u16* WoT  = alloc((size_t)2048 * 2048);
    u16* qbuf = alloc((size_t)4096 * 2048);   // pre-rope q; reused as Y
    u16* Qr   = alloc((size_t)4096 * 2048);
    u16* Kr   = alloc((size_t)4096 * 512);
    u16* Vt   = alloc((size_t)4096 * 512);    // [B, NKV, HD, sigma(L)]
    // --- dead once attention starts (Opart overlays this region) ---
    char* pdead = p;
    u16* Xb   = alloc((size_t)4096 * 2048);
    u16* WqT  = alloc((size_t)2048 * 2048);   // NOTE: WqT|WcT adjacent (fused)
    u16* WcT  = alloc((size_t)512 * 2048);
    u16* WkT  = alloc((size_t)512 * 512);     // NOTE: WkT|WvT adjacent (fused)
    u16* WvT  = alloc((size_t)512 * 512);
    u16* cbuf = alloc((size_t)4096 * 512);
    u16* kbuf = alloc((size_t)4096 * 512);
    u16* vbuf = alloc((size_t)4096 * 512);
    float* Opart = (float*)pdead;
    float* lpart = (float*)(pdead + (size_t)1024 * 4 * 32 * 128 * 4);

    // converts
    cvt_kernel<<<8388608 / 4 / 256, 256, 0, stream>>>(x, Xb, 8388608 / 4);
    cvt_transpose_kernel<<<dim3(2048 / 32, 2048 / 32), 256, 0, stream>>>(Wq, WqT, 2048, 2048);
    cvt_transpose_kernel<<<dim3(512 / 32, 2048 / 32), 256, 0, stream>>>(Wc, WcT, 2048, 512);
    cvt_transpose_kernel<<<dim3(512 / 32, 512 / 32), 256, 0, stream>>>(Wk, WkT, 512, 512);
    cvt_transpose_kernel<<<dim3(512 / 32, 512 / 32), 256, 0, stream>>>(Wv, WvT, 512, 512);
    cvt_transpose_kernel<<<dim3(2048 / 32, 2048 / 32), 256, 0, stream>>>(Wo, WoT, 2048, 2048);

    // projections: fused [Wq|Wc] (N=2560) and [Wk|Wv] (N=1024)
    gemm_bt_split<<<dim3(20, 32), 256, 0, stream>>>(Xb, WqT, qbuf, cbuf,
                                                    4096, 2560, 2048, 2048, 2048, 512);
    gemm_bt_split<<<dim3(8, 32), 256, 0, stream>>>(cbuf, WkT, kbuf, vbuf,
                                                   4096, 1024, 512, 512, 512, 512);

    // rope + permute to head-major; V -> [b,kvh,d,sigma(l)]
    rope_perm<<<(2 * 16 * 2048 * 64) / 256, 256, 0, stream>>>(qbuf, Qr, 16, 4);
    rope_perm<<<(2 * 4 * 2048 * 64) / 256, 256, 0, stream>>>(kbuf, Kr, 4, 2);
    transpose_v_kernel<<<dim3(64, 4, 8), 256, 0, stream>>>(vbuf, Vt);

    // attention partials + combine (Y into qbuf, dead after rope)
    attn_mfma<<<dim3(1024), 256, 0, stream>>>(Qr, Kr, Vt, amask, qbuf, Opart, lpart);
    attn_combine<<<dim3(2048), 256, 0, stream>>>(Opart, lpart, qbuf);

    // output projection (fp32 out)
    gemm_bt<0><<<dim3(16, 32), 256, 0, stream>>>(qbuf, WoT, out, 4096, 2048, 2048);
}

// Round 8
// 359.463 us; speedup vs baseline: 1.6894x; 1.0410x over previous
//
#include <hip/hip_runtime.h>
#include <hip/hip_bf16.h>
#include <cstdint>
#include <cstddef>

// Problem constants
#define B_    2
#define L_    2048
#define HID_  2048
#define NH_   16
#define NKV_  4
#define HD_   128
#define LAT_  512
#define SCALE_ 0.08838834764831845f   // 1/sqrt(128)
#define SC2_   0.1275174365f          // SCALE * log2(e)

typedef unsigned short u16;
typedef unsigned int   u32;
typedef __attribute__((ext_vector_type(8))) short   short8;
typedef __attribute__((ext_vector_type(4))) float   floatx4;

typedef __attribute__((address_space(1))) const u32 gas_u32;
typedef __attribute__((address_space(3))) u32       las_u32;

__device__ __forceinline__ void gl_lds16(const u16* g, u16* l) {
    // async global->LDS, 16B/lane; LDS dest = wave-uniform base + lane*16
    __builtin_amdgcn_global_load_lds((gas_u32*)g, (las_u32*)l, 16, 0, 0);
}

__device__ __forceinline__ float bf2f(u16 u) {
    union { u32 i; float f; } v; v.i = ((u32)u) << 16; return v.f;
}
__device__ __forceinline__ u16 f2bf(float f) {
    union { float f; u32 u; } v; v.f = f;
    u32 u = v.u;
    u32 r = (u + 0x7fffu + ((u >> 16) & 1u)) >> 16;   // RNE
    return (u16)r;
}
// HW bf16 cast (compiler fuses pairs into v_cvt_pk_bf16_f32, RNE)
__device__ __forceinline__ u16 f2bf_hw(float f) {
    union { __hip_bfloat16 h; u16 u; } c;
    c.h = __float2bfloat16(f);
    return c.u;
}

// ---------------- fp32 -> bf16 elementwise (x4 vectorized) ----------------
__global__ void cvt_kernel(const float* __restrict__ in, u16* __restrict__ out, int n4) {
    int i = blockIdx.x * 256 + threadIdx.x;
    if (i < n4) {
        float4 v = ((const float4*)in)[i];
        union { u16 w[4]; uint2 v; } o;
        o.w[0] = f2bf(v.x); o.w[1] = f2bf(v.y);
        o.w[2] = f2bf(v.z); o.w[3] = f2bf(v.w);
        ((uint2*)out)[i] = o.v;
    }
}

// ---------------- fp32 [R][C] -> bf16 [C][R] (transpose) ----------------
__global__ void cvt_transpose_kernel(const float* __restrict__ in, u16* __restrict__ out,
                                     int R, int C) {
    __shared__ u16 tile[32][33];
    int c0 = blockIdx.x * 32, r0 = blockIdx.y * 32;
    int tx = threadIdx.x & 31, ty = threadIdx.x >> 5;   // ty in 0..7
    for (int i = ty; i < 32; i += 8)
        tile[tx][i] = f2bf(in[(size_t)(r0 + i) * C + c0 + tx]);
    __syncthreads();
    for (int i = ty; i < 32; i += 8)
        out[(size_t)(c0 + i) * R + r0 + tx] = tile[i][tx];
}

// ---------------- bf16 [b,l,kvh,d] -> bf16 [b,kvh,d,sigma(l)] -------------
// sigma matches the SWAPPED-QK in-register P layout: for key k (within a
// 64-block) with ni=k>>4, qd=(k>>2)&3, r=k&3, its column position is
// p = ((ni>>1)<<5) | (qd<<3) | ((ni&1)<<2) | r.  Then PV's B-fragment read
// (plain contiguous b128) sees the same k-order as the in-register P pack,
// and MFMA's k-sum is order-agnostic.
__global__ void transpose_v_kernel(const u16* __restrict__ in, u16* __restrict__ out) {
    __shared__ u16 t[32][33];
    int lt = blockIdx.x, dt = blockIdx.y, bh = blockIdx.z;   // bh = b*NKV + kvh
    int b = bh >> 2, kvh = bh & 3;
    int tx = threadIdx.x & 31, ty = threadIdx.x >> 5;
    for (int i = ty; i < 32; i += 8)
        t[i][tx] = in[(((size_t)b * L_ + lt * 32 + i) * NKV_ + kvh) * HD_ + dt * 32 + tx];
    __syncthreads();
    const int lcol = lt * 32 + tx;
    const int k6 = lcol & 63;
    const int ni = k6 >> 4, qd = (k6 >> 2) & 3, r = k6 & 3;
    const int p = ((ni >> 1) << 5) | (qd << 3) | ((ni & 1) << 2) | r;
    const int csig = (lcol & ~63) | p;
    for (int i = ty; i < 32; i += 8)
        out[((size_t)bh * HD_ + dt * 32 + i) * L_ + csig] = t[tx][i];
}

// ---------------- bf16 GEMM: C[M,N] = A[M,K] * BT[N,K]^T ----------------
template<int OUT_BF16>
__global__ __launch_bounds__(256)
void gemm_bt(const u16* __restrict__ A, const u16* __restrict__ BT,
             void* __restrict__ C, int M, int N, int K) {
    __shared__ __align__(16) u16 As[128][32];
    __shared__ __align__(16) u16 Bs[128][32];
    const int tid  = threadIdx.x;
    const int m0   = blockIdx.y * 128, n0 = blockIdx.x * 128;
    const int wave = tid >> 6, lane = tid & 63;
    const int wm   = (wave >> 1) * 64, wn = (wave & 1) * 64;
    const int quad = lane >> 4, l16 = lane & 15;

    const int srow = wave * 32 + (lane >> 2);
    const int scol = (lane & 3) * 8;
    const u16* aptr0 = A  + (size_t)(m0 + srow) * K + scol;
    const u16* bptr0 = BT + (size_t)(n0 + srow) * K + scol;
    const u16* aptr1 = aptr0 + (size_t)16 * K;
    const u16* bptr1 = bptr0 + (size_t)16 * K;
    u16* lA0 = &As[wave * 32][0];
    u16* lA1 = &As[wave * 32 + 16][0];
    u16* lB0 = &Bs[wave * 32][0];
    u16* lB1 = &Bs[wave * 32 + 16][0];

    floatx4 acc[4][4] = {};

    for (int k0 = 0; k0 < K; k0 += 32) {
        gl_lds16(aptr0 + k0, lA0);
        gl_lds16(aptr1 + k0, lA1);
        gl_lds16(bptr0 + k0, lB0);
        gl_lds16(bptr1 + k0, lB1);
        __syncthreads();

        short8 af[4], bfr[4];
        #pragma unroll
        for (int i = 0; i < 4; i++) af[i]  = *(const short8*)&As[wm + i * 16 + l16][quad * 8];
        #pragma unroll
        for (int i = 0; i < 4; i++) bfr[i] = *(const short8*)&Bs[wn + i * 16 + l16][quad * 8];
        #pragma unroll
        for (int mi = 0; mi < 4; mi++)
            #pragma unroll
            for (int ni = 0; ni < 4; ni++)
                acc[mi][ni] = __builtin_amdgcn_mfma_f32_16x16x32_bf16(
                    af[mi], bfr[ni], acc[mi][ni], 0, 0, 0);
        __syncthreads();
    }

    #pragma unroll
    for (int mi = 0; mi < 4; mi++) {
        #pragma unroll
        for (int ni = 0; ni < 4; ni++) {
            #pragma unroll
            for (int r = 0; r < 4; r++) {
                int row = m0 + wm + mi * 16 + quad * 4 + r;
                int col = n0 + wn + ni * 16 + l16;
                float v = acc[mi][ni][r];
                if (OUT_BF16) ((u16*)C)[(size_t)row * N + col] = f2bf(v);
                else          ((float*)C)[(size_t)row * N + col] = v;
            }
        }
    }
}

// ---- same GEMM, bf16 out, fused [B0|B1] N-stack (Nsplit % 128 == 0) ----
__global__ __launch_bounds__(256)
void gemm_bt_split(const u16* __restrict__ A, const u16* __restrict__ BT,
                   u16* __restrict__ C0, u16* __restrict__ C1,
                   int M, int N, int K, int Nsplit, int N0, int N1) {
    __shared__ __align__(16) u16 As[128][32];
    __shared__ __align__(16) u16 Bs[128][32];
    const int tid  = threadIdx.x;
    const int m0   = blockIdx.y * 128, n0 = blockIdx.x * 128;
    const int wave = tid >> 6, lane = tid & 63;
    const int wm   = (wave >> 1) * 64, wn = (wave & 1) * 64;
    const int quad = lane >> 4, l16 = lane & 15;

    const int srow = wave * 32 + (lane >> 2);
    const int scol = (lane & 3) * 8;
    const u16* aptr0 = A  + (size_t)(m0 + srow) * K + scol;
    const u16* bptr0 = BT + (size_t)(n0 + srow) * K + scol;
    const u16* aptr1 = aptr0 + (size_t)16 * K;
    const u16* bptr1 = bptr0 + (size_t)16 * K;
    u16* lA0 = &As[wave * 32][0];
    u16* lA1 = &As[wave * 32 + 16][0];
    u16* lB0 = &Bs[wave * 32][0];
    u16* lB1 = &Bs[wave * 32 + 16][0];

    floatx4 acc[4][4] = {};

    for (int k0 = 0; k0 < K; k0 += 32) {
        gl_lds16(aptr0 + k0, lA0);
        gl_lds16(aptr1 + k0, lA1);
        gl_lds16(bptr0 + k0, lB0);
        gl_lds16(bptr1 + k0, lB1);
        __syncthreads();

        short8 af[4], bfr[4];
        #pragma unroll
        for (int i = 0; i < 4; i++) af[i]  = *(const short8*)&As[wm + i * 16 + l16][quad * 8];
        #pragma unroll
        for (int i = 0; i < 4; i++) bfr[i] = *(const short8*)&Bs[wn + i * 16 + l16][quad * 8];
        #pragma unroll
        for (int mi = 0; mi < 4; mi++)
            #pragma unroll
            for (int ni = 0; ni < 4; ni++)
                acc[mi][ni] = __builtin_amdgcn_mfma_f32_16x16x32_bf16(
                    af[mi], bfr[ni], acc[mi][ni], 0, 0, 0);
        __syncthreads();
    }

    const int side = (n0 >= Nsplit);
    u16* Cw = side ? C1 : C0;
    const int nw = side ? N1 : N0;
    const int cbase = side ? Nsplit : 0;

    #pragma unroll
    for (int mi = 0; mi < 4; mi++) {
        #pragma unroll
        for (int ni = 0; ni < 4; ni++) {
            #pragma unroll
            for (int r = 0; r < 4; r++) {
                int row = m0 + wm + mi * 16 + quad * 4 + r;
                int col = n0 + wn + ni * 16 + l16 - cbase;
                Cw[(size_t)row * nw + col] = f2bf(acc[mi][ni][r]);
            }
        }
    }
}

// ---------------- RoPE + head-major permute ----------------
__global__ void rope_perm(const u16* __restrict__ in, u16* __restrict__ out,
                          int nh, int nhbits) {
    int idx = blockIdx.x * 256 + threadIdx.x;   // one thread per (b,h,l,d<64)
    int d = idx & 63;
    int l = (idx >> 6) & (L_ - 1);
    int h = (idx >> 17) & (nh - 1);
    int b = idx >> (17 + nhbits);
    const u16* src = &in[(((size_t)b * L_ + l) * nh + h) * HD_];
    u16* dst = &out[(((size_t)b * nh + h) * L_ + l) * HD_];
    float t1 = bf2f(src[d]), t2 = bf2f(src[d + 64]);
    float inv = expf(-(float)d * 0.14391156831212787f);  // ln(10000)/64
    float fr = (float)l * inv;
    float c = cosf(fr), sn = sinf(fr);
    dst[d]      = f2bf(t1 * c - t2 * sn);
    dst[d + 64] = f2bf(t2 * c + t1 * sn);
}

// ---------------- MFMA flash attention (GQA head-merged waves) -----------
// Block = 4 waves = 4 HEADS of one kv-group, same 32 q-rows. LDS 32.5 KB,
// plain __launch_bounds__(256) (R4/R5: min-waves clamp -> 64/64 split ->
// spill).  This round:
//  * SWAPPED QK^T: sfr = mfma(K, Q) puts q in the lane (col=l16) and keys
//    in (quad,reg) -> each lane already holds its PV A-fragment values.
//    P never touches LDS; the middle barrier disappears (2 barriers/iter).
//  * V columns sigma-permuted at transpose time so PV's B-operand k-order
//    matches the register P order.
//  * K/V staging via global_load_lds with PRE-SWIZZLED global source
//    (rule 21/m173): linear LDS dest, XOR swizzle in the source address
//    (stays within one 128B line -> coalescing kept). Frees 32 staging
//    VGPRs, halves staging issue, removes the VGPR round trip.
//  * Wave-uniform mask fast-path: full tiles skip cmp/cndmask chains.
// Work split unchanged: grid 1024 = 4 chunks per c=(bkvh,j), 33 k-tiles/c,
// heavy->nh=2|3 fp32-NT partials, single light chunk direct-writes bf16.
__global__ __launch_bounds__(256)
void attn_mfma(const u16* __restrict__ Q, const u16* __restrict__ K,
               const u16* __restrict__ Vt, const int* __restrict__ amask,
               u16* __restrict__ Y, float* __restrict__ Opart,
               float* __restrict__ lpart) {
    __shared__ __align__(16) u16 Ks[64][128];    // 16 KB
    __shared__ __align__(16) u16 Vs[128][64];    // 16 KB (sigma-ordered k)

    const int tid  = threadIdx.x;
    const int wave = tid >> 6, lane = tid & 63;
    const int quad = lane >> 4, l16 = lane & 15;

    const int bid = blockIdx.x;
    const int s   = bid >> 8;                // 0..3 chunk slot
    const int c   = bid & 255;
    const int bkvh = c & 7;                  // XCD-affine: bid%8 -> XCD
    const int j   = c >> 3;                  // 0..31
    const int b   = bkvh >> 2, kvh = bkvh & 3;

    const int H  = ((32 + j) >> 1) + 1;      // heavy tile key-tiles (17..32)
    const int Lg = ((31 - j) >> 1) + 1;      // light tile key-tiles (1..16)
    const int m2 = max((H + 1) >> 1, (Lg + 1) >> 1);
    const int m3 = max((H + 2) / 3, Lg);
    const int nh = (m2 <= m3) ? 2 : 3;
    const int nl = 4 - nh;
    int t, kt0, kt1, pi;
    if (s < nh) {
        t = 32 + j; kt0 = (H * s) / nh; kt1 = (H * (s + 1)) / nh; pi = bid;
    } else {
        t = 31 - j;
        const int ls = s - nh;
        kt0 = (Lg * ls) / nl; kt1 = (Lg * (ls + 1)) / nl;
        pi = (nl == 1) ? -1 : bid;           // whole light tile -> direct write
    }

    const int h   = kvh * 4 + wave;          // wave = head
    const int q0  = t * 32;

    const u16* Qbase = Q  + ((size_t)b * NH_  + h)   * L_ * HD_;
    const u16* Kbase = K  + ((size_t)b * NKV_ + kvh) * L_ * HD_;
    const u16* Vbase = Vt + ((size_t)b * NKV_ + kvh) * (size_t)HD_ * L_;
    const int* mbase = amask + b * L_;

    // Q fragments in registers for the whole kernel
    short8 qa[2][4];
    #pragma unroll
    for (int mi = 0; mi < 2; ++mi)
        #pragma unroll
        for (int ks = 0; ks < 4; ++ks)
            qa[mi][ks] = *(const short8*)&Qbase[(size_t)(q0 + mi * 16 + l16) * HD_ + ks * 32 + quad * 8];

    floatx4 Oacc[2][8] = {};
    float lsum[2] = {0.0f, 0.0f};

    // ---- DMA staging setup: per-wave 4 segments of 1KB for K and V ----
    // K seg: rows seg*4+(lane>>4), 16 slots of 16B; slot sl holds global
    // chunk sl^(row&7). V seg: rows seg*8+(lane>>3), 8 slots; same form.
    const int slK = lane & 15, rKl = lane >> 4;
    const int slV = lane & 7,  rVl = lane >> 3;
    int okg[4], ovg[4];
    u16 *klds[4], *vlds[4];
    #pragma unroll
    for (int cc = 0; cc < 4; ++cc) {
        const int seg = wave * 4 + cc;
        const int rk = seg * 4 + rKl;
        okg[cc] = rk * HD_ + ((slK ^ (rk & 7)) * 8);
        klds[cc] = (u16*)Ks + seg * 512;
        const int rv = seg * 8 + rVl;
        ovg[cc] = rv * L_ + ((slV ^ (rv & 7)) * 8);
        vlds[cc] = (u16*)Vs + seg * 512;
    }
    const u16* kgb = Kbase + (size_t)kt0 * 64 * HD_;
    const u16* vgb = Vbase + kt0 * 64;

    for (int kt = kt0; kt < kt1; ++kt) {
        const int kbase = kt * 64;

        // ---- stage K/V tile via global_load_lds (pre-swizzled source) ----
        #pragma unroll
        for (int cc = 0; cc < 4; ++cc) {
            gl_lds16(kgb + okg[cc], klds[cc]);
            gl_lds16(vgb + ovg[cc], vlds[cc]);
        }
        // wave-uniform mask vote (global, L2-hot)
        const int am_l = mbase[kbase + lane];
        const bool allm = __all(am_l > 0);
        kgb += (size_t)64 * HD_;
        vgb += 64;
        __syncthreads();

        // ---- S^T = K Q^T (swapped): col=l16 -> q, row=quad*4+r -> key ----
        floatx4 sfr[2][4] = {};
        __builtin_amdgcn_s_setprio(1);
        #pragma unroll
        for (int ni = 0; ni < 4; ++ni) {
            #pragma unroll
            for (int ks = 0; ks < 4; ++ks) {
                short8 kf = *(const short8*)&Ks[ni * 16 + l16][((ks * 4 + quad) ^ (l16 & 7)) * 8];
                sfr[0][ni] = __builtin_amdgcn_mfma_f32_16x16x32_bf16(kf, qa[0][ks], sfr[0][ni], 0, 0, 0);
                sfr[1][ni] = __builtin_amdgcn_mfma_f32_16x16x32_bf16(kf, qa[1][ks], sfr[1][ni], 0, 0, 0);
            }
        }
        __builtin_amdgcn_s_setprio(0);

        // ---- softmax in-register: p = exp2(s*SC2 - 8) ----
        if (allm & (kbase + 63 <= q0)) {
            // full tile: no masking needed
            #pragma unroll
            for (int mi = 0; mi < 2; ++mi)
                #pragma unroll
                for (int ni = 0; ni < 4; ++ni)
                    #pragma unroll
                    for (int r = 0; r < 4; ++r) {
                        float p = exp2f(fmaf(sfr[mi][ni][r], SC2_, -8.0f));
                        lsum[mi] += p;
                        sfr[mi][ni][r] = p;
                    }
        } else {
            #pragma unroll
            for (int ni = 0; ni < 4; ++ni) {
                const int4 amv = *(const int4*)&mbase[kbase + ni * 16 + quad * 4];
                const int amr[4] = {amv.x, amv.y, amv.z, amv.w};
                #pragma unroll
                for (int mi = 0; mi < 2; ++mi) {
                    const int qrow = q0 + mi * 16 + l16;
                    #pragma unroll
                    for (int r = 0; r < 4; ++r) {
                        const int kpos = kbase + ni * 16 + quad * 4 + r;
                        const bool ok = (kpos <= qrow) & (amr[r] > 0);
                        float p = ok ? exp2f(fmaf(sfr[mi][ni][r], SC2_, -8.0f)) : 0.0f;
                        lsum[mi] += p;
                        sfr[mi][ni][r] = p;
                    }
                }
            }
        }

        // ---- pack P to bf16 A-fragments (pure register, no LDS) ----
        short8 pf[2][2];
        #pragma unroll
        for (int mi = 0; mi < 2; ++mi)
            #pragma unroll
            for (int kc = 0; kc < 2; ++kc) {
                union { u16 w[8]; short8 s8; } u;
                #pragma unroll
                for (int r = 0; r < 4; ++r) {
                    u.w[r]     = f2bf_hw(sfr[mi][kc * 2][r]);
                    u.w[4 + r] = f2bf_hw(sfr[mi][kc * 2 + 1][r]);
                }
                pf[mi][kc] = u.s8;
            }

        // ---- O += P V (V sigma-ordered) ----
        __builtin_amdgcn_s_setprio(1);
        #pragma unroll
        for (int kc = 0; kc < 2; ++kc) {
            #pragma unroll
            for (int dn = 0; dn < 8; ++dn) {
                short8 vf = *(const short8*)&Vs[dn * 16 + l16][((kc * 4 + quad) ^ (l16 & 7)) * 8];
                Oacc[0][dn] = __builtin_amdgcn_mfma_f32_16x16x32_bf16(pf[0][kc], vf, Oacc[0][dn], 0, 0, 0);
                Oacc[1][dn] = __builtin_amdgcn_mfma_f32_16x16x32_bf16(pf[1][kc], vf, Oacc[1][dn], 0, 0, 0);
            }
        }
        __builtin_amdgcn_s_setprio(0);
        __syncthreads();   // Ks/Vs consumed; safe for next DMA stage
    }

    // ---- epilogue: lsum[mi] holds q=l16 partial over this lane's keys ----
    float lr[2];
    #pragma unroll
    for (int mi = 0; mi < 2; ++mi) {
        float v = lsum[mi];
        v += __shfl_xor(v, 16);
        v += __shfl_xor(v, 32);
        lr[mi] = v;                      // all lanes: l for q = mi*16 + l16
    }

    if (pi < 0) {
        // direct write: need linv for Oacc row q = quad*4+r -> bpermute
        #pragma unroll
        for (int mi = 0; mi < 2; ++mi) {
            #pragma unroll
            for (int r = 0; r < 4; ++r) {
                const float linv = 1.0f / __shfl(lr[mi], quad * 4 + r);
                const int qrow = q0 + mi * 16 + quad * 4 + r;
                u16* dst = &Y[(((size_t)b * L_ + qrow) * NH_ + h) * HD_];
                #pragma unroll
                for (int dn = 0; dn < 8; ++dn)
                    dst[dn * 16 + l16] = f2bf(Oacc[mi][dn][r] * linv);
            }
        }
    } else {
        float* od = Opart + ((size_t)pi * 4 + wave) * 32 * 128;
        float* lp = lpart + ((size_t)pi * 4 + wave) * 32;
        #pragma unroll
        for (int mi = 0; mi < 2; ++mi) {
            if (quad == 0)
                __builtin_nontemporal_store(lr[mi], &lp[mi * 16 + l16]);
            #pragma unroll
            for (int r = 0; r < 4; ++r) {
                const int qi = mi * 16 + quad * 4 + r;
                #pragma unroll
                for (int dn = 0; dn < 8; ++dn)
                    __builtin_nontemporal_store(Oacc[mi][dn][r],
                                                &od[(size_t)qi * 128 + dn * 16 + l16]);
            }
        }
    }
}

// ---------------- combine split-tile partials -> final bf16 Y ------------
__global__ __launch_bounds__(256)
void attn_combine(const float* __restrict__ Opart, const float* __restrict__ lpart,
                  u16* __restrict__ Y) {
    const int cb = blockIdx.x;
    const int c  = cb & 255, z = cb >> 8;
    const int tile = z >> 2, hw = z & 3;
    const int bkvh = c & 7, j = c >> 3;
    const int b = bkvh >> 2, kvh = bkvh & 3;
    const int h = kvh * 4 + hw;
    const int H  = ((32 + j) >> 1) + 1;
    const int Lg = ((31 - j) >> 1) + 1;
    const int m2 = max((H + 1) >> 1, (Lg + 1) >> 1);
    const int m3 = max((H + 2) / 3, Lg);
    const int nh = (m2 <= m3) ? 2 : 3;
    const int nl = 4 - nh;
    if (tile == 1 && nl == 1) return;        // direct-written by attn block
    const int s0 = tile ? nh : 0;
    const int ns = tile ? nl : nh;
    const int t  = tile ? (31 - j) : (32 + j);
    const int tid = threadIdx.x;
    const int q = tid >> 3, dg = tid & 7;    // q 0..31, d-block 0..7 (16 floats)

    float4 a0 = {0,0,0,0}, a1 = {0,0,0,0}, a2 = {0,0,0,0}, a3 = {0,0,0,0};
    float lacc = 0.0f;
    for (int i = 0; i < ns; ++i) {
        const size_t rowb = ((size_t)((s0 + i) * 256 + c) * 4 + hw) * 32 + q;
        lacc += lpart[rowb];
        const float4* op = (const float4*)(Opart + rowb * 128 + dg * 16);
        float4 v0 = op[0], v1 = op[1], v2 = op[2], v3 = op[3];
        a0.x += v0.x; a0.y += v0.y; a0.z += v0.z; a0.w += v0.w;
        a1.x += v1.x; a1.y += v1.y; a1.z += v1.z; a1.w += v1.w;
        a2.x += v2.x; a2.y += v2.y; a2.z += v2.z; a2.w += v2.w;
        a3.x += v3.x; a3.y += v3.y; a3.z += v3.z; a3.w += v3.w;
    }
    const float linv = 1.0f / lacc;
    const int qrow = t * 32 + q;
    u16* dst = &Y[(((size_t)b * L_ + qrow) * NH_ + h) * HD_ + dg * 16];

    u16 tmp[16];
    tmp[0]  = f2bf(a0.x * linv); tmp[1]  = f2bf(a0.y * linv);
    tmp[2]  = f2bf(a0.z * linv); tmp[3]  = f2bf(a0.w * linv);
    tmp[4]  = f2bf(a1.x * linv); tmp[5]  = f2bf(a1.y * linv);
    tmp[6]  = f2bf(a1.z * linv); tmp[7]  = f2bf(a1.w * linv);
    tmp[8]  = f2bf(a2.x * linv); tmp[9]  = f2bf(a2.y * linv);
    tmp[10] = f2bf(a2.z * linv); tmp[11] = f2bf(a2.w * linv);
    tmp[12] = f2bf(a3.x * linv); tmp[13] = f2bf(a3.y * linv);
    tmp[14] = f2bf(a3.z * linv); tmp[15] = f2bf(a3.w * linv);
    *(uint4*)(dst)     = *(const uint4*)(&tmp[0]);
    *(uint4*)(dst + 8) = *(const uint4*)(&tmp[8]);
}

// ---------------- launch ----------------
extern "C" void kernel_launch(void* const* d_in, const int* in_sizes, int n_in,
                              void* d_out, int out_size, void* d_ws, size_t ws_size,
                              hipStream_t stream) {
    const float* x  = (const float*)d_in[0];
    const float* Wq = (const float*)d_in[1];
    const float* Wc = (const float*)d_in[2];
    const float* Wk = (const float*)d_in[3];
    const float* Wv = (const float*)d_in[4];
    const float* Wo = (const float*)d_in[5];
    const int* amask = (const int*)d_in[6];
    float* out = (float*)d_out;

    char* p = (char*)d_ws;
    auto alloc = [&](size_t elems) {
        u16* r = (u16*)p;
        p += ((elems * 2 + 255) / 256) * 256;
        return r;
    };
    // --- alive through attention ---
    u16* WoT  = alloc((size_t)2048 * 2048);
    u16* qbuf = alloc((size_t)4096 * 2048);   // pre-rope q; reused as Y
    u16* Qr   = alloc((size_t)4096 * 2048);
    u16* Kr   = alloc((size_t)4096 * 512);
    u16* Vt   = alloc((size_t)4096 * 512);    // [B, NKV, HD, sigma(L)]
    // --- dead once attention starts (Opart overlays this region) ---
    char* pdead = p;
    u16* Xb   = alloc((size_t)4096 * 2048);
    u16* WqT  = alloc((size_t)2048 * 2048);   // NOTE: WqT|WcT adjacent (fused)
    u16* WcT  = alloc((size_t)512 * 2048);
    u16* WkT  = alloc((size_t)512 * 512);     // NOTE: WkT|WvT adjacent (fused)
    u16* WvT  = alloc((size_t)512 * 512);
    u16* cbuf = alloc((size_t)4096 * 512);
    u16* kbuf = alloc((size_t)4096 * 512);
    u16* vbuf = alloc((size_t)4096 * 512);
    float* Opart = (float*)pdead;
    float* lpart = (float*)(pdead + (size_t)1024 * 4 * 32 * 128 * 4);

    // converts
    cvt_kernel<<<8388608 / 4 / 256, 256, 0, stream>>>(x, Xb, 8388608 / 4);
    cvt_transpose_kernel<<<dim3(2048 / 32, 2048 / 32), 256, 0, stream>>>(Wq, WqT, 2048, 2048);
    cvt_transpose_kernel<<<dim3(512 / 32, 2048 / 32), 256, 0, stream>>>(Wc, WcT, 2048, 512);
    cvt_transpose_kernel<<<dim3(512 / 32, 512 / 32), 256, 0, stream>>>(Wk, WkT, 512, 512);
    cvt_transpose_kernel<<<dim3(512 / 32, 512 / 32), 256, 0, stream>>>(Wv, WvT, 512, 512);
    cvt_transpose_kernel<<<dim3(2048 / 32, 2048 / 32), 256, 0, stream>>>(Wo, WoT, 2048, 2048);

    // projections: fused [Wq|Wc] (N=2560) and [Wk|Wv] (N=1024)
    gemm_bt_split<<<dim3(20, 32), 256, 0, stream>>>(Xb, WqT, qbuf, cbuf,
                                                    4096, 2560, 2048, 2048, 2048, 512);
    gemm_bt_split<<<dim3(8, 32), 256, 0, stream>>>(cbuf, WkT, kbuf, vbuf,
                                                   4096, 1024, 512, 512, 512, 512);

    // rope + permute to head-major; V -> [b,kvh,d,sigma(l)]
    rope_perm<<<(2 * 16 * 2048 * 64) / 256, 256, 0, stream>>>(qbuf, Qr, 16, 4);
    rope_perm<<<(2 * 4 * 2048 * 64) / 256, 256, 0, stream>>>(kbuf, Kr, 4, 2);
    transpose_v_kernel<<<dim3(64, 4, 8), 256, 0, stream>>>(vbuf, Vt);

    // attention partials + combine (Y into qbuf, dead after rope)
    attn_mfma<<<dim3(1024), 256, 0, stream>>>(Qr, Kr, Vt, amask, qbuf, Opart, lpart);
    attn_combine<<<dim3(2048), 256, 0, stream>>>(Opart, lpart, qbuf);

    // output projection (fp32 out)
    gemm_bt<0><<<dim3(16, 32), 256, 0, stream>>>(qbuf, WoT, out, 4096, 2048, 2048);
}

// Round 9
// 350.287 us; speedup vs baseline: 1.7336x; 1.0262x over previous
//
#include <hip/hip_runtime.h>
#include <hip/hip_bf16.h>
#include <cstdint>
#include <cstddef>

// Problem constants
#define B_    2
#define L_    2048
#define HID_  2048
#define NH_   16
#define NKV_  4
#define HD_   128
#define LAT_  512
#define SCALE_ 0.08838834764831845f   // 1/sqrt(128)
#define SC2_   0.1275174365f          // SCALE * log2(e)

typedef unsigned short u16;
typedef unsigned int   u32;
typedef __attribute__((ext_vector_type(8))) short   short8;
typedef __attribute__((ext_vector_type(4))) float   floatx4;

typedef __attribute__((address_space(1))) const u32 gas_u32;
typedef __attribute__((address_space(3))) u32       las_u32;

__device__ __forceinline__ void gl_lds16(const u16* g, u16* l) {
    // async global->LDS, 16B/lane; LDS dest = wave-uniform base + lane*16
    __builtin_amdgcn_global_load_lds((gas_u32*)g, (las_u32*)l, 16, 0, 0);
}

__device__ __forceinline__ float bf2f(u16 u) {
    union { u32 i; float f; } v; v.i = ((u32)u) << 16; return v.f;
}
__device__ __forceinline__ u16 f2bf(float f) {
    union { float f; u32 u; } v; v.f = f;
    u32 u = v.u;
    u32 r = (u + 0x7fffu + ((u >> 16) & 1u)) >> 16;   // RNE
    return (u16)r;
}
// HW bf16 cast (compiler fuses pairs into v_cvt_pk_bf16_f32, RNE)
__device__ __forceinline__ u16 f2bf_hw(float f) {
    union { __hip_bfloat16 h; u16 u; } c;
    c.h = __float2bfloat16(f);
    return c.u;
}

// ---------------- fp32 -> bf16 elementwise (x4 vectorized) ----------------
__global__ void cvt_kernel(const float* __restrict__ in, u16* __restrict__ out, int n4) {
    int i = blockIdx.x * 256 + threadIdx.x;
    if (i < n4) {
        float4 v = ((const float4*)in)[i];
        union { u16 w[4]; uint2 v; } o;
        o.w[0] = f2bf(v.x); o.w[1] = f2bf(v.y);
        o.w[2] = f2bf(v.z); o.w[3] = f2bf(v.w);
        ((uint2*)out)[i] = o.v;
    }
}

// ---------------- fp32 [R][C] -> bf16 [C][R], two tensors per launch ------
__global__ void cvt_transpose2_kernel(const float* __restrict__ in0, u16* __restrict__ out0,
                                      const float* __restrict__ in1, u16* __restrict__ out1,
                                      int R, int C) {
    __shared__ u16 tile[32][33];
    const float* in = blockIdx.z ? in1 : in0;
    u16* out = blockIdx.z ? out1 : out0;
    int c0 = blockIdx.x * 32, r0 = blockIdx.y * 32;
    int tx = threadIdx.x & 31, ty = threadIdx.x >> 5;   // ty in 0..7
    for (int i = ty; i < 32; i += 8)
        tile[tx][i] = f2bf(in[(size_t)(r0 + i) * C + c0 + tx]);
    __syncthreads();
    for (int i = ty; i < 32; i += 8)
        out[(size_t)(c0 + i) * R + r0 + tx] = tile[i][tx];
}

// ---------------- bf16 kv[(b,l)][1024] v-half -> [b,kvh,d,sigma(l)] -------
// sigma matches the SWAPPED-QK in-register P layout: for key k (within a
// 64-block) with ni=k>>4, qd=(k>>2)&3, r=k&3, its column position is
// p = ((ni>>1)<<5) | (qd<<3) | ((ni&1)<<2) | r.
__global__ void transpose_v_kernel(const u16* __restrict__ kv, u16* __restrict__ out) {
    __shared__ u16 t[32][33];
    int lt = blockIdx.x, dt = blockIdx.y, bh = blockIdx.z;   // bh = b*NKV + kvh
    int b = bh >> 2, kvh = bh & 3;
    int tx = threadIdx.x & 31, ty = threadIdx.x >> 5;
    for (int i = ty; i < 32; i += 8)
        t[i][tx] = kv[(size_t)(b * L_ + lt * 32 + i) * 1024 + 512 + kvh * HD_ + dt * 32 + tx];
    __syncthreads();
    const int lcol = lt * 32 + tx;
    const int k6 = lcol & 63;
    const int ni = k6 >> 4, qd = (k6 >> 2) & 3, r = k6 & 3;
    const int p = ((ni >> 1) << 5) | (qd << 3) | ((ni & 1) << 2) | r;
    const int csig = (lcol & ~63) | p;
    for (int i = ty; i < 32; i += 8)
        out[((size_t)bh * HD_ + dt * 32 + i) * L_ + csig] = t[tx][i];
}

// ---------------- bf16 GEMM: C[M,N] = A[M,K] * BT[N,K]^T ----------------
// BK=64, XOR-swizzled LDS (swizzle folded into the per-lane DMA SOURCE
// address; LDS dest linear per rule 21). 32 barriers @ K=2048 (was 64),
// conflict-free ds_read_b128 fragments.
template<int OUT_BF16>
__global__ __launch_bounds__(256)
void gemm_bt(const u16* __restrict__ A, const u16* __restrict__ BT,
             void* __restrict__ C, int M, int N, int K) {
    __shared__ __align__(16) u16 As[128][64];
    __shared__ __align__(16) u16 Bs[128][64];
    const int tid  = threadIdx.x;
    const int m0   = blockIdx.y * 128, n0 = blockIdx.x * 128;
    const int wave = tid >> 6, lane = tid & 63;
    const int wm   = (wave >> 1) * 64, wn = (wave & 1) * 64;
    const int quad = lane >> 4, l16 = lane & 15;

    // staging: per wave 4 segments of 1KB (8 rows) per matrix.
    // lane l -> row seg*8+(l>>3), LDS chunk (l&7); source chunk (l&7)^(l>>3)
    // so that LDS chunk c of row r holds global chunk c^(r&7).
    const int r8 = lane >> 3, srcc = ((lane & 7) ^ r8) * 8;
    const u16* ap[4]; const u16* bp[4];
    u16 *la[4], *lb[4];
    #pragma unroll
    for (int cc = 0; cc < 4; ++cc) {
        const int seg = wave * 4 + cc;
        const int row = seg * 8 + r8;
        ap[cc] = A  + (size_t)(m0 + row) * K + srcc;
        bp[cc] = BT + (size_t)(n0 + row) * K + srcc;
        la[cc] = &As[0][0] + seg * 512;
        lb[cc] = &Bs[0][0] + seg * 512;
    }

    floatx4 acc[4][4] = {};

    for (int k0 = 0; k0 < K; k0 += 64) {
        #pragma unroll
        for (int cc = 0; cc < 4; ++cc) {
            gl_lds16(ap[cc] + k0, la[cc]);
            gl_lds16(bp[cc] + k0, lb[cc]);
        }
        __syncthreads();

        short8 af[4][2], bfr[4][2];
        #pragma unroll
        for (int i = 0; i < 4; i++) {
            const int ra = wm + i * 16 + l16, rb = wn + i * 16 + l16;
            #pragma unroll
            for (int kk = 0; kk < 2; kk++) {
                af[i][kk]  = *(const short8*)&As[ra][((kk * 4 + quad) ^ (l16 & 7)) * 8];
                bfr[i][kk] = *(const short8*)&Bs[rb][((kk * 4 + quad) ^ (l16 & 7)) * 8];
            }
        }
        #pragma unroll
        for (int kk = 0; kk < 2; kk++)
            #pragma unroll
            for (int mi = 0; mi < 4; mi++)
                #pragma unroll
                for (int ni = 0; ni < 4; ni++)
                    acc[mi][ni] = __builtin_amdgcn_mfma_f32_16x16x32_bf16(
                        af[mi][kk], bfr[ni][kk], acc[mi][ni], 0, 0, 0);
        __syncthreads();
    }

    #pragma unroll
    for (int mi = 0; mi < 4; mi++) {
        #pragma unroll
        for (int ni = 0; ni < 4; ni++) {
            #pragma unroll
            for (int r = 0; r < 4; r++) {
                int row = m0 + wm + mi * 16 + quad * 4 + r;
                int col = n0 + wn + ni * 16 + l16;
                float v = acc[mi][ni][r];
                if (OUT_BF16) ((u16*)C)[(size_t)row * N + col] = f2bf(v);
                else          ((float*)C)[(size_t)row * N + col] = v;
            }
        }
    }
}

// ---- same GEMM, bf16 out, fused [B0|B1] N-stack (Nsplit % 128 == 0) ----
__global__ __launch_bounds__(256)
void gemm_bt_split(const u16* __restrict__ A, const u16* __restrict__ BT,
                   u16* __restrict__ C0, u16* __restrict__ C1,
                   int M, int N, int K, int Nsplit, int N0, int N1) {
    __shared__ __align__(16) u16 As[128][64];
    __shared__ __align__(16) u16 Bs[128][64];
    const int tid  = threadIdx.x;
    const int m0   = blockIdx.y * 128, n0 = blockIdx.x * 128;
    const int wave = tid >> 6, lane = tid & 63;
    const int wm   = (wave >> 1) * 64, wn = (wave & 1) * 64;
    const int quad = lane >> 4, l16 = lane & 15;

    const int r8 = lane >> 3, srcc = ((lane & 7) ^ r8) * 8;
    const u16* ap[4]; const u16* bp[4];
    u16 *la[4], *lb[4];
    #pragma unroll
    for (int cc = 0; cc < 4; ++cc) {
        const int seg = wave * 4 + cc;
        const int row = seg * 8 + r8;
        ap[cc] = A  + (size_t)(m0 + row) * K + srcc;
        bp[cc] = BT + (size_t)(n0 + row) * K + srcc;
        la[cc] = &As[0][0] + seg * 512;
        lb[cc] = &Bs[0][0] + seg * 512;
    }

    floatx4 acc[4][4] = {};

    for (int k0 = 0; k0 < K; k0 += 64) {
        #pragma unroll
        for (int cc = 0; cc < 4; ++cc) {
            gl_lds16(ap[cc] + k0, la[cc]);
            gl_lds16(bp[cc] + k0, lb[cc]);
        }
        __syncthreads();

        short8 af[4][2], bfr[4][2];
        #pragma unroll
        for (int i = 0; i < 4; i++) {
            const int ra = wm + i * 16 + l16, rb = wn + i * 16 + l16;
            #pragma unroll
            for (int kk = 0; kk < 2; kk++) {
                af[i][kk]  = *(const short8*)&As[ra][((kk * 4 + quad) ^ (l16 & 7)) * 8];
                bfr[i][kk] = *(const short8*)&Bs[rb][((kk * 4 + quad) ^ (l16 & 7)) * 8];
            }
        }
        #pragma unroll
        for (int kk = 0; kk < 2; kk++)
            #pragma unroll
            for (int mi = 0; mi < 4; mi++)
                #pragma unroll
                for (int ni = 0; ni < 4; ni++)
                    acc[mi][ni] = __builtin_amdgcn_mfma_f32_16x16x32_bf16(
                        af[mi][kk], bfr[ni][kk], acc[mi][ni], 0, 0, 0);
        __syncthreads();
    }

    const int side = (n0 >= Nsplit);
    u16* Cw = side ? C1 : C0;
    const int nw = side ? N1 : N0;
    const int cbase = side ? Nsplit : 0;

    #pragma unroll
    for (int mi = 0; mi < 4; mi++) {
        #pragma unroll
        for (int ni = 0; ni < 4; ni++) {
            #pragma unroll
            for (int r = 0; r < 4; r++) {
                int row = m0 + wm + mi * 16 + quad * 4 + r;
                int col = n0 + wn + ni * 16 + l16 - cbase;
                Cw[(size_t)row * nw + col] = f2bf(acc[mi][ni][r]);
            }
        }
    }
}

// ---------------- RoPE + head-major permute (src row stride rs) ----------
__global__ void rope_perm(const u16* __restrict__ in, u16* __restrict__ out,
                          int nh, int nhbits, int rs) {
    int idx = blockIdx.x * 256 + threadIdx.x;   // one thread per (b,h,l,d<64)
    int d = idx & 63;
    int l = (idx >> 6) & (L_ - 1);
    int h = (idx >> 17) & (nh - 1);
    int b = idx >> (17 + nhbits);
    const u16* src = &in[(size_t)(b * L_ + l) * rs + h * HD_];
    u16* dst = &out[(((size_t)b * nh + h) * L_ + l) * HD_];
    float t1 = bf2f(src[d]), t2 = bf2f(src[d + 64]);
    float inv = expf(-(float)d * 0.14391156831212787f);  // ln(10000)/64
    float fr = (float)l * inv;
    float c = cosf(fr), sn = sinf(fr);
    dst[d]      = f2bf(t1 * c - t2 * sn);
    dst[d + 64] = f2bf(t2 * c + t1 * sn);
}

// ---------------- MFMA flash attention (unchanged from R8) ---------------
// Swapped QK^T (P in-register), DMA staging w/ pre-swizzled source,
// grid 1024 = 4 balanced chunks per (bkvh,j), fp32 NT partials + combine.
__global__ __launch_bounds__(256)
void attn_mfma(const u16* __restrict__ Q, const u16* __restrict__ K,
               const u16* __restrict__ Vt, const int* __restrict__ amask,
               u16* __restrict__ Y, float* __restrict__ Opart,
               float* __restrict__ lpart) {
    __shared__ __align__(16) u16 Ks[64][128];    // 16 KB
    __shared__ __align__(16) u16 Vs[128][64];    // 16 KB (sigma-ordered k)

    const int tid  = threadIdx.x;
    const int wave = tid >> 6, lane = tid & 63;
    const int quad = lane >> 4, l16 = lane & 15;

    const int bid = blockIdx.x;
    const int s   = bid >> 8;                // 0..3 chunk slot
    const int c   = bid & 255;
    const int bkvh = c & 7;                  // XCD-affine: bid%8 -> XCD
    const int j   = c >> 3;                  // 0..31
    const int b   = bkvh >> 2, kvh = bkvh & 3;

    const int H  = ((32 + j) >> 1) + 1;      // heavy tile key-tiles (17..32)
    const int Lg = ((31 - j) >> 1) + 1;      // light tile key-tiles (1..16)
    const int m2 = max((H + 1) >> 1, (Lg + 1) >> 1);
    const int m3 = max((H + 2) / 3, Lg);
    const int nh = (m2 <= m3) ? 2 : 3;
    const int nl = 4 - nh;
    int t, kt0, kt1, pi;
    if (s < nh) {
        t = 32 + j; kt0 = (H * s) / nh; kt1 = (H * (s + 1)) / nh; pi = bid;
    } else {
        t = 31 - j;
        const int ls = s - nh;
        kt0 = (Lg * ls) / nl; kt1 = (Lg * (ls + 1)) / nl;
        pi = (nl == 1) ? -1 : bid;           // whole light tile -> direct write
    }

    const int h   = kvh * 4 + wave;          // wave = head
    const int q0  = t * 32;

    const u16* Qbase = Q  + ((size_t)b * NH_  + h)   * L_ * HD_;
    const u16* Kbase = K  + ((size_t)b * NKV_ + kvh) * L_ * HD_;
    const u16* Vbase = Vt + ((size_t)b * NKV_ + kvh) * (size_t)HD_ * L_;
    const int* mbase = amask + b * L_;

    short8 qa[2][4];
    #pragma unroll
    for (int mi = 0; mi < 2; ++mi)
        #pragma unroll
        for (int ks = 0; ks < 4; ++ks)
            qa[mi][ks] = *(const short8*)&Qbase[(size_t)(q0 + mi * 16 + l16) * HD_ + ks * 32 + quad * 8];

    floatx4 Oacc[2][8] = {};
    float lsum[2] = {0.0f, 0.0f};

    const int slK = lane & 15, rKl = lane >> 4;
    const int slV = lane & 7,  rVl = lane >> 3;
    int okg[4], ovg[4];
    u16 *klds[4], *vlds[4];
    #pragma unroll
    for (int cc = 0; cc < 4; ++cc) {
        const int seg = wave * 4 + cc;
        const int rk = seg * 4 + rKl;
        okg[cc] = rk * HD_ + ((slK ^ (rk & 7)) * 8);
        klds[cc] = (u16*)Ks + seg * 512;
        const int rv = seg * 8 + rVl;
        ovg[cc] = rv * L_ + ((slV ^ (rv & 7)) * 8);
        vlds[cc] = (u16*)Vs + seg * 512;
    }
    const u16* kgb = Kbase + (size_t)kt0 * 64 * HD_;
    const u16* vgb = Vbase + kt0 * 64;

    for (int kt = kt0; kt < kt1; ++kt) {
        const int kbase = kt * 64;

        #pragma unroll
        for (int cc = 0; cc < 4; ++cc) {
            gl_lds16(kgb + okg[cc], klds[cc]);
            gl_lds16(vgb + ovg[cc], vlds[cc]);
        }
        const int am_l = mbase[kbase + lane];
        const bool allm = __all(am_l > 0);
        kgb += (size_t)64 * HD_;
        vgb += 64;
        __syncthreads();

        // ---- S^T = K Q^T (swapped): col=l16 -> q, row=quad*4+r -> key ----
        floatx4 sfr[2][4] = {};
        __builtin_amdgcn_s_setprio(1);
        #pragma unroll
        for (int ni = 0; ni < 4; ++ni) {
            #pragma unroll
            for (int ks = 0; ks < 4; ++ks) {
                short8 kf = *(const short8*)&Ks[ni * 16 + l16][((ks * 4 + quad) ^ (l16 & 7)) * 8];
                sfr[0][ni] = __builtin_amdgcn_mfma_f32_16x16x32_bf16(kf, qa[0][ks], sfr[0][ni], 0, 0, 0);
                sfr[1][ni] = __builtin_amdgcn_mfma_f32_16x16x32_bf16(kf, qa[1][ks], sfr[1][ni], 0, 0, 0);
            }
        }
        __builtin_amdgcn_s_setprio(0);

        if (allm & (kbase + 63 <= q0)) {
            #pragma unroll
            for (int mi = 0; mi < 2; ++mi)
                #pragma unroll
                for (int ni = 0; ni < 4; ++ni)
                    #pragma unroll
                    for (int r = 0; r < 4; ++r) {
                        float p = exp2f(fmaf(sfr[mi][ni][r], SC2_, -8.0f));
                        lsum[mi] += p;
                        sfr[mi][ni][r] = p;
                    }
        } else {
            #pragma unroll
            for (int ni = 0; ni < 4; ++ni) {
                const int4 amv = *(const int4*)&mbase[kbase + ni * 16 + quad * 4];
                const int amr[4] = {amv.x, amv.y, amv.z, amv.w};
                #pragma unroll
                for (int mi = 0; mi < 2; ++mi) {
                    const int qrow = q0 + mi * 16 + l16;
                    #pragma unroll
                    for (int r = 0; r < 4; ++r) {
                        const int kpos = kbase + ni * 16 + quad * 4 + r;
                        const bool ok = (kpos <= qrow) & (amr[r] > 0);
                        float p = ok ? exp2f(fmaf(sfr[mi][ni][r], SC2_, -8.0f)) : 0.0f;
                        lsum[mi] += p;
                        sfr[mi][ni][r] = p;
                    }
                }
            }
        }

        short8 pf[2][2];
        #pragma unroll
        for (int mi = 0; mi < 2; ++mi)
            #pragma unroll
            for (int kc = 0; kc < 2; ++kc) {
                union { u16 w[8]; short8 s8; } u;
                #pragma unroll
                for (int r = 0; r < 4; ++r) {
                    u.w[r]     = f2bf_hw(sfr[mi][kc * 2][r]);
                    u.w[4 + r] = f2bf_hw(sfr[mi][kc * 2 + 1][r]);
                }
                pf[mi][kc] = u.s8;
            }

        __builtin_amdgcn_s_setprio(1);
        #pragma unroll
        for (int kc = 0; kc < 2; ++kc) {
            #pragma unroll
            for (int dn = 0; dn < 8; ++dn) {
                short8 vf = *(const short8*)&Vs[dn * 16 + l16][((kc * 4 + quad) ^ (l16 & 7)) * 8];
                Oacc[0][dn] = __builtin_amdgcn_mfma_f32_16x16x32_bf16(pf[0][kc], vf, Oacc[0][dn], 0, 0, 0);
                Oacc[1][dn] = __builtin_amdgcn_mfma_f32_16x16x32_bf16(pf[1][kc], vf, Oacc[1][dn], 0, 0, 0);
            }
        }
        __builtin_amdgcn_s_setprio(0);
        __syncthreads();
    }

    float lr[2];
    #pragma unroll
    for (int mi = 0; mi < 2; ++mi) {
        float v = lsum[mi];
        v += __shfl_xor(v, 16);
        v += __shfl_xor(v, 32);
        lr[mi] = v;
    }

    if (pi < 0) {
        #pragma unroll
        for (int mi = 0; mi < 2; ++mi) {
            #pragma unroll
            for (int r = 0; r < 4; ++r) {
                const float linv = 1.0f / __shfl(lr[mi], quad * 4 + r);
                const int qrow = q0 + mi * 16 + quad * 4 + r;
                u16* dst = &Y[(((size_t)b * L_ + qrow) * NH_ + h) * HD_];
                #pragma unroll
                for (int dn = 0; dn < 8; ++dn)
                    dst[dn * 16 + l16] = f2bf(Oacc[mi][dn][r] * linv);
            }
        }
    } else {
        float* od = Opart + ((size_t)pi * 4 + wave) * 32 * 128;
        float* lp = lpart + ((size_t)pi * 4 + wave) * 32;
        #pragma unroll
        for (int mi = 0; mi < 2; ++mi) {
            if (quad == 0)
                __builtin_nontemporal_store(lr[mi], &lp[mi * 16 + l16]);
            #pragma unroll
            for (int r = 0; r < 4; ++r) {
                const int qi = mi * 16 + quad * 4 + r;
                #pragma unroll
                for (int dn = 0; dn < 8; ++dn)
                    __builtin_nontemporal_store(Oacc[mi][dn][r],
                                                &od[(size_t)qi * 128 + dn * 16 + l16]);
            }
        }
    }
}

// ---------------- combine split-tile partials -> final bf16 Y ------------
__global__ __launch_bounds__(256)
void attn_combine(const float* __restrict__ Opart, const float* __restrict__ lpart,
                  u16* __restrict__ Y) {
    const int cb = blockIdx.x;
    const int c  = cb & 255, z = cb >> 8;
    const int tile = z >> 2, hw = z & 3;
    const int bkvh = c & 7, j = c >> 3;
    const int b = bkvh >> 2, kvh = bkvh & 3;
    const int h = kvh * 4 + hw;
    const int H  = ((32 + j) >> 1) + 1;
    const int Lg = ((31 - j) >> 1) + 1;
    const int m2 = max((H + 1) >> 1, (Lg + 1) >> 1);
    const int m3 = max((H + 2) / 3, Lg);
    const int nh = (m2 <= m3) ? 2 : 3;
    const int nl = 4 - nh;
    if (tile == 1 && nl == 1) return;        // direct-written by attn block
    const int s0 = tile ? nh : 0;
    const int ns = tile ? nl : nh;
    const int t  = tile ? (31 - j) : (32 + j);
    const int tid = threadIdx.x;
    const int q = tid >> 3, dg = tid & 7;    // q 0..31, d-block 0..7 (16 floats)

    float4 a0 = {0,0,0,0}, a1 = {0,0,0,0}, a2 = {0,0,0,0}, a3 = {0,0,0,0};
    float lacc = 0.0f;
    for (int i = 0; i < ns; ++i) {
        const size_t rowb = ((size_t)((s0 + i) * 256 + c) * 4 + hw) * 32 + q;
        lacc += lpart[rowb];
        const float4* op = (const float4*)(Opart + rowb * 128 + dg * 16);
        float4 v0 = op[0], v1 = op[1], v2 = op[2], v3 = op[3];
        a0.x += v0.x; a0.y += v0.y; a0.z += v0.z; a0.w += v0.w;
        a1.x += v1.x; a1.y += v1.y; a1.z += v1.z; a1.w += v1.w;
        a2.x += v2.x; a2.y += v2.y; a2.z += v2.z; a2.w += v2.w;
        a3.x += v3.x; a3.y += v3.y; a3.z += v3.z; a3.w += v3.w;
    }
    const float linv = 1.0f / lacc;
    const int qrow = t * 32 + q;
    u16* dst = &Y[(((size_t)b * L_ + qrow) * NH_ + h) * HD_ + dg * 16];

    u16 tmp[16];
    tmp[0]  = f2bf(a0.x * linv); tmp[1]  = f2bf(a0.y * linv);
    tmp[2]  = f2bf(a0.z * linv); tmp[3]  = f2bf(a0.w * linv);
    tmp[4]  = f2bf(a1.x * linv); tmp[5]  = f2bf(a1.y * linv);
    tmp[6]  = f2bf(a1.z * linv); tmp[7]  = f2bf(a1.w * linv);
    tmp[8]  = f2bf(a2.x * linv); tmp[9]  = f2bf(a2.y * linv);
    tmp[10] = f2bf(a2.z * linv); tmp[11] = f2bf(a2.w * linv);
    tmp[12] = f2bf(a3.x * linv); tmp[13] = f2bf(a3.y * linv);
    tmp[14] = f2bf(a3.z * linv); tmp[15] = f2bf(a3.w * linv);
    *(uint4*)(dst)     = *(const uint4*)(&tmp[0]);
    *(uint4*)(dst + 8) = *(const uint4*)(&tmp[8]);
}

// ---------------- launch ----------------
extern "C" void kernel_launch(void* const* d_in, const int* in_sizes, int n_in,
                              void* d_out, int out_size, void* d_ws, size_t ws_size,
                              hipStream_t stream) {
    const float* x  = (const float*)d_in[0];
    const float* Wq = (const float*)d_in[1];
    const float* Wc = (const float*)d_in[2];
    const float* Wk = (const float*)d_in[3];
    const float* Wv = (const float*)d_in[4];
    const float* Wo = (const float*)d_in[5];
    const int* amask = (const int*)d_in[6];
    float* out = (float*)d_out;

    char* p = (char*)d_ws;
    auto alloc = [&](size_t elems) {
        u16* r = (u16*)p;
        p += ((elems * 2 + 255) / 256) * 256;
        return r;
    };
    // --- alive through attention ---
    u16* WoT  = alloc((size_t)2048 * 2048);
    u16* qbuf = alloc((size_t)4096 * 2048);   // q proj; reused as Y
    u16* Qr   = alloc((size_t)4096 * 2048);
    u16* Kr   = alloc((size_t)4096 * 512);
    u16* Vt   = alloc((size_t)4096 * 512);    // [B, NKV, HD, sigma(L)]
    // --- dead once attention starts (Opart overlays this region) ---
    char* pdead = p;
    u16* WqT  = alloc((size_t)2048 * 2048);   // [WqT|WckvT] must be adjacent
    u16* WckvT= alloc((size_t)1024 * 2048);   // fused (Wc@Wk)^T ; (Wc@Wv)^T
    u16* WkT  = alloc((size_t)512 * 512);     // [WkT|WvT] adjacent (stacked A)
    u16* WvT  = alloc((size_t)512 * 512);
    u16* Wcb  = alloc((size_t)2048 * 512);    // Wc as bf16, non-transposed
    u16* Xb   = alloc((size_t)4096 * 2048);
    u16* kvbuf= alloc((size_t)4096 * 1024);   // [k(512) | v(512)] per token
    float* Opart = (float*)pdead;
    float* lpart = (float*)(pdead + (size_t)1024 * 4 * 32 * 128 * 4);

    // converts
    cvt_kernel<<<8388608 / 4 / 256, 256, 0, stream>>>(x, Xb, 8388608 / 4);
    cvt_kernel<<<(2048 * 512 / 4) / 256, 256, 0, stream>>>(Wc, Wcb, 2048 * 512 / 4);
    cvt_transpose2_kernel<<<dim3(64, 64, 2), 256, 0, stream>>>(Wq, WqT, Wo, WoT, 2048, 2048);
    cvt_transpose2_kernel<<<dim3(16, 16, 2), 256, 0, stream>>>(Wk, WkT, Wv, WvT, 512, 512);

    // weight fusion: WckvT[1024x2048] = [WkT;WvT] @ Wcb^T-form (2.1 GF)
    gemm_bt<1><<<dim3(16, 8), 256, 0, stream>>>(WkT, Wcb, WckvT, 1024, 2048, 512);

    // mega projection: [q|k|v] = Xb @ [WqT|WckvT]^T, N=3072, 768 blocks
    // = exactly 3 blocks/CU, all-resident, no tail.
    gemm_bt_split<<<dim3(24, 32), 256, 0, stream>>>(Xb, WqT, qbuf, kvbuf,
                                                    4096, 3072, 2048, 2048, 2048, 1024);

    // rope + permute to head-major; V -> [b,kvh,d,sigma(l)]
    rope_perm<<<(2 * 16 * 2048 * 64) / 256, 256, 0, stream>>>(qbuf, Qr, 16, 4, 2048);
    rope_perm<<<(2 * 4 * 2048 * 64) / 256, 256, 0, stream>>>(kvbuf, Kr, 4, 2, 1024);
    transpose_v_kernel<<<dim3(64, 4, 8), 256, 0, stream>>>(kvbuf, Vt);

    // attention partials + combine (Y into qbuf, dead after rope)
    attn_mfma<<<dim3(1024), 256, 0, stream>>>(Qr, Kr, Vt, amask, qbuf, Opart, lpart);
    attn_combine<<<dim3(2048), 256, 0, stream>>>(Opart, lpart, qbuf);

    // output projection (fp32 out)
    gemm_bt<0><<<dim3(16, 32), 256, 0, stream>>>(qbuf, WoT, out, 4096, 2048, 2048);
}

// Round 10
// 342.317 us; speedup vs baseline: 1.7740x; 1.0233x over previous
//
#include <hip/hip_runtime.h>
#include <hip/hip_bf16.h>
#include <cstdint>
#include <cstddef>

// Problem constants
#define B_    2
#define L_    2048
#define HID_  2048
#define NH_   16
#define NKV_  4
#define HD_   128
#define LAT_  512
#define SCALE_ 0.08838834764831845f   // 1/sqrt(128)
#define SC2_   0.1275174365f          // SCALE * log2(e)

typedef unsigned short u16;
typedef unsigned int   u32;
typedef __attribute__((ext_vector_type(8))) short   short8;
typedef __attribute__((ext_vector_type(4))) float   floatx4;

typedef __attribute__((address_space(1))) const u32 gas_u32;
typedef __attribute__((address_space(3))) u32       las_u32;

__device__ __forceinline__ void gl_lds16(const u16* g, u16* l) {
    // async global->LDS, 16B/lane; LDS dest = wave-uniform base + lane*16
    __builtin_amdgcn_global_load_lds((gas_u32*)g, (las_u32*)l, 16, 0, 0);
}

__device__ __forceinline__ float bf2f(u16 u) {
    union { u32 i; float f; } v; v.i = ((u32)u) << 16; return v.f;
}
__device__ __forceinline__ u16 f2bf(float f) {
    union { float f; u32 u; } v; v.f = f;
    u32 u = v.u;
    u32 r = (u + 0x7fffu + ((u >> 16) & 1u)) >> 16;   // RNE
    return (u16)r;
}
// HW bf16 cast (compiler fuses pairs into v_cvt_pk_bf16_f32, RNE)
__device__ __forceinline__ u16 f2bf_hw(float f) {
    union { __hip_bfloat16 h; u16 u; } c;
    c.h = __float2bfloat16(f);
    return c.u;
}

// ---------------- fp32 -> bf16 elementwise (x4 vectorized) ----------------
__global__ void cvt_kernel(const float* __restrict__ in, u16* __restrict__ out, int n4) {
    int i = blockIdx.x * 256 + threadIdx.x;
    if (i < n4) {
        float4 v = ((const float4*)in)[i];
        union { u16 w[4]; uint2 v; } o;
        o.w[0] = f2bf(v.x); o.w[1] = f2bf(v.y);
        o.w[2] = f2bf(v.z); o.w[3] = f2bf(v.w);
        ((uint2*)out)[i] = o.v;
    }
}

// ---------------- fp32 [R][C] -> bf16 [C][R], two tensors per launch ------
__global__ void cvt_transpose2_kernel(const float* __restrict__ in0, u16* __restrict__ out0,
                                      const float* __restrict__ in1, u16* __restrict__ out1,
                                      int R, int C) {
    __shared__ u16 tile[32][33];
    const float* in = blockIdx.z ? in1 : in0;
    u16* out = blockIdx.z ? out1 : out0;
    int c0 = blockIdx.x * 32, r0 = blockIdx.y * 32;
    int tx = threadIdx.x & 31, ty = threadIdx.x >> 5;   // ty in 0..7
    for (int i = ty; i < 32; i += 8)
        tile[tx][i] = f2bf(in[(size_t)(r0 + i) * C + c0 + tx]);
    __syncthreads();
    for (int i = ty; i < 32; i += 8)
        out[(size_t)(c0 + i) * R + r0 + tx] = tile[i][tx];
}

// ---------------- bf16 kv[(b,l)][1024] v-half -> [b,kvh,d,sigma(l)] -------
// sigma matches the SWAPPED-QK in-register P layout: for key k (within a
// 64-block) with ni=k>>4, qd=(k>>2)&3, r=k&3, its column position is
// p = ((ni>>1)<<5) | (qd<<3) | ((ni&1)<<2) | r.
__global__ void transpose_v_kernel(const u16* __restrict__ kv, u16* __restrict__ out) {
    __shared__ u16 t[32][33];
    int lt = blockIdx.x, dt = blockIdx.y, bh = blockIdx.z;   // bh = b*NKV + kvh
    int b = bh >> 2, kvh = bh & 3;
    int tx = threadIdx.x & 31, ty = threadIdx.x >> 5;
    for (int i = ty; i < 32; i += 8)
        t[i][tx] = kv[(size_t)(b * L_ + lt * 32 + i) * 1024 + 512 + kvh * HD_ + dt * 32 + tx];
    __syncthreads();
    const int lcol = lt * 32 + tx;
    const int k6 = lcol & 63;
    const int ni = k6 >> 4, qd = (k6 >> 2) & 3, r = k6 & 3;
    const int p = ((ni >> 1) << 5) | (qd << 3) | ((ni & 1) << 2) | r;
    const int csig = (lcol & ~63) | p;
    for (int i = ty; i < 32; i += 8)
        out[((size_t)bh * HD_ + dt * 32 + i) * L_ + csig] = t[tx][i];
}

// ---------------- bf16 GEMM: C[M,N] = A[M,K] * BT[N,K]^T ----------------
// BK=64, XOR-swizzled LDS (swizzle folded into the per-lane DMA SOURCE
// address; LDS dest linear per rule 21). kk-SPLIT inner loop (R9 lesson):
// only 32 fragment VGPRs live at once (af[4]+bfr[4] per kk), not 64 --
// R9's kk-unrolled form pushed unified regs to ~152 -> <=2 blocks/CU ->
// DMA drain exposed (MfmaUtil 25%). Target: 4 waves/SIMD residency.
template<int OUT_BF16>
__global__ __launch_bounds__(256)
void gemm_bt(const u16* __restrict__ A, const u16* __restrict__ BT,
             void* __restrict__ C, int M, int N, int K) {
    __shared__ __align__(16) u16 As[128][64];
    __shared__ __align__(16) u16 Bs[128][64];
    const int tid  = threadIdx.x;
    const int m0   = blockIdx.y * 128, n0 = blockIdx.x * 128;
    const int wave = tid >> 6, lane = tid & 63;
    const int wm   = (wave >> 1) * 64, wn = (wave & 1) * 64;
    const int quad = lane >> 4, l16 = lane & 15;

    // staging: per wave 4 segments of 1KB (8 rows) per matrix.
    // lane l -> row seg*8+(l>>3), LDS chunk (l&7); source chunk (l&7)^(l>>3)
    // so that LDS chunk c of row r holds global chunk c^(r&7).
    const int r8 = lane >> 3, srcc = ((lane & 7) ^ r8) * 8;
    const int row0 = wave * 32 + r8;         // + cc*8
    const u16* aBase = A  + (size_t)(m0 + row0) * K + srcc;
    const u16* bBase = BT + (size_t)(n0 + row0) * K + srcc;
    u16* laBase = &As[0][0] + wave * 2048;   // + cc*512
    u16* lbBase = &Bs[0][0] + wave * 2048;

    floatx4 acc[4][4] = {};

    for (int k0 = 0; k0 < K; k0 += 64) {
        #pragma unroll
        for (int cc = 0; cc < 4; ++cc) {
            gl_lds16(aBase + (size_t)cc * 8 * K + k0, laBase + cc * 512);
            gl_lds16(bBase + (size_t)cc * 8 * K + k0, lbBase + cc * 512);
        }
        __syncthreads();

        #pragma unroll
        for (int kk = 0; kk < 2; kk++) {
            short8 af[4], bfr[4];
            const int co = ((kk * 4 + quad) ^ (l16 & 7)) * 8;
            #pragma unroll
            for (int i = 0; i < 4; i++) {
                af[i]  = *(const short8*)&As[wm + i * 16 + l16][co];
                bfr[i] = *(const short8*)&Bs[wn + i * 16 + l16][co];
            }
            #pragma unroll
            for (int mi = 0; mi < 4; mi++)
                #pragma unroll
                for (int ni = 0; ni < 4; ni++)
                    acc[mi][ni] = __builtin_amdgcn_mfma_f32_16x16x32_bf16(
                        af[mi], bfr[ni], acc[mi][ni], 0, 0, 0);
        }
        __syncthreads();
    }

    #pragma unroll
    for (int mi = 0; mi < 4; mi++) {
        #pragma unroll
        for (int ni = 0; ni < 4; ni++) {
            #pragma unroll
            for (int r = 0; r < 4; r++) {
                int row = m0 + wm + mi * 16 + quad * 4 + r;
                int col = n0 + wn + ni * 16 + l16;
                float v = acc[mi][ni][r];
                if (OUT_BF16) ((u16*)C)[(size_t)row * N + col] = f2bf(v);
                else          ((float*)C)[(size_t)row * N + col] = v;
            }
        }
    }
}

// ---- same GEMM, bf16 out, fused [B0|B1] N-stack (Nsplit % 128 == 0) ----
__global__ __launch_bounds__(256)
void gemm_bt_split(const u16* __restrict__ A, const u16* __restrict__ BT,
                   u16* __restrict__ C0, u16* __restrict__ C1,
                   int M, int N, int K, int Nsplit, int N0, int N1) {
    __shared__ __align__(16) u16 As[128][64];
    __shared__ __align__(16) u16 Bs[128][64];
    const int tid  = threadIdx.x;
    const int m0   = blockIdx.y * 128, n0 = blockIdx.x * 128;
    const int wave = tid >> 6, lane = tid & 63;
    const int wm   = (wave >> 1) * 64, wn = (wave & 1) * 64;
    const int quad = lane >> 4, l16 = lane & 15;

    const int r8 = lane >> 3, srcc = ((lane & 7) ^ r8) * 8;
    const int row0 = wave * 32 + r8;
    const u16* aBase = A  + (size_t)(m0 + row0) * K + srcc;
    const u16* bBase = BT + (size_t)(n0 + row0) * K + srcc;
    u16* laBase = &As[0][0] + wave * 2048;
    u16* lbBase = &Bs[0][0] + wave * 2048;

    floatx4 acc[4][4] = {};

    for (int k0 = 0; k0 < K; k0 += 64) {
        #pragma unroll
        for (int cc = 0; cc < 4; ++cc) {
            gl_lds16(aBase + (size_t)cc * 8 * K + k0, laBase + cc * 512);
            gl_lds16(bBase + (size_t)cc * 8 * K + k0, lbBase + cc * 512);
        }
        __syncthreads();

        #pragma unroll
        for (int kk = 0; kk < 2; kk++) {
            short8 af[4], bfr[4];
            const int co = ((kk * 4 + quad) ^ (l16 & 7)) * 8;
            #pragma unroll
            for (int i = 0; i < 4; i++) {
                af[i]  = *(const short8*)&As[wm + i * 16 + l16][co];
                bfr[i] = *(const short8*)&Bs[wn + i * 16 + l16][co];
            }
            #pragma unroll
            for (int mi = 0; mi < 4; mi++)
                #pragma unroll
                for (int ni = 0; ni < 4; ni++)
                    acc[mi][ni] = __builtin_amdgcn_mfma_f32_16x16x32_bf16(
                        af[mi], bfr[ni], acc[mi][ni], 0, 0, 0);
        }
        __syncthreads();
    }

    const int side = (n0 >= Nsplit);
    u16* Cw = side ? C1 : C0;
    const int nw = side ? N1 : N0;
    const int cbase = side ? Nsplit : 0;

    #pragma unroll
    for (int mi = 0; mi < 4; mi++) {
        #pragma unroll
        for (int ni = 0; ni < 4; ni++) {
            #pragma unroll
            for (int r = 0; r < 4; r++) {
                int row = m0 + wm + mi * 16 + quad * 4 + r;
                int col = n0 + wn + ni * 16 + l16 - cbase;
                Cw[(size_t)row * nw + col] = f2bf(acc[mi][ni][r]);
            }
        }
    }
}

// ---------------- RoPE + head-major permute (src row stride rs) ----------
__global__ void rope_perm(const u16* __restrict__ in, u16* __restrict__ out,
                          int nh, int nhbits, int rs) {
    int idx = blockIdx.x * 256 + threadIdx.x;   // one thread per (b,h,l,d<64)
    int d = idx & 63;
    int l = (idx >> 6) & (L_ - 1);
    int h = (idx >> 17) & (nh - 1);
    int b = idx >> (17 + nhbits);
    const u16* src = &in[(size_t)(b * L_ + l) * rs + h * HD_];
    u16* dst = &out[(((size_t)b * nh + h) * L_ + l) * HD_];
    float t1 = bf2f(src[d]), t2 = bf2f(src[d + 64]);
    float inv = expf(-(float)d * 0.14391156831212787f);  // ln(10000)/64
    float fr = (float)l * inv;
    float c = cosf(fr), sn = sinf(fr);
    dst[d]      = f2bf(t1 * c - t2 * sn);
    dst[d + 64] = f2bf(t2 * c + t1 * sn);
}

// ---------------- MFMA flash attention (unchanged from R8) ---------------
// Swapped QK^T (P in-register), DMA staging w/ pre-swizzled source,
// grid 1024 = 4 balanced chunks per (bkvh,j), fp32 NT partials + combine.
__global__ __launch_bounds__(256)
void attn_mfma(const u16* __restrict__ Q, const u16* __restrict__ K,
               const u16* __restrict__ Vt, const int* __restrict__ amask,
               u16* __restrict__ Y, float* __restrict__ Opart,
               float* __restrict__ lpart) {
    __shared__ __align__(16) u16 Ks[64][128];    // 16 KB
    __shared__ __align__(16) u16 Vs[128][64];    // 16 KB (sigma-ordered k)

    const int tid  = threadIdx.x;
    const int wave = tid >> 6, lane = tid & 63;
    const int quad = lane >> 4, l16 = lane & 15;

    const int bid = blockIdx.x;
    const int s   = bid >> 8;                // 0..3 chunk slot
    const int c   = bid & 255;
    const int bkvh = c & 7;                  // XCD-affine: bid%8 -> XCD
    const int j   = c >> 3;                  // 0..31
    const int b   = bkvh >> 2, kvh = bkvh & 3;

    const int H  = ((32 + j) >> 1) + 1;      // heavy tile key-tiles (17..32)
    const int Lg = ((31 - j) >> 1) + 1;      // light tile key-tiles (1..16)
    const int m2 = max((H + 1) >> 1, (Lg + 1) >> 1);
    const int m3 = max((H + 2) / 3, Lg);
    const int nh = (m2 <= m3) ? 2 : 3;
    const int nl = 4 - nh;
    int t, kt0, kt1, pi;
    if (s < nh) {
        t = 32 + j; kt0 = (H * s) / nh; kt1 = (H * (s + 1)) / nh; pi = bid;
    } else {
        t = 31 - j;
        const int ls = s - nh;
        kt0 = (Lg * ls) / nl; kt1 = (Lg * (ls + 1)) / nl;
        pi = (nl == 1) ? -1 : bid;           // whole light tile -> direct write
    }

    const int h   = kvh * 4 + wave;          // wave = head
    const int q0  = t * 32;

    const u16* Qbase = Q  + ((size_t)b * NH_  + h)   * L_ * HD_;
    const u16* Kbase = K  + ((size_t)b * NKV_ + kvh) * L_ * HD_;
    const u16* Vbase = Vt + ((size_t)b * NKV_ + kvh) * (size_t)HD_ * L_;
    const int* mbase = amask + b * L_;

    short8 qa[2][4];
    #pragma unroll
    for (int mi = 0; mi < 2; ++mi)
        #pragma unroll
        for (int ks = 0; ks < 4; ++ks)
            qa[mi][ks] = *(const short8*)&Qbase[(size_t)(q0 + mi * 16 + l16) * HD_ + ks * 32 + quad * 8];

    floatx4 Oacc[2][8] = {};
    float lsum[2] = {0.0f, 0.0f};

    const int slK = lane & 15, rKl = lane >> 4;
    const int slV = lane & 7,  rVl = lane >> 3;
    int okg[4], ovg[4];
    u16 *klds[4], *vlds[4];
    #pragma unroll
    for (int cc = 0; cc < 4; ++cc) {
        const int seg = wave * 4 + cc;
        const int rk = seg * 4 + rKl;
        okg[cc] = rk * HD_ + ((slK ^ (rk & 7)) * 8);
        klds[cc] = (u16*)Ks + seg * 512;
        const int rv = seg * 8 + rVl;
        ovg[cc] = rv * L_ + ((slV ^ (rv & 7)) * 8);
        vlds[cc] = (u16*)Vs + seg * 512;
    }
    const u16* kgb = Kbase + (size_t)kt0 * 64 * HD_;
    const u16* vgb = Vbase + kt0 * 64;

    for (int kt = kt0; kt < kt1; ++kt) {
        const int kbase = kt * 64;

        #pragma unroll
        for (int cc = 0; cc < 4; ++cc) {
            gl_lds16(kgb + okg[cc], klds[cc]);
            gl_lds16(vgb + ovg[cc], vlds[cc]);
        }
        const int am_l = mbase[kbase + lane];
        const bool allm = __all(am_l > 0);
        kgb += (size_t)64 * HD_;
        vgb += 64;
        __syncthreads();

        // ---- S^T = K Q^T (swapped): col=l16 -> q, row=quad*4+r -> key ----
        floatx4 sfr[2][4] = {};
        __builtin_amdgcn_s_setprio(1);
        #pragma unroll
        for (int ni = 0; ni < 4; ++ni) {
            #pragma unroll
            for (int ks = 0; ks < 4; ++ks) {
                short8 kf = *(const short8*)&Ks[ni * 16 + l16][((ks * 4 + quad) ^ (l16 & 7)) * 8];
                sfr[0][ni] = __builtin_amdgcn_mfma_f32_16x16x32_bf16(kf, qa[0][ks], sfr[0][ni], 0, 0, 0);
                sfr[1][ni] = __builtin_amdgcn_mfma_f32_16x16x32_bf16(kf, qa[1][ks], sfr[1][ni], 0, 0, 0);
            }
        }
        __builtin_amdgcn_s_setprio(0);

        if (allm & (kbase + 63 <= q0)) {
            #pragma unroll
            for (int mi = 0; mi < 2; ++mi)
                #pragma unroll
                for (int ni = 0; ni < 4; ++ni)
                    #pragma unroll
                    for (int r = 0; r < 4; ++r) {
                        float p = exp2f(fmaf(sfr[mi][ni][r], SC2_, -8.0f));
                        lsum[mi] += p;
                        sfr[mi][ni][r] = p;
                    }
        } else {
            #pragma unroll
            for (int ni = 0; ni < 4; ++ni) {
                const int4 amv = *(const int4*)&mbase[kbase + ni * 16 + quad * 4];
                const int amr[4] = {amv.x, amv.y, amv.z, amv.w};
                #pragma unroll
                for (int mi = 0; mi < 2; ++mi) {
                    const int qrow = q0 + mi * 16 + l16;
                    #pragma unroll
                    for (int r = 0; r < 4; ++r) {
                        const int kpos = kbase + ni * 16 + quad * 4 + r;
                        const bool ok = (kpos <= qrow) & (amr[r] > 0);
                        float p = ok ? exp2f(fmaf(sfr[mi][ni][r], SC2_, -8.0f)) : 0.0f;
                        lsum[mi] += p;
                        sfr[mi][ni][r] = p;
                    }
                }
            }
        }

        short8 pf[2][2];
        #pragma unroll
        for (int mi = 0; mi < 2; ++mi)
            #pragma unroll
            for (int kc = 0; kc < 2; ++kc) {
                union { u16 w[8]; short8 s8; } u;
                #pragma unroll
                for (int r = 0; r < 4; ++r) {
                    u.w[r]     = f2bf_hw(sfr[mi][kc * 2][r]);
                    u.w[4 + r] = f2bf_hw(sfr[mi][kc * 2 + 1][r]);
                }
                pf[mi][kc] = u.s8;
            }

        __builtin_amdgcn_s_setprio(1);
        #pragma unroll
        for (int kc = 0; kc < 2; ++kc) {
            #pragma unroll
            for (int dn = 0; dn < 8; ++dn) {
                short8 vf = *(const short8*)&Vs[dn * 16 + l16][((kc * 4 + quad) ^ (l16 & 7)) * 8];
                Oacc[0][dn] = __builtin_amdgcn_mfma_f32_16x16x32_bf16(pf[0][kc], vf, Oacc[0][dn], 0, 0, 0);
                Oacc[1][dn] = __builtin_amdgcn_mfma_f32_16x16x32_bf16(pf[1][kc], vf, Oacc[1][dn], 0, 0, 0);
            }
        }
        __builtin_amdgcn_s_setprio(0);
        __syncthreads();
    }

    float lr[2];
    #pragma unroll
    for (int mi = 0; mi < 2; ++mi) {
        float v = lsum[mi];
        v += __shfl_xor(v, 16);
        v += __shfl_xor(v, 32);
        lr[mi] = v;
    }

    if (pi < 0) {
        #pragma unroll
        for (int mi = 0; mi < 2; ++mi) {
            #pragma unroll
            for (int r = 0; r < 4; ++r) {
                const float linv = 1.0f / __shfl(lr[mi], quad * 4 + r);
                const int qrow = q0 + mi * 16 + quad * 4 + r;
                u16* dst = &Y[(((size_t)b * L_ + qrow) * NH_ + h) * HD_];
                #pragma unroll
                for (int dn = 0; dn < 8; ++dn)
                    dst[dn * 16 + l16] = f2bf(Oacc[mi][dn][r] * linv);
            }
        }
    } else {
        float* od = Opart + ((size_t)pi * 4 + wave) * 32 * 128;
        float* lp = lpart + ((size_t)pi * 4 + wave) * 32;
        #pragma unroll
        for (int mi = 0; mi < 2; ++mi) {
            if (quad == 0)
                __builtin_nontemporal_store(lr[mi], &lp[mi * 16 + l16]);
            #pragma unroll
            for (int r = 0; r < 4; ++r) {
                const int qi = mi * 16 + quad * 4 + r;
                #pragma unroll
                for (int dn = 0; dn < 8; ++dn)
                    __builtin_nontemporal_store(Oacc[mi][dn][r],
                                                &od[(size_t)qi * 128 + dn * 16 + l16]);
            }
        }
    }
}

// ---------------- combine split-tile partials -> final bf16 Y ------------
__global__ __launch_bounds__(256)
void attn_combine(const float* __restrict__ Opart, const float* __restrict__ lpart,
                  u16* __restrict__ Y) {
    const int cb = blockIdx.x;
    const int c  = cb & 255, z = cb >> 8;
    const int tile = z >> 2, hw = z & 3;
    const int bkvh = c & 7, j = c >> 3;
    const int b = bkvh >> 2, kvh = bkvh & 3;
    const int h = kvh * 4 + hw;
    const int H  = ((32 + j) >> 1) + 1;
    const int Lg = ((31 - j) >> 1) + 1;
    const int m2 = max((H + 1) >> 1, (Lg + 1) >> 1);
    const int m3 = max((H + 2) / 3, Lg);
    const int nh = (m2 <= m3) ? 2 : 3;
    const int nl = 4 - nh;
    if (tile == 1 && nl == 1) return;        // direct-written by attn block
    const int s0 = tile ? nh : 0;
    const int ns = tile ? nl : nh;
    const int t  = tile ? (31 - j) : (32 + j);
    const int tid = threadIdx.x;
    const int q = tid >> 3, dg = tid & 7;    // q 0..31, d-block 0..7 (16 floats)

    float4 a0 = {0,0,0,0}, a1 = {0,0,0,0}, a2 = {0,0,0,0}, a3 = {0,0,0,0};
    float lacc = 0.0f;
    for (int i = 0; i < ns; ++i) {
        const size_t rowb = ((size_t)((s0 + i) * 256 + c) * 4 + hw) * 32 + q;
        lacc += lpart[rowb];
        const float4* op = (const float4*)(Opart + rowb * 128 + dg * 16);
        float4 v0 = op[0], v1 = op[1], v2 = op[2], v3 = op[3];
        a0.x += v0.x; a0.y += v0.y; a0.z += v0.z; a0.w += v0.w;
        a1.x += v1.x; a1.y += v1.y; a1.z += v1.z; a1.w += v1.w;
        a2.x += v2.x; a2.y += v2.y; a2.z += v2.z; a2.w += v2.w;
        a3.x += v3.x; a3.y += v3.y; a3.z += v3.z; a3.w += v3.w;
    }
    const float linv = 1.0f / lacc;
    const int qrow = t * 32 + q;
    u16* dst = &Y[(((size_t)b * L_ + qrow) * NH_ + h) * HD_ + dg * 16];

    u16 tmp[16];
    tmp[0]  = f2bf(a0.x * linv); tmp[1]  = f2bf(a0.y * linv);
    tmp[2]  = f2bf(a0.z * linv); tmp[3]  = f2bf(a0.w * linv);
    tmp[4]  = f2bf(a1.x * linv); tmp[5]  = f2bf(a1.y * linv);
    tmp[6]  = f2bf(a1.z * linv); tmp[7]  = f2bf(a1.w * linv);
    tmp[8]  = f2bf(a2.x * linv); tmp[9]  = f2bf(a2.y * linv);
    tmp[10] = f2bf(a2.z * linv); tmp[11] = f2bf(a2.w * linv);
    tmp[12] = f2bf(a3.x * linv); tmp[13] = f2bf(a3.y * linv);
    tmp[14] = f2bf(a3.z * linv); tmp[15] = f2bf(a3.w * linv);
    *(uint4*)(dst)     = *(const uint4*)(&tmp[0]);
    *(uint4*)(dst + 8) = *(const uint4*)(&tmp[8]);
}

// ---------------- launch ----------------
extern "C" void kernel_launch(void* const* d_in, const int* in_sizes, int n_in,
                              void* d_out, int out_size, void* d_ws, size_t ws_size,
                              hipStream_t stream) {
    const float* x  = (const float*)d_in[0];
    const float* Wq = (const float*)d_in[1];
    const float* Wc = (const float*)d_in[2];
    const float* Wk = (const float*)d_in[3];
    const float* Wv = (const float*)d_in[4];
    const float* Wo = (const float*)d_in[5];
    const int* amask = (const int*)d_in[6];
    float* out = (float*)d_out;

    char* p = (char*)d_ws;
    auto alloc = [&](size_t elems) {
        u16* r = (u16*)p;
        p += ((elems * 2 + 255) / 256) * 256;
        return r;
    };
    // --- alive through attention ---
    u16* WoT  = alloc((size_t)2048 * 2048);
    u16* qbuf = alloc((size_t)4096 * 2048);   // q proj; reused as Y
    u16* Qr   = alloc((size_t)4096 * 2048);
    u16* Kr   = alloc((size_t)4096 * 512);
    u16* Vt   = alloc((size_t)4096 * 512);    // [B, NKV, HD, sigma(L)]
    // --- dead once attention starts (Opart overlays this region) ---
    char* pdead = p;
    u16* WqT  = alloc((size_t)2048 * 2048);   // [WqT|WckvT] must be adjacent
    u16* WckvT= alloc((size_t)1024 * 2048);   // fused (Wc@Wk)^T ; (Wc@Wv)^T
    u16* WkT  = alloc((size_t)512 * 512);     // [WkT|WvT] adjacent (stacked A)
    u16* WvT  = alloc((size_t)512 * 512);
    u16* Wcb  = alloc((size_t)2048 * 512);    // Wc as bf16, non-transposed
    u16* Xb   = alloc((size_t)4096 * 2048);
    u16* kvbuf= alloc((size_t)4096 * 1024);   // [k(512) | v(512)] per token
    float* Opart = (float*)pdead;
    float* lpart = (float*)(pdead + (size_t)1024 * 4 * 32 * 128 * 4);

    // converts
    cvt_kernel<<<8388608 / 4 / 256, 256, 0, stream>>>(x, Xb, 8388608 / 4);
    cvt_kernel<<<(2048 * 512 / 4) / 256, 256, 0, stream>>>(Wc, Wcb, 2048 * 512 / 4);
    cvt_transpose2_kernel<<<dim3(64, 64, 2), 256, 0, stream>>>(Wq, WqT, Wo, WoT, 2048, 2048);
    cvt_transpose2_kernel<<<dim3(16, 16, 2), 256, 0, stream>>>(Wk, WkT, Wv, WvT, 512, 512);

    // weight fusion: WckvT[1024x2048] = [WkT;WvT] @ Wcb^T-form (2.1 GF)
    gemm_bt<1><<<dim3(16, 8), 256, 0, stream>>>(WkT, Wcb, WckvT, 1024, 2048, 512);

    // mega projection: [q|k|v] = Xb @ [WqT|WckvT]^T, N=3072, 768 blocks
    // = exactly 3 blocks/CU, all-resident, no tail.
    gemm_bt_split<<<dim3(24, 32), 256, 0, stream>>>(Xb, WqT, qbuf, kvbuf,
                                                    4096, 3072, 2048, 2048, 2048, 1024);

    // rope + permute to head-major; V -> [b,kvh,d,sigma(l)]
    rope_perm<<<(2 * 16 * 2048 * 64) / 256, 256, 0, stream>>>(qbuf, Qr, 16, 4, 2048);
    rope_perm<<<(2 * 4 * 2048 * 64) / 256, 256, 0, stream>>>(kvbuf, Kr, 4, 2, 1024);
    transpose_v_kernel<<<dim3(64, 4, 8), 256, 0, stream>>>(kvbuf, Vt);

    // attention partials + combine (Y into qbuf, dead after rope)
    attn_mfma<<<dim3(1024), 256, 0, stream>>>(Qr, Kr, Vt, amask, qbuf, Opart, lpart);
    attn_combine<<<dim3(2048), 256, 0, stream>>>(Opart, lpart, qbuf);

    // output projection (fp32 out)
    gemm_bt<0><<<dim3(16, 32), 256, 0, stream>>>(qbuf, WoT, out, 4096, 2048, 2048);
}

// Round 11
// 339.318 us; speedup vs baseline: 1.7896x; 1.0088x over previous
//
#include <hip/hip_runtime.h>
#include <hip/hip_bf16.h>
#include <cstdint>
#include <cstddef>

// Problem constants
#define B_    2
#define L_    2048
#define HID_  2048
#define NH_   16
#define NKV_  4
#define HD_   128
#define LAT_  512
#define SCALE_ 0.08838834764831845f   // 1/sqrt(128)
#define SC2_   0.1275174365f          // SCALE * log2(e)

typedef unsigned short u16;
typedef unsigned int   u32;
typedef __attribute__((ext_vector_type(8))) short   short8;
typedef __attribute__((ext_vector_type(4))) float   floatx4;

typedef __attribute__((address_space(1))) const u32 gas_u32;
typedef __attribute__((address_space(3))) u32       las_u32;

__device__ __forceinline__ void gl_lds16(const u16* g, u16* l) {
    // async global->LDS, 16B/lane; LDS dest = wave-uniform base + lane*16
    __builtin_amdgcn_global_load_lds((gas_u32*)g, (las_u32*)l, 16, 0, 0);
}

__device__ __forceinline__ float bf2f(u16 u) {
    union { u32 i; float f; } v; v.i = ((u32)u) << 16; return v.f;
}
__device__ __forceinline__ u16 f2bf(float f) {
    union { float f; u32 u; } v; v.f = f;
    u32 u = v.u;
    u32 r = (u + 0x7fffu + ((u >> 16) & 1u)) >> 16;   // RNE
    return (u16)r;
}
// HW bf16 cast (compiler fuses pairs into v_cvt_pk_bf16_f32, RNE)
__device__ __forceinline__ u16 f2bf_hw(float f) {
    union { __hip_bfloat16 h; u16 u; } c;
    c.h = __float2bfloat16(f);
    return c.u;
}

// ---------------- fp32 -> bf16 elementwise (x4 vectorized) ----------------
__global__ void cvt_kernel(const float* __restrict__ in, u16* __restrict__ out, int n4) {
    int i = blockIdx.x * 256 + threadIdx.x;
    if (i < n4) {
        float4 v = ((const float4*)in)[i];
        union { u16 w[4]; uint2 v; } o;
        o.w[0] = f2bf(v.x); o.w[1] = f2bf(v.y);
        o.w[2] = f2bf(v.z); o.w[3] = f2bf(v.w);
        ((uint2*)out)[i] = o.v;
    }
}

// ---------------- fp32 [R][C] -> bf16 [C][R], two tensors per launch ------
__global__ void cvt_transpose2_kernel(const float* __restrict__ in0, u16* __restrict__ out0,
                                      const float* __restrict__ in1, u16* __restrict__ out1,
                                      int R, int C) {
    __shared__ u16 tile[32][33];
    const float* in = blockIdx.z ? in1 : in0;
    u16* out = blockIdx.z ? out1 : out0;
    int c0 = blockIdx.x * 32, r0 = blockIdx.y * 32;
    int tx = threadIdx.x & 31, ty = threadIdx.x >> 5;   // ty in 0..7
    for (int i = ty; i < 32; i += 8)
        tile[tx][i] = f2bf(in[(size_t)(r0 + i) * C + c0 + tx]);
    __syncthreads();
    for (int i = ty; i < 32; i += 8)
        out[(size_t)(c0 + i) * R + r0 + tx] = tile[i][tx];
}

// ---------------- bf16 kv[(b,l)][1024] v-half -> [b,kvh,d,sigma(l)] -------
// sigma matches the SWAPPED-QK in-register P layout: for key k (within a
// 64-block) with ni=k>>4, qd=(k>>2)&3, r=k&3, its column position is
// p = ((ni>>1)<<5) | (qd<<3) | ((ni&1)<<2) | r.
__global__ void transpose_v_kernel(const u16* __restrict__ kv, u16* __restrict__ out) {
    __shared__ u16 t[32][33];
    int lt = blockIdx.x, dt = blockIdx.y, bh = blockIdx.z;   // bh = b*NKV + kvh
    int b = bh >> 2, kvh = bh & 3;
    int tx = threadIdx.x & 31, ty = threadIdx.x >> 5;
    for (int i = ty; i < 32; i += 8)
        t[i][tx] = kv[(size_t)(b * L_ + lt * 32 + i) * 1024 + 512 + kvh * HD_ + dt * 32 + tx];
    __syncthreads();
    const int lcol = lt * 32 + tx;
    const int k6 = lcol & 63;
    const int ni = k6 >> 4, qd = (k6 >> 2) & 3, r = k6 & 3;
    const int p = ((ni >> 1) << 5) | (qd << 3) | ((ni & 1) << 2) | r;
    const int csig = (lcol & ~63) | p;
    for (int i = ty; i < 32; i += 8)
        out[((size_t)bh * HD_ + dt * 32 + i) * L_ + csig] = t[tx][i];
}

// ---------------- bf16 GEMM: C[M,N] = A[M,K] * BT[N,K]^T ----------------
// BK=64, XOR-swizzled LDS (swizzle folded into the per-lane DMA SOURCE
// address; LDS dest linear per rule 21). kk-SPLIT inner loop (R9 lesson):
// only 32 fragment VGPRs live at once -> 4 waves/SIMD residency.
template<int OUT_BF16>
__global__ __launch_bounds__(256)
void gemm_bt(const u16* __restrict__ A, const u16* __restrict__ BT,
             void* __restrict__ C, int M, int N, int K) {
    __shared__ __align__(16) u16 As[128][64];
    __shared__ __align__(16) u16 Bs[128][64];
    const int tid  = threadIdx.x;
    const int m0   = blockIdx.y * 128, n0 = blockIdx.x * 128;
    const int wave = tid >> 6, lane = tid & 63;
    const int wm   = (wave >> 1) * 64, wn = (wave & 1) * 64;
    const int quad = lane >> 4, l16 = lane & 15;

    const int r8 = lane >> 3, srcc = ((lane & 7) ^ r8) * 8;
    const int row0 = wave * 32 + r8;         // + cc*8
    const u16* aBase = A  + (size_t)(m0 + row0) * K + srcc;
    const u16* bBase = BT + (size_t)(n0 + row0) * K + srcc;
    u16* laBase = &As[0][0] + wave * 2048;   // + cc*512
    u16* lbBase = &Bs[0][0] + wave * 2048;

    floatx4 acc[4][4] = {};

    for (int k0 = 0; k0 < K; k0 += 64) {
        #pragma unroll
        for (int cc = 0; cc < 4; ++cc) {
            gl_lds16(aBase + (size_t)cc * 8 * K + k0, laBase + cc * 512);
            gl_lds16(bBase + (size_t)cc * 8 * K + k0, lbBase + cc * 512);
        }
        __syncthreads();

        #pragma unroll
        for (int kk = 0; kk < 2; kk++) {
            short8 af[4], bfr[4];
            const int co = ((kk * 4 + quad) ^ (l16 & 7)) * 8;
            #pragma unroll
            for (int i = 0; i < 4; i++) {
                af[i]  = *(const short8*)&As[wm + i * 16 + l16][co];
                bfr[i] = *(const short8*)&Bs[wn + i * 16 + l16][co];
            }
            #pragma unroll
            for (int mi = 0; mi < 4; mi++)
                #pragma unroll
                for (int ni = 0; ni < 4; ni++)
                    acc[mi][ni] = __builtin_amdgcn_mfma_f32_16x16x32_bf16(
                        af[mi], bfr[ni], acc[mi][ni], 0, 0, 0);
        }
        __syncthreads();
    }

    #pragma unroll
    for (int mi = 0; mi < 4; mi++) {
        #pragma unroll
        for (int ni = 0; ni < 4; ni++) {
            #pragma unroll
            for (int r = 0; r < 4; r++) {
                int row = m0 + wm + mi * 16 + quad * 4 + r;
                int col = n0 + wn + ni * 16 + l16;
                float v = acc[mi][ni][r];
                if (OUT_BF16) ((u16*)C)[(size_t)row * N + col] = f2bf(v);
                else          ((float*)C)[(size_t)row * N + col] = v;
            }
        }
    }
}

// ---- same GEMM, bf16 out, fused [B0|B1] N-stack (Nsplit % 128 == 0) ----
__global__ __launch_bounds__(256)
void gemm_bt_split(const u16* __restrict__ A, const u16* __restrict__ BT,
                   u16* __restrict__ C0, u16* __restrict__ C1,
                   int M, int N, int K, int Nsplit, int N0, int N1) {
    __shared__ __align__(16) u16 As[128][64];
    __shared__ __align__(16) u16 Bs[128][64];
    const int tid  = threadIdx.x;
    const int m0   = blockIdx.y * 128, n0 = blockIdx.x * 128;
    const int wave = tid >> 6, lane = tid & 63;
    const int wm   = (wave >> 1) * 64, wn = (wave & 1) * 64;
    const int quad = lane >> 4, l16 = lane & 15;

    const int r8 = lane >> 3, srcc = ((lane & 7) ^ r8) * 8;
    const int row0 = wave * 32 + r8;
    const u16* aBase = A  + (size_t)(m0 + row0) * K + srcc;
    const u16* bBase = BT + (size_t)(n0 + row0) * K + srcc;
    u16* laBase = &As[0][0] + wave * 2048;
    u16* lbBase = &Bs[0][0] + wave * 2048;

    floatx4 acc[4][4] = {};

    for (int k0 = 0; k0 < K; k0 += 64) {
        #pragma unroll
        for (int cc = 0; cc < 4; ++cc) {
            gl_lds16(aBase + (size_t)cc * 8 * K + k0, laBase + cc * 512);
            gl_lds16(bBase + (size_t)cc * 8 * K + k0, lbBase + cc * 512);
        }
        __syncthreads();

        #pragma unroll
        for (int kk = 0; kk < 2; kk++) {
            short8 af[4], bfr[4];
            const int co = ((kk * 4 + quad) ^ (l16 & 7)) * 8;
            #pragma unroll
            for (int i = 0; i < 4; i++) {
                af[i]  = *(const short8*)&As[wm + i * 16 + l16][co];
                bfr[i] = *(const short8*)&Bs[wn + i * 16 + l16][co];
            }
            #pragma unroll
            for (int mi = 0; mi < 4; mi++)
                #pragma unroll
                for (int ni = 0; ni < 4; ni++)
                    acc[mi][ni] = __builtin_amdgcn_mfma_f32_16x16x32_bf16(
                        af[mi], bfr[ni], acc[mi][ni], 0, 0, 0);
        }
        __syncthreads();
    }

    const int side = (n0 >= Nsplit);
    u16* Cw = side ? C1 : C0;
    const int nw = side ? N1 : N0;
    const int cbase = side ? Nsplit : 0;

    #pragma unroll
    for (int mi = 0; mi < 4; mi++) {
        #pragma unroll
        for (int ni = 0; ni < 4; ni++) {
            #pragma unroll
            for (int r = 0; r < 4; r++) {
                int row = m0 + wm + mi * 16 + quad * 4 + r;
                int col = n0 + wn + ni * 16 + l16 - cbase;
                Cw[(size_t)row * nw + col] = f2bf(acc[mi][ni][r]);
            }
        }
    }
}

// ---------------- RoPE + head-major permute (src row stride rs) ----------
__global__ void rope_perm(const u16* __restrict__ in, u16* __restrict__ out,
                          int nh, int nhbits, int rs) {
    int idx = blockIdx.x * 256 + threadIdx.x;   // one thread per (b,h,l,d<64)
    int d = idx & 63;
    int l = (idx >> 6) & (L_ - 1);
    int h = (idx >> 17) & (nh - 1);
    int b = idx >> (17 + nhbits);
    const u16* src = &in[(size_t)(b * L_ + l) * rs + h * HD_];
    u16* dst = &out[(((size_t)b * nh + h) * L_ + l) * HD_];
    float t1 = bf2f(src[d]), t2 = bf2f(src[d + 64]);
    float inv = expf(-(float)d * 0.14391156831212787f);  // ln(10000)/64
    float fr = (float)l * inv;
    float c = cosf(fr), sn = sinf(fr);
    dst[d]      = f2bf(t1 * c - t2 * sn);
    dst[d + 64] = f2bf(t2 * c + t1 * sn);
}

// ---------------- MFMA flash attention (GQA head-merged waves) -----------
// Block = 4 waves = 4 HEADS of one kv-group, same 32 q-rows.
// R11: LDS DOUBLE-BUFFER, single barrier per iteration.
//   loop: __syncthreads()  [implicit vmcnt(0) drains loads issued a full
//         compute-phase ago -> cheap]  ->  STAGE(buf^1, kt+1)  ->
//         compute(buf).
//   DMA latency for kt+1 hides entirely under compute(kt); barrier count
//   halves (was stage->bar->compute->bar). Race-free: stage of buf^1 is
//   after the barrier where every wave finished reading buf^1 (iter kt-1);
//   reads of buf are after every wave's own vmcnt(0)+barrier.
//   LDS 64 KB -> 2 blocks/CU + 2 backfill rounds (grid 1024).
// Still: swapped QK^T (P in-register, no LDS round-trip), DMA staging with
// pre-swizzled source, sigma-ordered V, wave-uniform mask fast-path,
// grid 1024 = 4 balanced chunks per c=(bkvh,j), fp32 NT partials+combine.
__global__ __launch_bounds__(256)
void attn_mfma(const u16* __restrict__ Q, const u16* __restrict__ K,
               const u16* __restrict__ Vt, const int* __restrict__ amask,
               u16* __restrict__ Y, float* __restrict__ Opart,
               float* __restrict__ lpart) {
    __shared__ __align__(16) u16 Ks[2][64][128];   // 2 x 16 KB
    __shared__ __align__(16) u16 Vs[2][128][64];   // 2 x 16 KB (sigma k)

    const int tid  = threadIdx.x;
    const int wave = tid >> 6, lane = tid & 63;
    const int quad = lane >> 4, l16 = lane & 15;

    const int bid = blockIdx.x;
    const int s   = bid >> 8;                // 0..3 chunk slot
    const int c   = bid & 255;
    const int bkvh = c & 7;                  // XCD-affine: bid%8 -> XCD
    const int j   = c >> 3;                  // 0..31
    const int b   = bkvh >> 2, kvh = bkvh & 3;

    const int H  = ((32 + j) >> 1) + 1;      // heavy tile key-tiles (17..32)
    const int Lg = ((31 - j) >> 1) + 1;      // light tile key-tiles (1..16)
    const int m2 = max((H + 1) >> 1, (Lg + 1) >> 1);
    const int m3 = max((H + 2) / 3, Lg);
    const int nh = (m2 <= m3) ? 2 : 3;
    const int nl = 4 - nh;
    int t, kt0, kt1, pi;
    if (s < nh) {
        t = 32 + j; kt0 = (H * s) / nh; kt1 = (H * (s + 1)) / nh; pi = bid;
    } else {
        t = 31 - j;
        const int ls = s - nh;
        kt0 = (Lg * ls) / nl; kt1 = (Lg * (ls + 1)) / nl;
        pi = (nl == 1) ? -1 : bid;           // whole light tile -> direct write
    }

    const int h   = kvh * 4 + wave;          // wave = head
    const int q0  = t * 32;

    const u16* Qbase = Q  + ((size_t)b * NH_  + h)   * L_ * HD_;
    const u16* Kbase = K  + ((size_t)b * NKV_ + kvh) * L_ * HD_;
    const u16* Vbase = Vt + ((size_t)b * NKV_ + kvh) * (size_t)HD_ * L_;
    const int* mbase = amask + b * L_;

    short8 qa[2][4];
    #pragma unroll
    for (int mi = 0; mi < 2; ++mi)
        #pragma unroll
        for (int ks = 0; ks < 4; ++ks)
            qa[mi][ks] = *(const short8*)&Qbase[(size_t)(q0 + mi * 16 + l16) * HD_ + ks * 32 + quad * 8];

    floatx4 Oacc[2][8] = {};
    float lsum[2] = {0.0f, 0.0f};

    // DMA staging: per-wave 4 segments of 1KB each for K and V (buffer 0).
    const int slK = lane & 15, rKl = lane >> 4;
    const int slV = lane & 7,  rVl = lane >> 3;
    int okg[4], ovg[4];
    u16 *klds[4], *vlds[4];
    #pragma unroll
    for (int cc = 0; cc < 4; ++cc) {
        const int seg = wave * 4 + cc;
        const int rk = seg * 4 + rKl;
        okg[cc] = rk * HD_ + ((slK ^ (rk & 7)) * 8);
        klds[cc] = &Ks[0][0][0] + seg * 512;
        const int rv = seg * 8 + rVl;
        ovg[cc] = rv * L_ + ((slV ^ (rv & 7)) * 8);
        vlds[cc] = &Vs[0][0][0] + seg * 512;
    }
    const u16* kgb = Kbase + (size_t)kt0 * 64 * HD_;
    const u16* vgb = Vbase + kt0 * 64;

    // ---- prologue: stage kt0 into buffer 0 ----
    #pragma unroll
    for (int cc = 0; cc < 4; ++cc) {
        gl_lds16(kgb + okg[cc], klds[cc]);
        gl_lds16(vgb + ovg[cc], vlds[cc]);
    }
    kgb += (size_t)64 * HD_;
    vgb += 64;

    int bufoff = 0;                          // 0 or 8192 (u16 elements)
    for (int kt = kt0; kt < kt1; ++kt) {
        const int kbase = kt * 64;

        __syncthreads();   // drains this wave's buf loads (issued a full
                           // compute phase ago) + syncs all waves

        // ---- stage NEXT tile into the other buffer (hides under compute) --
        const int nb = bufoff ^ 8192;
        if (kt + 1 < kt1) {
            #pragma unroll
            for (int cc = 0; cc < 4; ++cc) {
                gl_lds16(kgb + okg[cc], klds[cc] + nb);
                gl_lds16(vgb + ovg[cc], vlds[cc] + nb);
            }
            kgb += (size_t)64 * HD_;
            vgb += 64;
        }
        const int am_l = mbase[kbase + lane];
        const bool allm = __all(am_l > 0);
        const u16* KsB = &Ks[0][0][0] + bufoff;
        const u16* VsB = &Vs[0][0][0] + bufoff;

        // ---- S^T = K Q^T (swapped): col=l16 -> q, row=quad*4+r -> key ----
        floatx4 sfr[2][4] = {};
        __builtin_amdgcn_s_setprio(1);
        #pragma unroll
        for (int ni = 0; ni < 4; ++ni) {
            #pragma unroll
            for (int ks = 0; ks < 4; ++ks) {
                short8 kf = *(const short8*)&KsB[(ni * 16 + l16) * 128 + ((ks * 4 + quad) ^ (l16 & 7)) * 8];
                sfr[0][ni] = __builtin_amdgcn_mfma_f32_16x16x32_bf16(kf, qa[0][ks], sfr[0][ni], 0, 0, 0);
                sfr[1][ni] = __builtin_amdgcn_mfma_f32_16x16x32_bf16(kf, qa[1][ks], sfr[1][ni], 0, 0, 0);
            }
        }
        __builtin_amdgcn_s_setprio(0);

        if (allm & (kbase + 63 <= q0)) {
            #pragma unroll
            for (int mi = 0; mi < 2; ++mi)
                #pragma unroll
                for (int ni = 0; ni < 4; ++ni)
                    #pragma unroll
                    for (int r = 0; r < 4; ++r) {
                        float p = exp2f(fmaf(sfr[mi][ni][r], SC2_, -8.0f));
                        lsum[mi] += p;
                        sfr[mi][ni][r] = p;
                    }
        } else {
            #pragma unroll
            for (int ni = 0; ni < 4; ++ni) {
                const int4 amv = *(const int4*)&mbase[kbase + ni * 16 + quad * 4];
                const int amr[4] = {amv.x, amv.y, amv.z, amv.w};
                #pragma unroll
                for (int mi = 0; mi < 2; ++mi) {
                    const int qrow = q0 + mi * 16 + l16;
                    #pragma unroll
                    for (int r = 0; r < 4; ++r) {
                        const int kpos = kbase + ni * 16 + quad * 4 + r;
                        const bool ok = (kpos <= qrow) & (amr[r] > 0);
                        float p = ok ? exp2f(fmaf(sfr[mi][ni][r], SC2_, -8.0f)) : 0.0f;
                        lsum[mi] += p;
                        sfr[mi][ni][r] = p;
                    }
                }
            }
        }

        short8 pf[2][2];
        #pragma unroll
        for (int mi = 0; mi < 2; ++mi)
            #pragma unroll
            for (int kc = 0; kc < 2; ++kc) {
                union { u16 w[8]; short8 s8; } u;
                #pragma unroll
                for (int r = 0; r < 4; ++r) {
                    u.w[r]     = f2bf_hw(sfr[mi][kc * 2][r]);
                    u.w[4 + r] = f2bf_hw(sfr[mi][kc * 2 + 1][r]);
                }
                pf[mi][kc] = u.s8;
            }

        __builtin_amdgcn_s_setprio(1);
        #pragma unroll
        for (int kc = 0; kc < 2; ++kc) {
            #pragma unroll
            for (int dn = 0; dn < 8; ++dn) {
                short8 vf = *(const short8*)&VsB[(dn * 16 + l16) * 64 + ((kc * 4 + quad) ^ (l16 & 7)) * 8];
                Oacc[0][dn] = __builtin_amdgcn_mfma_f32_16x16x32_bf16(pf[0][kc], vf, Oacc[0][dn], 0, 0, 0);
                Oacc[1][dn] = __builtin_amdgcn_mfma_f32_16x16x32_bf16(pf[1][kc], vf, Oacc[1][dn], 0, 0, 0);
            }
        }
        __builtin_amdgcn_s_setprio(0);

        bufoff = nb;
    }

    float lr[2];
    #pragma unroll
    for (int mi = 0; mi < 2; ++mi) {
        float v = lsum[mi];
        v += __shfl_xor(v, 16);
        v += __shfl_xor(v, 32);
        lr[mi] = v;
    }

    if (pi < 0) {
        #pragma unroll
        for (int mi = 0; mi < 2; ++mi) {
            #pragma unroll
            for (int r = 0; r < 4; ++r) {
                const float linv = 1.0f / __shfl(lr[mi], quad * 4 + r);
                const int qrow = q0 + mi * 16 + quad * 4 + r;
                u16* dst = &Y[(((size_t)b * L_ + qrow) * NH_ + h) * HD_];
                #pragma unroll
                for (int dn = 0; dn < 8; ++dn)
                    dst[dn * 16 + l16] = f2bf(Oacc[mi][dn][r] * linv);
            }
        }
    } else {
        float* od = Opart + ((size_t)pi * 4 + wave) * 32 * 128;
        float* lp = lpart + ((size_t)pi * 4 + wave) * 32;
        #pragma unroll
        for (int mi = 0; mi < 2; ++mi) {
            if (quad == 0)
                __builtin_nontemporal_store(lr[mi], &lp[mi * 16 + l16]);
            #pragma unroll
            for (int r = 0; r < 4; ++r) {
                const int qi = mi * 16 + quad * 4 + r;
                #pragma unroll
                for (int dn = 0; dn < 8; ++dn)
                    __builtin_nontemporal_store(Oacc[mi][dn][r],
                                                &od[(size_t)qi * 128 + dn * 16 + l16]);
            }
        }
    }
}

// ---------------- combine split-tile partials -> final bf16 Y ------------
__global__ __launch_bounds__(256)
void attn_combine(const float* __restrict__ Opart, const float* __restrict__ lpart,
                  u16* __restrict__ Y) {
    const int cb = blockIdx.x;
    const int c  = cb & 255, z = cb >> 8;
    const int tile = z >> 2, hw = z & 3;
    const int bkvh = c & 7, j = c >> 3;
    const int b = bkvh >> 2, kvh = bkvh & 3;
    const int h = kvh * 4 + hw;
    const int H  = ((32 + j) >> 1) + 1;
    const int Lg = ((31 - j) >> 1) + 1;
    const int m2 = max((H + 1) >> 1, (Lg + 1) >> 1);
    const int m3 = max((H + 2) / 3, Lg);
    const int nh = (m2 <= m3) ? 2 : 3;
    const int nl = 4 - nh;
    if (tile == 1 && nl == 1) return;        // direct-written by attn block
    const int s0 = tile ? nh : 0;
    const int ns = tile ? nl : nh;
    const int t  = tile ? (31 - j) : (32 + j);
    const int tid = threadIdx.x;
    const int q = tid >> 3, dg = tid & 7;    // q 0..31, d-block 0..7 (16 floats)

    float4 a0 = {0,0,0,0}, a1 = {0,0,0,0}, a2 = {0,0,0,0}, a3 = {0,0,0,0};
    float lacc = 0.0f;
    for (int i = 0; i < ns; ++i) {
        const size_t rowb = ((size_t)((s0 + i) * 256 + c) * 4 + hw) * 32 + q;
        lacc += lpart[rowb];
        const float4* op = (const float4*)(Opart + rowb * 128 + dg * 16);
        float4 v0 = op[0], v1 = op[1], v2 = op[2], v3 = op[3];
        a0.x += v0.x; a0.y += v0.y; a0.z += v0.z; a0.w += v0.w;
        a1.x += v1.x; a1.y += v1.y; a1.z += v1.z; a1.w += v1.w;
        a2.x += v2.x; a2.y += v2.y; a2.z += v2.z; a2.w += v2.w;
        a3.x += v3.x; a3.y += v3.y; a3.z += v3.z; a3.w += v3.w;
    }
    const float linv = 1.0f / lacc;
    const int qrow = t * 32 + q;
    u16* dst = &Y[(((size_t)b * L_ + qrow) * NH_ + h) * HD_ + dg * 16];

    u16 tmp[16];
    tmp[0]  = f2bf(a0.x * linv); tmp[1]  = f2bf(a0.y * linv);
    tmp[2]  = f2bf(a0.z * linv); tmp[3]  = f2bf(a0.w * linv);
    tmp[4]  = f2bf(a1.x * linv); tmp[5]  = f2bf(a1.y * linv);
    tmp[6]  = f2bf(a1.z * linv); tmp[7]  = f2bf(a1.w * linv);
    tmp[8]  = f2bf(a2.x * linv); tmp[9]  = f2bf(a2.y * linv);
    tmp[10] = f2bf(a2.z * linv); tmp[11] = f2bf(a2.w * linv);
    tmp[12] = f2bf(a3.x * linv); tmp[13] = f2bf(a3.y * linv);
    tmp[14] = f2bf(a3.z * linv); tmp[15] = f2bf(a3.w * linv);
    *(uint4*)(dst)     = *(const uint4*)(&tmp[0]);
    *(uint4*)(dst + 8) = *(const uint4*)(&tmp[8]);
}

// ---------------- launch ----------------
extern "C" void kernel_launch(void* const* d_in, const int* in_sizes, int n_in,
                              void* d_out, int out_size, void* d_ws, size_t ws_size,
                              hipStream_t stream) {
    const float* x  = (const float*)d_in[0];
    const float* Wq = (const float*)d_in[1];
    const float* Wc = (const float*)d_in[2];
    const float* Wk = (const float*)d_in[3];
    const float* Wv = (const float*)d_in[4];
    const float* Wo = (const float*)d_in[5];
    const int* amask = (const int*)d_in[6];
    float* out = (float*)d_out;

    char* p = (char*)d_ws;
    auto alloc = [&](size_t elems) {
        u16* r = (u16*)p;
        p += ((elems * 2 + 255) / 256) * 256;
        return r;
    };
    // --- alive through attention ---
    u16* WoT  = alloc((size_t)2048 * 2048);
    u16* qbuf = alloc((size_t)4096 * 2048);   // q proj; reused as Y
    u16* Qr   = alloc((size_t)4096 * 2048);
    u16* Kr   = alloc((size_t)4096 * 512);
    u16* Vt   = alloc((size_t)4096 * 512);    // [B, NKV, HD, sigma(L)]
    // --- dead once attention starts (Opart overlays this region) ---
    char* pdead = p;
    u16* WqT  = alloc((size_t)2048 * 2048);   // [WqT|WckvT] must be adjacent
    u16* WckvT= alloc((size_t)1024 * 2048);   // fused (Wc@Wk)^T ; (Wc@Wv)^T
    u16* WkT  = alloc((size_t)512 * 512);     // [WkT|WvT] adjacent (stacked A)
    u16* WvT  = alloc((size_t)512 * 512);
    u16* Wcb  = alloc((size_t)2048 * 512);    // Wc as bf16, non-transposed
    u16* Xb   = alloc((size_t)4096 * 2048);
    u16* kvbuf= alloc((size_t)4096 * 1024);   // [k(512) | v(512)] per token
    float* Opart = (float*)pdead;
    float* lpart = (float*)(pdead + (size_t)1024 * 4 * 32 * 128 * 4);

    // converts
    cvt_kernel<<<8388608 / 4 / 256, 256, 0, stream>>>(x, Xb, 8388608 / 4);
    cvt_kernel<<<(2048 * 512 / 4) / 256, 256, 0, stream>>>(Wc, Wcb, 2048 * 512 / 4);
    cvt_transpose2_kernel<<<dim3(64, 64, 2), 256, 0, stream>>>(Wq, WqT, Wo, WoT, 2048, 2048);
    cvt_transpose2_kernel<<<dim3(16, 16, 2), 256, 0, stream>>>(Wk, WkT, Wv, WvT, 512, 512);

    // weight fusion: WckvT[1024x2048] = [WkT;WvT] @ Wcb^T-form (2.1 GF)
    gemm_bt<1><<<dim3(16, 8), 256, 0, stream>>>(WkT, Wcb, WckvT, 1024, 2048, 512);

    // mega projection: [q|k|v] = Xb @ [WqT|WckvT]^T, N=3072, 768 blocks
    gemm_bt_split<<<dim3(24, 32), 256, 0, stream>>>(Xb, WqT, qbuf, kvbuf,
                                                    4096, 3072, 2048, 2048, 2048, 1024);

    // rope + permute to head-major; V -> [b,kvh,d,sigma(l)]
    rope_perm<<<(2 * 16 * 2048 * 64) / 256, 256, 0, stream>>>(qbuf, Qr, 16, 4, 2048);
    rope_perm<<<(2 * 4 * 2048 * 64) / 256, 256, 0, stream>>>(kvbuf, Kr, 4, 2, 1024);
    transpose_v_kernel<<<dim3(64, 4, 8), 256, 0, stream>>>(kvbuf, Vt);

    // attention partials + combine (Y into qbuf, dead after rope)
    attn_mfma<<<dim3(1024), 256, 0, stream>>>(Qr, Kr, Vt, amask, qbuf, Opart, lpart);
    attn_combine<<<dim3(2048), 256, 0, stream>>>(Opart, lpart, qbuf);

    // output projection (fp32 out)
    gemm_bt<0><<<dim3(16, 32), 256, 0, stream>>>(qbuf, WoT, out, 4096, 2048, 2048);
}

// Round 12
// 339.156 us; speedup vs baseline: 1.7905x; 1.0005x over previous
//
#include <hip/hip_runtime.h>
#include <hip/hip_bf16.h>
#include <cstdint>
#include <cstddef>

// Problem constants
#define B_    2
#define L_    2048
#define HID_  2048
#define NH_   16
#define NKV_  4
#define HD_   128
#define LAT_  512
#define SCALE_ 0.08838834764831845f   // 1/sqrt(128)
#define SC2_   0.1275174365f          // SCALE * log2(e)

typedef unsigned short u16;
typedef unsigned int   u32;
typedef __attribute__((ext_vector_type(8))) short   short8;
typedef __attribute__((ext_vector_type(4))) float   floatx4;

typedef __attribute__((address_space(1))) const u32 gas_u32;
typedef __attribute__((address_space(3))) u32       las_u32;

__device__ __forceinline__ void gl_lds16(const u16* g, u16* l) {
    // async global->LDS, 16B/lane; LDS dest = wave-uniform base + lane*16
    __builtin_amdgcn_global_load_lds((gas_u32*)g, (las_u32*)l, 16, 0, 0);
}

__device__ __forceinline__ float bf2f(u16 u) {
    union { u32 i; float f; } v; v.i = ((u32)u) << 16; return v.f;
}
__device__ __forceinline__ u16 f2bf(float f) {
    union { float f; u32 u; } v; v.f = f;
    u32 u = v.u;
    u32 r = (u + 0x7fffu + ((u >> 16) & 1u)) >> 16;   // RNE
    return (u16)r;
}
// HW bf16 cast (compiler fuses pairs into v_cvt_pk_bf16_f32, RNE)
__device__ __forceinline__ u16 f2bf_hw(float f) {
    union { __hip_bfloat16 h; u16 u; } c;
    c.h = __float2bfloat16(f);
    return c.u;
}

// ---------------- fp32 -> bf16 elementwise (x4 vectorized) ----------------
__global__ void cvt_kernel(const float* __restrict__ in, u16* __restrict__ out, int n4) {
    int i = blockIdx.x * 256 + threadIdx.x;
    if (i < n4) {
        float4 v = ((const float4*)in)[i];
        union { u16 w[4]; uint2 v; } o;
        o.w[0] = f2bf(v.x); o.w[1] = f2bf(v.y);
        o.w[2] = f2bf(v.z); o.w[3] = f2bf(v.w);
        ((uint2*)out)[i] = o.v;
    }
}

// ---------------- fp32 [R][C] -> bf16 [C][R], two tensors per launch ------
__global__ void cvt_transpose2_kernel(const float* __restrict__ in0, u16* __restrict__ out0,
                                      const float* __restrict__ in1, u16* __restrict__ out1,
                                      int R, int C) {
    __shared__ u16 tile[32][33];
    const float* in = blockIdx.z ? in1 : in0;
    u16* out = blockIdx.z ? out1 : out0;
    int c0 = blockIdx.x * 32, r0 = blockIdx.y * 32;
    int tx = threadIdx.x & 31, ty = threadIdx.x >> 5;   // ty in 0..7
    for (int i = ty; i < 32; i += 8)
        tile[tx][i] = f2bf(in[(size_t)(r0 + i) * C + c0 + tx]);
    __syncthreads();
    for (int i = ty; i < 32; i += 8)
        out[(size_t)(c0 + i) * R + r0 + tx] = tile[i][tx];
}

// ---------------- bf16 kv[(b,l)][1024] v-half -> [b,kvh,d,sigma(l)] -------
// sigma matches the SWAPPED-QK in-register P layout: for key k (within a
// 64-block) with ni=k>>4, qd=(k>>2)&3, r=k&3, its column position is
// p = ((ni>>1)<<5) | (qd<<3) | ((ni&1)<<2) | r.
__global__ void transpose_v_kernel(const u16* __restrict__ kv, u16* __restrict__ out) {
    __shared__ u16 t[32][33];
    int lt = blockIdx.x, dt = blockIdx.y, bh = blockIdx.z;   // bh = b*NKV + kvh
    int b = bh >> 2, kvh = bh & 3;
    int tx = threadIdx.x & 31, ty = threadIdx.x >> 5;
    for (int i = ty; i < 32; i += 8)
        t[i][tx] = kv[(size_t)(b * L_ + lt * 32 + i) * 1024 + 512 + kvh * HD_ + dt * 32 + tx];
    __syncthreads();
    const int lcol = lt * 32 + tx;
    const int k6 = lcol & 63;
    const int ni = k6 >> 4, qd = (k6 >> 2) & 3, r = k6 & 3;
    const int p = ((ni >> 1) << 5) | (qd << 3) | ((ni & 1) << 2) | r;
    const int csig = (lcol & ~63) | p;
    for (int i = ty; i < 32; i += 8)
        out[((size_t)bh * HD_ + dt * 32 + i) * L_ + csig] = t[tx][i];
}

// ---------------- bf16 GEMM: C[M,N] = A[M,K] * BT[N,K]^T ----------------
// BK=64, XOR-swizzled LDS (swizzle in the DMA SOURCE address; linear dest,
// rule 21), kk-split inner loop (R9: 32 live fragment regs).
// R12: LDS DOUBLE-BUFFER + single barrier/iter (proven on attn in R11):
//   loop: barrier [drains own DMA issued a compute-phase ago] ->
//         stage(buf^1, k0+64) -> compute(buf).
//   LDS 64 KB -> 2 blocks/CU (same residency as measured before), but the
//   per-iteration L2-latency+transfer drain leaves the critical path and
//   barrier count halves.
template<int OUT_BF16>
__global__ __launch_bounds__(256)
void gemm_bt(const u16* __restrict__ A, const u16* __restrict__ BT,
             void* __restrict__ C, int M, int N, int K) {
    __shared__ __align__(16) u16 As[2][128][64];
    __shared__ __align__(16) u16 Bs[2][128][64];
    const int tid  = threadIdx.x;
    const int m0   = blockIdx.y * 128, n0 = blockIdx.x * 128;
    const int wave = tid >> 6, lane = tid & 63;
    const int wm   = (wave >> 1) * 64, wn = (wave & 1) * 64;
    const int quad = lane >> 4, l16 = lane & 15;

    const int r8 = lane >> 3, srcc = ((lane & 7) ^ r8) * 8;
    const int row0 = wave * 32 + r8;         // + cc*8
    const u16* aBase = A  + (size_t)(m0 + row0) * K + srcc;
    const u16* bBase = BT + (size_t)(n0 + row0) * K + srcc;
    u16* laBase = &As[0][0][0] + wave * 2048;   // + cc*512 (+ buf*8192)
    u16* lbBase = &Bs[0][0][0] + wave * 2048;
    const u16* AsF = &As[0][0][0];
    const u16* BsF = &Bs[0][0][0];

    floatx4 acc[4][4] = {};

    // prologue: stage k0=0 into buffer 0
    #pragma unroll
    for (int cc = 0; cc < 4; ++cc) {
        gl_lds16(aBase + (size_t)cc * 8 * K, laBase + cc * 512);
        gl_lds16(bBase + (size_t)cc * 8 * K, lbBase + cc * 512);
    }

    int bufoff = 0;                          // 0 or 8192 (u16 elements)
    for (int k0 = 0; k0 < K; k0 += 64) {
        __syncthreads();   // drains this wave's buf loads (issued a full
                           // compute phase ago) + syncs all waves

        const int nb = bufoff ^ 8192;
        if (k0 + 64 < K) {
            #pragma unroll
            for (int cc = 0; cc < 4; ++cc) {
                gl_lds16(aBase + (size_t)cc * 8 * K + k0 + 64, laBase + nb + cc * 512);
                gl_lds16(bBase + (size_t)cc * 8 * K + k0 + 64, lbBase + nb + cc * 512);
            }
        }

        #pragma unroll
        for (int kk = 0; kk < 2; kk++) {
            short8 af[4], bfr[4];
            const int co = ((kk * 4 + quad) ^ (l16 & 7)) * 8;
            #pragma unroll
            for (int i = 0; i < 4; i++) {
                af[i]  = *(const short8*)&AsF[bufoff + (wm + i * 16 + l16) * 64 + co];
                bfr[i] = *(const short8*)&BsF[bufoff + (wn + i * 16 + l16) * 64 + co];
            }
            #pragma unroll
            for (int mi = 0; mi < 4; mi++)
                #pragma unroll
                for (int ni = 0; ni < 4; ni++)
                    acc[mi][ni] = __builtin_amdgcn_mfma_f32_16x16x32_bf16(
                        af[mi], bfr[ni], acc[mi][ni], 0, 0, 0);
        }
        bufoff = nb;
    }

    #pragma unroll
    for (int mi = 0; mi < 4; mi++) {
        #pragma unroll
        for (int ni = 0; ni < 4; ni++) {
            #pragma unroll
            for (int r = 0; r < 4; r++) {
                int row = m0 + wm + mi * 16 + quad * 4 + r;
                int col = n0 + wn + ni * 16 + l16;
                float v = acc[mi][ni][r];
                if (OUT_BF16) ((u16*)C)[(size_t)row * N + col] = f2bf(v);
                else          ((float*)C)[(size_t)row * N + col] = v;
            }
        }
    }
}

// ---- same GEMM, bf16 out, fused [B0|B1] N-stack (Nsplit % 128 == 0) ----
__global__ __launch_bounds__(256)
void gemm_bt_split(const u16* __restrict__ A, const u16* __restrict__ BT,
                   u16* __restrict__ C0, u16* __restrict__ C1,
                   int M, int N, int K, int Nsplit, int N0, int N1) {
    __shared__ __align__(16) u16 As[2][128][64];
    __shared__ __align__(16) u16 Bs[2][128][64];
    const int tid  = threadIdx.x;
    const int m0   = blockIdx.y * 128, n0 = blockIdx.x * 128;
    const int wave = tid >> 6, lane = tid & 63;
    const int wm   = (wave >> 1) * 64, wn = (wave & 1) * 64;
    const int quad = lane >> 4, l16 = lane & 15;

    const int r8 = lane >> 3, srcc = ((lane & 7) ^ r8) * 8;
    const int row0 = wave * 32 + r8;
    const u16* aBase = A  + (size_t)(m0 + row0) * K + srcc;
    const u16* bBase = BT + (size_t)(n0 + row0) * K + srcc;
    u16* laBase = &As[0][0][0] + wave * 2048;
    u16* lbBase = &Bs[0][0][0] + wave * 2048;
    const u16* AsF = &As[0][0][0];
    const u16* BsF = &Bs[0][0][0];

    floatx4 acc[4][4] = {};

    #pragma unroll
    for (int cc = 0; cc < 4; ++cc) {
        gl_lds16(aBase + (size_t)cc * 8 * K, laBase + cc * 512);
        gl_lds16(bBase + (size_t)cc * 8 * K, lbBase + cc * 512);
    }

    int bufoff = 0;
    for (int k0 = 0; k0 < K; k0 += 64) {
        __syncthreads();

        const int nb = bufoff ^ 8192;
        if (k0 + 64 < K) {
            #pragma unroll
            for (int cc = 0; cc < 4; ++cc) {
                gl_lds16(aBase + (size_t)cc * 8 * K + k0 + 64, laBase + nb + cc * 512);
                gl_lds16(bBase + (size_t)cc * 8 * K + k0 + 64, lbBase + nb + cc * 512);
            }
        }

        #pragma unroll
        for (int kk = 0; kk < 2; kk++) {
            short8 af[4], bfr[4];
            const int co = ((kk * 4 + quad) ^ (l16 & 7)) * 8;
            #pragma unroll
            for (int i = 0; i < 4; i++) {
                af[i]  = *(const short8*)&AsF[bufoff + (wm + i * 16 + l16) * 64 + co];
                bfr[i] = *(const short8*)&BsF[bufoff + (wn + i * 16 + l16) * 64 + co];
            }
            #pragma unroll
            for (int mi = 0; mi < 4; mi++)
                #pragma unroll
                for (int ni = 0; ni < 4; ni++)
                    acc[mi][ni] = __builtin_amdgcn_mfma_f32_16x16x32_bf16(
                        af[mi], bfr[ni], acc[mi][ni], 0, 0, 0);
        }
        bufoff = nb;
    }

    const int side = (n0 >= Nsplit);
    u16* Cw = side ? C1 : C0;
    const int nw = side ? N1 : N0;
    const int cbase = side ? Nsplit : 0;

    #pragma unroll
    for (int mi = 0; mi < 4; mi++) {
        #pragma unroll
        for (int ni = 0; ni < 4; ni++) {
            #pragma unroll
            for (int r = 0; r < 4; r++) {
                int row = m0 + wm + mi * 16 + quad * 4 + r;
                int col = n0 + wn + ni * 16 + l16 - cbase;
                Cw[(size_t)row * nw + col] = f2bf(acc[mi][ni][r]);
            }
        }
    }
}

// ---------------- RoPE + head-major permute (src row stride rs) ----------
__global__ void rope_perm(const u16* __restrict__ in, u16* __restrict__ out,
                          int nh, int nhbits, int rs) {
    int idx = blockIdx.x * 256 + threadIdx.x;   // one thread per (b,h,l,d<64)
    int d = idx & 63;
    int l = (idx >> 6) & (L_ - 1);
    int h = (idx >> 17) & (nh - 1);
    int b = idx >> (17 + nhbits);
    const u16* src = &in[(size_t)(b * L_ + l) * rs + h * HD_];
    u16* dst = &out[(((size_t)b * nh + h) * L_ + l) * HD_];
    float t1 = bf2f(src[d]), t2 = bf2f(src[d + 64]);
    float inv = expf(-(float)d * 0.14391156831212787f);  // ln(10000)/64
    float fr = (float)l * inv;
    float c = cosf(fr), sn = sinf(fr);
    dst[d]      = f2bf(t1 * c - t2 * sn);
    dst[d + 64] = f2bf(t2 * c + t1 * sn);
}

// ---------------- MFMA flash attention (GQA head-merged waves) -----------
// Block = 4 waves = 4 HEADS of one kv-group, same 32 q-rows.
// LDS double-buffer, single barrier/iter (R11). Swapped QK^T (P in-register,
// no LDS round-trip), DMA staging with pre-swizzled source, sigma-ordered V,
// wave-uniform mask fast-path, grid 1024 = 4 balanced chunks per c=(bkvh,j),
// fp32 NT partials + combine.
__global__ __launch_bounds__(256)
void attn_mfma(const u16* __restrict__ Q, const u16* __restrict__ K,
               const u16* __restrict__ Vt, const int* __restrict__ amask,
               u16* __restrict__ Y, float* __restrict__ Opart,
               float* __restrict__ lpart) {
    __shared__ __align__(16) u16 Ks[2][64][128];   // 2 x 16 KB
    __shared__ __align__(16) u16 Vs[2][128][64];   // 2 x 16 KB (sigma k)

    const int tid  = threadIdx.x;
    const int wave = tid >> 6, lane = tid & 63;
    const int quad = lane >> 4, l16 = lane & 15;

    const int bid = blockIdx.x;
    const int s   = bid >> 8;                // 0..3 chunk slot
    const int c   = bid & 255;
    const int bkvh = c & 7;                  // XCD-affine: bid%8 -> XCD
    const int j   = c >> 3;                  // 0..31
    const int b   = bkvh >> 2, kvh = bkvh & 3;

    const int H  = ((32 + j) >> 1) + 1;      // heavy tile key-tiles (17..32)
    const int Lg = ((31 - j) >> 1) + 1;      // light tile key-tiles (1..16)
    const int m2 = max((H + 1) >> 1, (Lg + 1) >> 1);
    const int m3 = max((H + 2) / 3, Lg);
    const int nh = (m2 <= m3) ? 2 : 3;
    const int nl = 4 - nh;
    int t, kt0, kt1, pi;
    if (s < nh) {
        t = 32 + j; kt0 = (H * s) / nh; kt1 = (H * (s + 1)) / nh; pi = bid;
    } else {
        t = 31 - j;
        const int ls = s - nh;
        kt0 = (Lg * ls) / nl; kt1 = (Lg * (ls + 1)) / nl;
        pi = (nl == 1) ? -1 : bid;           // whole light tile -> direct write
    }

    const int h   = kvh * 4 + wave;          // wave = head
    const int q0  = t * 32;

    const u16* Qbase = Q  + ((size_t)b * NH_  + h)   * L_ * HD_;
    const u16* Kbase = K  + ((size_t)b * NKV_ + kvh) * L_ * HD_;
    const u16* Vbase = Vt + ((size_t)b * NKV_ + kvh) * (size_t)HD_ * L_;
    const int* mbase = amask + b * L_;

    short8 qa[2][4];
    #pragma unroll
    for (int mi = 0; mi < 2; ++mi)
        #pragma unroll
        for (int ks = 0; ks < 4; ++ks)
            qa[mi][ks] = *(const short8*)&Qbase[(size_t)(q0 + mi * 16 + l16) * HD_ + ks * 32 + quad * 8];

    floatx4 Oacc[2][8] = {};
    float lsum[2] = {0.0f, 0.0f};

    // DMA staging: per-wave 4 segments of 1KB each for K and V (buffer 0).
    const int slK = lane & 15, rKl = lane >> 4;
    const int slV = lane & 7,  rVl = lane >> 3;
    int okg[4], ovg[4];
    u16 *klds[4], *vlds[4];
    #pragma unroll
    for (int cc = 0; cc < 4; ++cc) {
        const int seg = wave * 4 + cc;
        const int rk = seg * 4 + rKl;
        okg[cc] = rk * HD_ + ((slK ^ (rk & 7)) * 8);
        klds[cc] = &Ks[0][0][0] + seg * 512;
        const int rv = seg * 8 + rVl;
        ovg[cc] = rv * L_ + ((slV ^ (rv & 7)) * 8);
        vlds[cc] = &Vs[0][0][0] + seg * 512;
    }
    const u16* kgb = Kbase + (size_t)kt0 * 64 * HD_;
    const u16* vgb = Vbase + kt0 * 64;

    // ---- prologue: stage kt0 into buffer 0 ----
    #pragma unroll
    for (int cc = 0; cc < 4; ++cc) {
        gl_lds16(kgb + okg[cc], klds[cc]);
        gl_lds16(vgb + ovg[cc], vlds[cc]);
    }
    kgb += (size_t)64 * HD_;
    vgb += 64;

    int bufoff = 0;                          // 0 or 8192 (u16 elements)
    for (int kt = kt0; kt < kt1; ++kt) {
        const int kbase = kt * 64;

        __syncthreads();   // drains this wave's buf loads (issued a full
                           // compute phase ago) + syncs all waves

        // ---- stage NEXT tile into the other buffer (hides under compute) --
        const int nb = bufoff ^ 8192;
        if (kt + 1 < kt1) {
            #pragma unroll
            for (int cc = 0; cc < 4; ++cc) {
                gl_lds16(kgb + okg[cc], klds[cc] + nb);
                gl_lds16(vgb + ovg[cc], vlds[cc] + nb);
            }
            kgb += (size_t)64 * HD_;
            vgb += 64;
        }
        const int am_l = mbase[kbase + lane];
        const bool allm = __all(am_l > 0);
        const u16* KsB = &Ks[0][0][0] + bufoff;
        const u16* VsB = &Vs[0][0][0] + bufoff;

        // ---- S^T = K Q^T (swapped): col=l16 -> q, row=quad*4+r -> key ----
        floatx4 sfr[2][4] = {};
        __builtin_amdgcn_s_setprio(1);
        #pragma unroll
        for (int ni = 0; ni < 4; ++ni) {
            #pragma unroll
            for (int ks = 0; ks < 4; ++ks) {
                short8 kf = *(const short8*)&KsB[(ni * 16 + l16) * 128 + ((ks * 4 + quad) ^ (l16 & 7)) * 8];
                sfr[0][ni] = __builtin_amdgcn_mfma_f32_16x16x32_bf16(kf, qa[0][ks], sfr[0][ni], 0, 0, 0);
                sfr[1][ni] = __builtin_amdgcn_mfma_f32_16x16x32_bf16(kf, qa[1][ks], sfr[1][ni], 0, 0, 0);
            }
        }
        __builtin_amdgcn_s_setprio(0);

        if (allm & (kbase + 63 <= q0)) {
            #pragma unroll
            for (int mi = 0; mi < 2; ++mi)
                #pragma unroll
                for (int ni = 0; ni < 4; ++ni)
                    #pragma unroll
                    for (int r = 0; r < 4; ++r) {
                        float p = exp2f(fmaf(sfr[mi][ni][r], SC2_, -8.0f));
                        lsum[mi] += p;
                        sfr[mi][ni][r] = p;
                    }
        } else {
            #pragma unroll
            for (int ni = 0; ni < 4; ++ni) {
                const int4 amv = *(const int4*)&mbase[kbase + ni * 16 + quad * 4];
                const int amr[4] = {amv.x, amv.y, amv.z, amv.w};
                #pragma unroll
                for (int mi = 0; mi < 2; ++mi) {
                    const int qrow = q0 + mi * 16 + l16;
                    #pragma unroll
                    for (int r = 0; r < 4; ++r) {
                        const int kpos = kbase + ni * 16 + quad * 4 + r;
                        const bool ok = (kpos <= qrow) & (amr[r] > 0);
                        float p = ok ? exp2f(fmaf(sfr[mi][ni][r], SC2_, -8.0f)) : 0.0f;
                        lsum[mi] += p;
                        sfr[mi][ni][r] = p;
                    }
                }
            }
        }

        short8 pf[2][2];
        #pragma unroll
        for (int mi = 0; mi < 2; ++mi)
            #pragma unroll
            for (int kc = 0; kc < 2; ++kc) {
                union { u16 w[8]; short8 s8; } u;
                #pragma unroll
                for (int r = 0; r < 4; ++r) {
                    u.w[r]     = f2bf_hw(sfr[mi][kc * 2][r]);
                    u.w[4 + r] = f2bf_hw(sfr[mi][kc * 2 + 1][r]);
                }
                pf[mi][kc] = u.s8;
            }

        __builtin_amdgcn_s_setprio(1);
        #pragma unroll
        for (int kc = 0; kc < 2; ++kc) {
            #pragma unroll
            for (int dn = 0; dn < 8; ++dn) {
                short8 vf = *(const short8*)&VsB[(dn * 16 + l16) * 64 + ((kc * 4 + quad) ^ (l16 & 7)) * 8];
                Oacc[0][dn] = __builtin_amdgcn_mfma_f32_16x16x32_bf16(pf[0][kc], vf, Oacc[0][dn], 0, 0, 0);
                Oacc[1][dn] = __builtin_amdgcn_mfma_f32_16x16x32_bf16(pf[1][kc], vf, Oacc[1][dn], 0, 0, 0);
            }
        }
        __builtin_amdgcn_s_setprio(0);

        bufoff = nb;
    }

    float lr[2];
    #pragma unroll
    for (int mi = 0; mi < 2; ++mi) {
        float v = lsum[mi];
        v += __shfl_xor(v, 16);
        v += __shfl_xor(v, 32);
        lr[mi] = v;
    }

    if (pi < 0) {
        #pragma unroll
        for (int mi = 0; mi < 2; ++mi) {
            #pragma unroll
            for (int r = 0; r < 4; ++r) {
                const float linv = 1.0f / __shfl(lr[mi], quad * 4 + r);
                const int qrow = q0 + mi * 16 + quad * 4 + r;
                u16* dst = &Y[(((size_t)b * L_ + qrow) * NH_ + h) * HD_];
                #pragma unroll
                for (int dn = 0; dn < 8; ++dn)
                    dst[dn * 16 + l16] = f2bf(Oacc[mi][dn][r] * linv);
            }
        }
    } else {
        float* od = Opart + ((size_t)pi * 4 + wave) * 32 * 128;
        float* lp = lpart + ((size_t)pi * 4 + wave) * 32;
        #pragma unroll
        for (int mi = 0; mi < 2; ++mi) {
            if (quad == 0)
                __builtin_nontemporal_store(lr[mi], &lp[mi * 16 + l16]);
            #pragma unroll
            for (int r = 0; r < 4; ++r) {
                const int qi = mi * 16 + quad * 4 + r;
                #pragma unroll
                for (int dn = 0; dn < 8; ++dn)
                    __builtin_nontemporal_store(Oacc[mi][dn][r],
                                                &od[(size_t)qi * 128 + dn * 16 + l16]);
            }
        }
    }
}

// ---------------- combine split-tile partials -> final bf16 Y ------------
__global__ __launch_bounds__(256)
void attn_combine(const float* __restrict__ Opart, const float* __restrict__ lpart,
                  u16* __restrict__ Y) {
    const int cb = blockIdx.x;
    const int c  = cb & 255, z = cb >> 8;
    const int tile = z >> 2, hw = z & 3;
    const int bkvh = c & 7, j = c >> 3;
    const int b = bkvh >> 2, kvh = bkvh & 3;
    const int h = kvh * 4 + hw;
    const int H  = ((32 + j) >> 1) + 1;
    const int Lg = ((31 - j) >> 1) + 1;
    const int m2 = max((H + 1) >> 1, (Lg + 1) >> 1);
    const int m3 = max((H + 2) / 3, Lg);
    const int nh = (m2 <= m3) ? 2 : 3;
    const int nl = 4 - nh;
    if (tile == 1 && nl == 1) return;        // direct-written by attn block
    const int s0 = tile ? nh : 0;
    const int ns = tile ? nl : nh;
    const int t  = tile ? (31 - j) : (32 + j);
    const int tid = threadIdx.x;
    const int q = tid >> 3, dg = tid & 7;    // q 0..31, d-block 0..7 (16 floats)

    float4 a0 = {0,0,0,0}, a1 = {0,0,0,0}, a2 = {0,0,0,0}, a3 = {0,0,0,0};
    float lacc = 0.0f;
    for (int i = 0; i < ns; ++i) {
        const size_t rowb = ((size_t)((s0 + i) * 256 + c) * 4 + hw) * 32 + q;
        lacc += lpart[rowb];
        const float4* op = (const float4*)(Opart + rowb * 128 + dg * 16);
        float4 v0 = op[0], v1 = op[1], v2 = op[2], v3 = op[3];
        a0.x += v0.x; a0.y += v0.y; a0.z += v0.z; a0.w += v0.w;
        a1.x += v1.x; a1.y += v1.y; a1.z += v1.z; a1.w += v1.w;
        a2.x += v2.x; a2.y += v2.y; a2.z += v2.z; a2.w += v2.w;
        a3.x += v3.x; a3.y += v3.y; a3.z += v3.z; a3.w += v3.w;
    }
    const float linv = 1.0f / lacc;
    const int qrow = t * 32 + q;
    u16* dst = &Y[(((size_t)b * L_ + qrow) * NH_ + h) * HD_ + dg * 16];

    u16 tmp[16];
    tmp[0]  = f2bf(a0.x * linv); tmp[1]  = f2bf(a0.y * linv);
    tmp[2]  = f2bf(a0.z * linv); tmp[3]  = f2bf(a0.w * linv);
    tmp[4]  = f2bf(a1.x * linv); tmp[5]  = f2bf(a1.y * linv);
    tmp[6]  = f2bf(a1.z * linv); tmp[7]  = f2bf(a1.w * linv);
    tmp[8]  = f2bf(a2.x * linv); tmp[9]  = f2bf(a2.y * linv);
    tmp[10] = f2bf(a2.z * linv); tmp[11] = f2bf(a2.w * linv);
    tmp[12] = f2bf(a3.x * linv); tmp[13] = f2bf(a3.y * linv);
    tmp[14] = f2bf(a3.z * linv); tmp[15] = f2bf(a3.w * linv);
    *(uint4*)(dst)     = *(const uint4*)(&tmp[0]);
    *(uint4*)(dst + 8) = *(const uint4*)(&tmp[8]);
}

// ---------------- launch ----------------
extern "C" void kernel_launch(void* const* d_in, const int* in_sizes, int n_in,
                              void* d_out, int out_size, void* d_ws, size_t ws_size,
                              hipStream_t stream) {
    const float* x  = (const float*)d_in[0];
    const float* Wq = (const float*)d_in[1];
    const float* Wc = (const float*)d_in[2];
    const float* Wk = (const float*)d_in[3];
    const float* Wv = (const float*)d_in[4];
    const float* Wo = (const float*)d_in[5];
    const int* amask = (const int*)d_in[6];
    float* out = (float*)d_out;

    char* p = (char*)d_ws;
    auto alloc = [&](size_t elems) {
        u16* r = (u16*)p;
        p += ((elems * 2 + 255) / 256) * 256;
        return r;
    };
    // --- alive through attention ---
    u16* WoT  = alloc((size_t)2048 * 2048);
    u16* qbuf = alloc((size_t)4096 * 2048);   // q proj; reused as Y
    u16* Qr   = alloc((size_t)4096 * 2048);
    u16* Kr   = alloc((size_t)4096 * 512);
    u16* Vt   = alloc((size_t)4096 * 512);    // [B, NKV, HD, sigma(L)]
    // --- dead once attention starts (Opart overlays this region) ---
    char* pdead = p;
    u16* WqT  = alloc((size_t)2048 * 2048);   // [WqT|WckvT] must be adjacent
    u16* WckvT= alloc((size_t)1024 * 2048);   // fused (Wc@Wk)^T ; (Wc@Wv)^T
    u16* WkT  = alloc((size_t)512 * 512);     // [WkT|WvT] adjacent (stacked A)
    u16* WvT  = alloc((size_t)512 * 512);
    u16* Wcb  = alloc((size_t)2048 * 512);    // Wc as bf16, non-transposed
    u16* Xb   = alloc((size_t)4096 * 2048);
    u16* kvbuf= alloc((size_t)4096 * 1024);   // [k(512) | v(512)] per token
    float* Opart = (float*)pdead;
    float* lpart = (float*)(pdead + (size_t)1024 * 4 * 32 * 128 * 4);

    // converts
    cvt_kernel<<<8388608 / 4 / 256, 256, 0, stream>>>(x, Xb, 8388608 / 4);
    cvt_kernel<<<(2048 * 512 / 4) / 256, 256, 0, stream>>>(Wc, Wcb, 2048 * 512 / 4);
    cvt_transpose2_kernel<<<dim3(64, 64, 2), 256, 0, stream>>>(Wq, WqT, Wo, WoT, 2048, 2048);
    cvt_transpose2_kernel<<<dim3(16, 16, 2), 256, 0, stream>>>(Wk, WkT, Wv, WvT, 512, 512);

    // weight fusion: WckvT[1024x2048] = [WkT;WvT] @ Wcb^T-form (2.1 GF)
    gemm_bt<1><<<dim3(16, 8), 256, 0, stream>>>(WkT, Wcb, WckvT, 1024, 2048, 512);

    // mega projection: [q|k|v] = Xb @ [WqT|WckvT]^T, N=3072, 768 blocks
    gemm_bt_split<<<dim3(24, 32), 256, 0, stream>>>(Xb, WqT, qbuf, kvbuf,
                                                    4096, 3072, 2048, 2048, 2048, 1024);

    // rope + permute to head-major; V -> [b,kvh,d,sigma(l)]
    rope_perm<<<(2 * 16 * 2048 * 64) / 256, 256, 0, stream>>>(qbuf, Qr, 16, 4, 2048);
    rope_perm<<<(2 * 4 * 2048 * 64) / 256, 256, 0, stream>>>(kvbuf, Kr, 4, 2, 1024);
    transpose_v_kernel<<<dim3(64, 4, 8), 256, 0, stream>>>(kvbuf, Vt);

    // attention partials + combine (Y into qbuf, dead after rope)
    attn_mfma<<<dim3(1024), 256, 0, stream>>>(Qr, Kr, Vt, amask, qbuf, Opart, lpart);
    attn_combine<<<dim3(2048), 256, 0, stream>>>(Opart, lpart, qbuf);

    // output projection (fp32 out)
    gemm_bt<0><<<dim3(16, 32), 256, 0, stream>>>(qbuf, WoT, out, 4096, 2048, 2048);
}

// Round 13
// 324.595 us; speedup vs baseline: 1.8708x; 1.0449x over previous
//
#include <hip/hip_runtime.h>
#include <hip/hip_bf16.h>
#include <cstdint>
#include <cstddef>

// Problem constants
#define B_    2
#define L_    2048
#define HID_  2048
#define NH_   16
#define NKV_  4
#define HD_   128
#define LAT_  512
#define SCALE_ 0.08838834764831845f   // 1/sqrt(128)
#define SC2_   0.1275174365f          // SCALE * log2(e)

typedef unsigned short u16;
typedef unsigned int   u32;
typedef __attribute__((ext_vector_type(8))) short   short8;
typedef __attribute__((ext_vector_type(4))) float   floatx4;

typedef __attribute__((address_space(1))) const u32 gas_u32;
typedef __attribute__((address_space(3))) u32       las_u32;

__device__ __forceinline__ void gl_lds16(const u16* g, u16* l) {
    // async global->LDS, 16B/lane; LDS dest = wave-uniform base + lane*16
    __builtin_amdgcn_global_load_lds((gas_u32*)g, (las_u32*)l, 16, 0, 0);
}

__device__ __forceinline__ float bf2f(u16 u) {
    union { u32 i; float f; } v; v.i = ((u32)u) << 16; return v.f;
}
__device__ __forceinline__ u16 f2bf(float f) {
    union { float f; u32 u; } v; v.f = f;
    u32 u = v.u;
    u32 r = (u + 0x7fffu + ((u >> 16) & 1u)) >> 16;   // RNE
    return (u16)r;
}
// HW bf16 cast (compiler fuses pairs into v_cvt_pk_bf16_f32, RNE)
__device__ __forceinline__ u16 f2bf_hw(float f) {
    union { __hip_bfloat16 h; u16 u; } c;
    c.h = __float2bfloat16(f);
    return c.u;
}

// ---------------- fp32 -> bf16, TWO tensors per launch (x4 vector) -------
__global__ void cvt2_kernel(const float* __restrict__ in0, u16* __restrict__ out0, int n40,
                            const float* __restrict__ in1, u16* __restrict__ out1, int n41) {
    int i = blockIdx.x * 256 + threadIdx.x;
    const float* in; u16* out; int k;
    if (i < n40) { in = in0; out = out0; k = i; }
    else if (i < n40 + n41) { in = in1; out = out1; k = i - n40; }
    else return;
    float4 v = ((const float4*)in)[k];
    union { u16 w[4]; uint2 v; } o;
    o.w[0] = f2bf(v.x); o.w[1] = f2bf(v.y);
    o.w[2] = f2bf(v.z); o.w[3] = f2bf(v.w);
    ((uint2*)out)[k] = o.v;
}

// ---------------- fp32 [R][C] -> bf16 [C][R], two tensors per launch ------
__global__ void cvt_transpose2_kernel(const float* __restrict__ in0, u16* __restrict__ out0,
                                      const float* __restrict__ in1, u16* __restrict__ out1,
                                      int R, int C) {
    __shared__ u16 tile[32][33];
    const float* in = blockIdx.z ? in1 : in0;
    u16* out = blockIdx.z ? out1 : out0;
    int c0 = blockIdx.x * 32, r0 = blockIdx.y * 32;
    int tx = threadIdx.x & 31, ty = threadIdx.x >> 5;   // ty in 0..7
    for (int i = ty; i < 32; i += 8)
        tile[tx][i] = f2bf(in[(size_t)(r0 + i) * C + c0 + tx]);
    __syncthreads();
    for (int i = ty; i < 32; i += 8)
        out[(size_t)(c0 + i) * R + r0 + tx] = tile[i][tx];
}

// ---------------- fused q/k RoPE + head-major permute, + V transpose -----
// blocks [0, NRQ)            : rope on qbuf -> Qr   (nh=16, rs=2048)
// blocks [NRQ, NRQ+NRK)      : rope on kvbuf k-half -> Kr (nh=4, rs=1024)
// blocks [NRQ+NRK, +2048)    : kvbuf v-half -> Vt [b,kvh,d,sigma(l)]
// sigma matches the SWAPPED-QK in-register P layout: for key k6 with
// ni=k6>>4, qd=(k6>>2)&3, r=k6&3: p = ((ni>>1)<<5)|(qd<<3)|((ni&1)<<2)|r.
#define NRQ_ 16384
#define NRK_ 4096
__global__ void prep_qkv(const u16* __restrict__ qbuf, u16* __restrict__ Qr,
                         const u16* __restrict__ kvbuf, u16* __restrict__ Kr,
                         u16* __restrict__ Vt) {
    __shared__ u16 tvt[32][33];
    const int bb = blockIdx.x;
    if (bb < NRQ_ + NRK_) {
        const bool isq = bb < NRQ_;
        const u16* in = isq ? qbuf : kvbuf;
        u16* out = isq ? Qr : Kr;
        const int nh = isq ? 16 : 4, nhbits = isq ? 4 : 2, rs = isq ? 2048 : 1024;
        int idx = (isq ? bb : bb - NRQ_) * 256 + threadIdx.x;
        int d = idx & 63;
        int l = (idx >> 6) & (L_ - 1);
        int h = (idx >> 17) & (nh - 1);
        int b = idx >> (17 + nhbits);
        const u16* src = &in[(size_t)(b * L_ + l) * rs + h * HD_];
        u16* dst = &out[(((size_t)b * nh + h) * L_ + l) * HD_];
        float t1 = bf2f(src[d]), t2 = bf2f(src[d + 64]);
        float inv = expf(-(float)d * 0.14391156831212787f);  // ln(10000)/64
        float fr = (float)l * inv;
        float c = cosf(fr), sn = sinf(fr);
        dst[d]      = f2bf(t1 * c - t2 * sn);
        dst[d + 64] = f2bf(t2 * c + t1 * sn);
    } else {
        const int i = bb - NRQ_ - NRK_;          // 0..2047
        const int lt = i & 63, dt = (i >> 6) & 3, bh = i >> 8;
        const int b = bh >> 2, kvh = bh & 3;
        const int tx = threadIdx.x & 31, ty = threadIdx.x >> 5;
        for (int k = ty; k < 32; k += 8)
            tvt[k][tx] = kvbuf[(size_t)(b * L_ + lt * 32 + k) * 1024 + 512 + kvh * HD_ + dt * 32 + tx];
        __syncthreads();
        const int lcol = lt * 32 + tx;
        const int k6 = lcol & 63;
        const int ni = k6 >> 4, qd = (k6 >> 2) & 3, r = k6 & 3;
        const int p = ((ni >> 1) << 5) | (qd << 3) | ((ni & 1) << 2) | r;
        const int csig = (lcol & ~63) | p;
        for (int k = ty; k < 32; k += 8)
            Vt[((size_t)bh * HD_ + dt * 32 + k) * L_ + csig] = tvt[tx][k];
    }
}

// ---------------- bf16 GEMM: C[M,N] = A[M,K] * BT[N,K]^T ----------------
// R11-proven single-buffer form: BK=64, XOR-swizzled LDS (swizzle in the
// DMA SOURCE address; linear dest per rule 21), kk-split inner loop (32
// live fragment regs). 32 KB LDS -> 3 blocks/CU at grid 768 all-resident.
// R12 lesson: double-buffering (64 KB) drops residency 3->2 and REGRESSES.
template<int OUT_BF16>
__global__ __launch_bounds__(256)
void gemm_bt(const u16* __restrict__ A, const u16* __restrict__ BT,
             void* __restrict__ C, int M, int N, int K) {
    __shared__ __align__(16) u16 As[128][64];
    __shared__ __align__(16) u16 Bs[128][64];
    const int tid  = threadIdx.x;
    const int m0   = blockIdx.y * 128, n0 = blockIdx.x * 128;
    const int wave = tid >> 6, lane = tid & 63;
    const int wm   = (wave >> 1) * 64, wn = (wave & 1) * 64;
    const int quad = lane >> 4, l16 = lane & 15;

    const int r8 = lane >> 3, srcc = ((lane & 7) ^ r8) * 8;
    const int row0 = wave * 32 + r8;         // + cc*8
    const u16* aBase = A  + (size_t)(m0 + row0) * K + srcc;
    const u16* bBase = BT + (size_t)(n0 + row0) * K + srcc;
    u16* laBase = &As[0][0] + wave * 2048;   // + cc*512
    u16* lbBase = &Bs[0][0] + wave * 2048;

    floatx4 acc[4][4] = {};

    for (int k0 = 0; k0 < K; k0 += 64) {
        #pragma unroll
        for (int cc = 0; cc < 4; ++cc) {
            gl_lds16(aBase + (size_t)cc * 8 * K + k0, laBase + cc * 512);
            gl_lds16(bBase + (size_t)cc * 8 * K + k0, lbBase + cc * 512);
        }
        __syncthreads();

        #pragma unroll
        for (int kk = 0; kk < 2; kk++) {
            short8 af[4], bfr[4];
            const int co = ((kk * 4 + quad) ^ (l16 & 7)) * 8;
            #pragma unroll
            for (int i = 0; i < 4; i++) {
                af[i]  = *(const short8*)&As[wm + i * 16 + l16][co];
                bfr[i] = *(const short8*)&Bs[wn + i * 16 + l16][co];
            }
            #pragma unroll
            for (int mi = 0; mi < 4; mi++)
                #pragma unroll
                for (int ni = 0; ni < 4; ni++)
                    acc[mi][ni] = __builtin_amdgcn_mfma_f32_16x16x32_bf16(
                        af[mi], bfr[ni], acc[mi][ni], 0, 0, 0);
        }
        __syncthreads();
    }

    #pragma unroll
    for (int mi = 0; mi < 4; mi++) {
        #pragma unroll
        for (int ni = 0; ni < 4; ni++) {
            #pragma unroll
            for (int r = 0; r < 4; r++) {
                int row = m0 + wm + mi * 16 + quad * 4 + r;
                int col = n0 + wn + ni * 16 + l16;
                float v = acc[mi][ni][r];
                if (OUT_BF16) ((u16*)C)[(size_t)row * N + col] = f2bf(v);
                else          ((float*)C)[(size_t)row * N + col] = v;
            }
        }
    }
}

// ---- same GEMM, bf16 out, fused [B0|B1] N-stack (Nsplit % 128 == 0) ----
__global__ __launch_bounds__(256)
void gemm_bt_split(const u16* __restrict__ A, const u16* __restrict__ BT,
                   u16* __restrict__ C0, u16* __restrict__ C1,
                   int M, int N, int K, int Nsplit, int N0, int N1) {
    __shared__ __align__(16) u16 As[128][64];
    __shared__ __align__(16) u16 Bs[128][64];
    const int tid  = threadIdx.x;
    const int m0   = blockIdx.y * 128, n0 = blockIdx.x * 128;
    const int wave = tid >> 6, lane = tid & 63;
    const int wm   = (wave >> 1) * 64, wn = (wave & 1) * 64;
    const int quad = lane >> 4, l16 = lane & 15;

    const int r8 = lane >> 3, srcc = ((lane & 7) ^ r8) * 8;
    const int row0 = wave * 32 + r8;
    const u16* aBase = A  + (size_t)(m0 + row0) * K + srcc;
    const u16* bBase = BT + (size_t)(n0 + row0) * K + srcc;
    u16* laBase = &As[0][0] + wave * 2048;
    u16* lbBase = &Bs[0][0] + wave * 2048;

    floatx4 acc[4][4] = {};

    for (int k0 = 0; k0 < K; k0 += 64) {
        #pragma unroll
        for (int cc = 0; cc < 4; ++cc) {
            gl_lds16(aBase + (size_t)cc * 8 * K + k0, laBase + cc * 512);
            gl_lds16(bBase + (size_t)cc * 8 * K + k0, lbBase + cc * 512);
        }
        __syncthreads();

        #pragma unroll
        for (int kk = 0; kk < 2; kk++) {
            short8 af[4], bfr[4];
            const int co = ((kk * 4 + quad) ^ (l16 & 7)) * 8;
            #pragma unroll
            for (int i = 0; i < 4; i++) {
                af[i]  = *(const short8*)&As[wm + i * 16 + l16][co];
                bfr[i] = *(const short8*)&Bs[wn + i * 16 + l16][co];
            }
            #pragma unroll
            for (int mi = 0; mi < 4; mi++)
                #pragma unroll
                for (int ni = 0; ni < 4; ni++)
                    acc[mi][ni] = __builtin_amdgcn_mfma_f32_16x16x32_bf16(
                        af[mi], bfr[ni], acc[mi][ni], 0, 0, 0);
        }
        __syncthreads();
    }

    const int side = (n0 >= Nsplit);
    u16* Cw = side ? C1 : C0;
    const int nw = side ? N1 : N0;
    const int cbase = side ? Nsplit : 0;

    #pragma unroll
    for (int mi = 0; mi < 4; mi++) {
        #pragma unroll
        for (int ni = 0; ni < 4; ni++) {
            #pragma unroll
            for (int r = 0; r < 4; r++) {
                int row = m0 + wm + mi * 16 + quad * 4 + r;
                int col = n0 + wn + ni * 16 + l16 - cbase;
                Cw[(size_t)row * nw + col] = f2bf(acc[mi][ni][r]);
            }
        }
    }
}

// ---------------- MFMA flash attention (GQA head-merged waves) -----------
// Block = 4 waves = 4 HEADS of one kv-group, same 32 q-rows.
// R13 split: grid 512 = EXACTLY 2 blocks/CU (64 KB dbuf LDS), all resident,
// zero backfill. Per c=(bkvh,j): 33 virtual k-tile iters, H=heavy (17..32),
// Lg=33-H=light.
//   s=0: heavy kt [0,17)            -> partial slot c*2     (17 iters)
//   s=1: heavy kt [17,H) -> slot c*2+1 (may be empty), then the COMPLETE
//        light tile -> DIRECT bf16 write                    (16 iters)
// Crossing block flushes heavy partial, reloads Q frags, re-primes dbuf.
// Combine only needed for heavy tiles (<=2 partials).
// Retained: LDS dbuf single barrier/iter, swapped QK^T (P in-register),
// DMA staging w/ pre-swizzled source, sigma-ordered V, mask fast-path.
__global__ __launch_bounds__(256)
void attn_mfma(const u16* __restrict__ Q, const u16* __restrict__ K,
               const u16* __restrict__ Vt, const int* __restrict__ amask,
               u16* __restrict__ Y, float* __restrict__ Opart,
               float* __restrict__ lpart) {
    __shared__ __align__(16) u16 Ks[2][64][128];   // 2 x 16 KB
    __shared__ __align__(16) u16 Vs[2][128][64];   // 2 x 16 KB (sigma k)

    const int tid  = threadIdx.x;
    const int wave = tid >> 6, lane = tid & 63;
    const int quad = lane >> 4, l16 = lane & 15;

    const int bid = blockIdx.x;
    const int s   = bid >> 8;                // 0 or 1
    const int c   = bid & 255;
    const int bkvh = c & 7;                  // XCD-affine: bid%8 -> XCD
    const int j   = c >> 3;                  // 0..31
    const int b   = bkvh >> 2, kvh = bkvh & 3;

    const int H  = ((32 + j) >> 1) + 1;      // heavy k-tiles (17..32)
    const int Lg = 33 - H;                   // light k-tiles (1..16)
    const int h  = kvh * 4 + wave;           // wave = head

    const u16* Qbase = Q  + ((size_t)b * NH_  + h)   * L_ * HD_;
    const u16* Kbase = K  + ((size_t)b * NKV_ + kvh) * L_ * HD_;
    const u16* Vbase = Vt + ((size_t)b * NKV_ + kvh) * (size_t)HD_ * L_;
    const int* mbase = amask + b * L_;

    // DMA staging: per-wave 4 segments of 1KB each for K and V (buffer 0).
    const int slK = lane & 15, rKl = lane >> 4;
    const int slV = lane & 7,  rVl = lane >> 3;
    int okg[4], ovg[4];
    u16 *klds[4], *vlds[4];
    #pragma unroll
    for (int cc = 0; cc < 4; ++cc) {
        const int seg = wave * 4 + cc;
        const int rk = seg * 4 + rKl;
        okg[cc] = rk * HD_ + ((slK ^ (rk & 7)) * 8);
        klds[cc] = &Ks[0][0][0] + seg * 512;
        const int rv = seg * 8 + rVl;
        ovg[cc] = rv * L_ + ((slV ^ (rv & 7)) * 8);
        vlds[cc] = &Vs[0][0][0] + seg * 512;
    }

    const int npass = (s == 0) ? 1 : 2;
    for (int pass = 0; pass < npass; ++pass) {
        int t, kt0, kt1, slot;
        if (s == 0)           { t = 32 + j; kt0 = 0;  kt1 = 17; slot = c * 2; }
        else if (pass == 0)   { t = 32 + j; kt0 = 17; kt1 = H;  slot = c * 2 + 1; }
        else                  { t = 31 - j; kt0 = 0;  kt1 = Lg; slot = -1; }
        if (kt1 <= kt0) continue;
        const int q0 = t * 32;

        // Q fragments for this tile
        short8 qa[2][4];
        #pragma unroll
        for (int mi = 0; mi < 2; ++mi)
            #pragma unroll
            for (int ks = 0; ks < 4; ++ks)
                qa[mi][ks] = *(const short8*)&Qbase[(size_t)(q0 + mi * 16 + l16) * HD_ + ks * 32 + quad * 8];

        floatx4 Oacc[2][8] = {};
        float lsum[2] = {0.0f, 0.0f};

        const u16* kgb = Kbase + (size_t)kt0 * 64 * HD_;
        const u16* vgb = Vbase + kt0 * 64;

        __syncthreads();   // all waves done with LDS from previous pass
        // ---- prologue: stage kt0 into buffer 0 ----
        #pragma unroll
        for (int cc = 0; cc < 4; ++cc) {
            gl_lds16(kgb + okg[cc], klds[cc]);
            gl_lds16(vgb + ovg[cc], vlds[cc]);
        }
        kgb += (size_t)64 * HD_;
        vgb += 64;

        int bufoff = 0;                      // 0 or 8192 (u16 elements)
        for (int kt = kt0; kt < kt1; ++kt) {
            const int kbase = kt * 64;

            __syncthreads();   // drains this wave's buf loads (issued a
                               // full compute phase ago) + syncs all waves

            const int nb = bufoff ^ 8192;
            if (kt + 1 < kt1) {
                #pragma unroll
                for (int cc = 0; cc < 4; ++cc) {
                    gl_lds16(kgb + okg[cc], klds[cc] + nb);
                    gl_lds16(vgb + ovg[cc], vlds[cc] + nb);
                }
                kgb += (size_t)64 * HD_;
                vgb += 64;
            }
            const int am_l = mbase[kbase + lane];
            const bool allm = __all(am_l > 0);
            const u16* KsB = &Ks[0][0][0] + bufoff;
            const u16* VsB = &Vs[0][0][0] + bufoff;

            // ---- S^T = K Q^T (swapped): col=l16 -> q, (quad,r) -> key ----
            floatx4 sfr[2][4] = {};
            __builtin_amdgcn_s_setprio(1);
            #pragma unroll
            for (int ni = 0; ni < 4; ++ni) {
                #pragma unroll
                for (int ks = 0; ks < 4; ++ks) {
                    short8 kf = *(const short8*)&KsB[(ni * 16 + l16) * 128 + ((ks * 4 + quad) ^ (l16 & 7)) * 8];
                    sfr[0][ni] = __builtin_amdgcn_mfma_f32_16x16x32_bf16(kf, qa[0][ks], sfr[0][ni], 0, 0, 0);
                    sfr[1][ni] = __builtin_amdgcn_mfma_f32_16x16x32_bf16(kf, qa[1][ks], sfr[1][ni], 0, 0, 0);
                }
            }
            __builtin_amdgcn_s_setprio(0);

            if (allm & (kbase + 63 <= q0)) {
                #pragma unroll
                for (int mi = 0; mi < 2; ++mi)
                    #pragma unroll
                    for (int ni = 0; ni < 4; ++ni)
                        #pragma unroll
                        for (int r = 0; r < 4; ++r) {
                            float p = exp2f(fmaf(sfr[mi][ni][r], SC2_, -8.0f));
                            lsum[mi] += p;
                            sfr[mi][ni][r] = p;
                        }
            } else {
                #pragma unroll
                for (int ni = 0; ni < 4; ++ni) {
                    const int4 amv = *(const int4*)&mbase[kbase + ni * 16 + quad * 4];
                    const int amr[4] = {amv.x, amv.y, amv.z, amv.w};
                    #pragma unroll
                    for (int mi = 0; mi < 2; ++mi) {
                        const int qrow = q0 + mi * 16 + l16;
                        #pragma unroll
                        for (int r = 0; r < 4; ++r) {
                            const int kpos = kbase + ni * 16 + quad * 4 + r;
                            const bool ok = (kpos <= qrow) & (amr[r] > 0);
                            float p = ok ? exp2f(fmaf(sfr[mi][ni][r], SC2_, -8.0f)) : 0.0f;
                            lsum[mi] += p;
                            sfr[mi][ni][r] = p;
                        }
                    }
                }
            }

            short8 pf[2][2];
            #pragma unroll
            for (int mi = 0; mi < 2; ++mi)
                #pragma unroll
                for (int kc = 0; kc < 2; ++kc) {
                    union { u16 w[8]; short8 s8; } u;
                    #pragma unroll
                    for (int r = 0; r < 4; ++r) {
                        u.w[r]     = f2bf_hw(sfr[mi][kc * 2][r]);
                        u.w[4 + r] = f2bf_hw(sfr[mi][kc * 2 + 1][r]);
                    }
                    pf[mi][kc] = u.s8;
                }

            __builtin_amdgcn_s_setprio(1);
            #pragma unroll
            for (int kc = 0; kc < 2; ++kc) {
                #pragma unroll
                for (int dn = 0; dn < 8; ++dn) {
                    short8 vf = *(const short8*)&VsB[(dn * 16 + l16) * 64 + ((kc * 4 + quad) ^ (l16 & 7)) * 8];
                    Oacc[0][dn] = __builtin_amdgcn_mfma_f32_16x16x32_bf16(pf[0][kc], vf, Oacc[0][dn], 0, 0, 0);
                    Oacc[1][dn] = __builtin_amdgcn_mfma_f32_16x16x32_bf16(pf[1][kc], vf, Oacc[1][dn], 0, 0, 0);
                }
            }
            __builtin_amdgcn_s_setprio(0);

            bufoff = nb;
        }

        // ---- per-pass epilogue ----
        float lr[2];
        #pragma unroll
        for (int mi = 0; mi < 2; ++mi) {
            float v = lsum[mi];
            v += __shfl_xor(v, 16);
            v += __shfl_xor(v, 32);
            lr[mi] = v;
        }

        if (slot < 0) {
            // complete light tile: direct bf16 write
            #pragma unroll
            for (int mi = 0; mi < 2; ++mi) {
                #pragma unroll
                for (int r = 0; r < 4; ++r) {
                    const float linv = 1.0f / __shfl(lr[mi], quad * 4 + r);
                    const int qrow = q0 + mi * 16 + quad * 4 + r;
                    u16* dst = &Y[(((size_t)b * L_ + qrow) * NH_ + h) * HD_];
                    #pragma unroll
                    for (int dn = 0; dn < 8; ++dn)
                        dst[dn * 16 + l16] = f2bf(Oacc[mi][dn][r] * linv);
                }
            }
        } else {
            float* od = Opart + ((size_t)slot * 4 + wave) * 32 * 128;
            float* lp = lpart + ((size_t)slot * 4 + wave) * 32;
            #pragma unroll
            for (int mi = 0; mi < 2; ++mi) {
                if (quad == 0)
                    __builtin_nontemporal_store(lr[mi], &lp[mi * 16 + l16]);
                #pragma unroll
                for (int r = 0; r < 4; ++r) {
                    const int qi = mi * 16 + quad * 4 + r;
                    #pragma unroll
                    for (int dn = 0; dn < 8; ++dn)
                        __builtin_nontemporal_store(Oacc[mi][dn][r],
                                                    &od[(size_t)qi * 128 + dn * 16 + l16]);
                }
            }
        }
    }
}

// ---------------- combine heavy-tile partials -> final bf16 Y ------------
// Grid 1024 = 4 hw x 256 c (cb&7 == c&7, XCD-affine). Heavy tile of c has
// partials in slot c*2 (always) and c*2+1 (iff H>17).
__global__ __launch_bounds__(256)
void attn_combine(const float* __restrict__ Opart, const float* __restrict__ lpart,
                  u16* __restrict__ Y) {
    const int cb = blockIdx.x;
    const int c  = cb & 255, hw = cb >> 8;
    const int bkvh = c & 7, j = c >> 3;
    const int b = bkvh >> 2, kvh = bkvh & 3;
    const int h = kvh * 4 + hw;
    const int H = ((32 + j) >> 1) + 1;
    const int ns = (H > 17) ? 2 : 1;
    const int t = 32 + j;
    const int tid = threadIdx.x;
    const int q = tid >> 3, dg = tid & 7;    // q 0..31, d-block 0..7 (16 floats)

    float4 a0 = {0,0,0,0}, a1 = {0,0,0,0}, a2 = {0,0,0,0}, a3 = {0,0,0,0};
    float lacc = 0.0f;
    for (int i = 0; i < ns; ++i) {
        const size_t rowb = ((size_t)(c * 2 + i) * 4 + hw) * 32 + q;
        lacc += lpart[rowb];
        const float4* op = (const float4*)(Opart + rowb * 128 + dg * 16);
        float4 v0 = op[0], v1 = op[1], v2 = op[2], v3 = op[3];
        a0.x += v0.x; a0.y += v0.y; a0.z += v0.z; a0.w += v0.w;
        a1.x += v1.x; a1.y += v1.y; a1.z += v1.z; a1.w += v1.w;
        a2.x += v2.x; a2.y += v2.y; a2.z += v2.z; a2.w += v2.w;
        a3.x += v3.x; a3.y += v3.y; a3.z += v3.z; a3.w += v3.w;
    }
    const float linv = 1.0f / lacc;
    const int qrow = t * 32 + q;
    u16* dst = &Y[(((size_t)b * L_ + qrow) * NH_ + h) * HD_ + dg * 16];

    u16 tmp[16];
    tmp[0]  = f2bf(a0.x * linv); tmp[1]  = f2bf(a0.y * linv);
    tmp[2]  = f2bf(a0.z * linv); tmp[3]  = f2bf(a0.w * linv);
    tmp[4]  = f2bf(a1.x * linv); tmp[5]  = f2bf(a1.y * linv);
    tmp[6]  = f2bf(a1.z * linv); tmp[7]  = f2bf(a1.w * linv);
    tmp[8]  = f2bf(a2.x * linv); tmp[9]  = f2bf(a2.y * linv);
    tmp[10] = f2bf(a2.z * linv); tmp[11] = f2bf(a2.w * linv);
    tmp[12] = f2bf(a3.x * linv); tmp[13] = f2bf(a3.y * linv);
    tmp[14] = f2bf(a3.z * linv); tmp[15] = f2bf(a3.w * linv);
    *(uint4*)(dst)     = *(const uint4*)(&tmp[0]);
    *(uint4*)(dst + 8) = *(const uint4*)(&tmp[8]);
}

// ---------------- launch ----------------
extern "C" void kernel_launch(void* const* d_in, const int* in_sizes, int n_in,
                              void* d_out, int out_size, void* d_ws, size_t ws_size,
                              hipStream_t stream) {
    const float* x  = (const float*)d_in[0];
    const float* Wq = (const float*)d_in[1];
    const float* Wc = (const float*)d_in[2];
    const float* Wk = (const float*)d_in[3];
    const float* Wv = (const float*)d_in[4];
    const float* Wo = (const float*)d_in[5];
    const int* amask = (const int*)d_in[6];
    float* out = (float*)d_out;

    char* p = (char*)d_ws;
    auto alloc = [&](size_t elems) {
        u16* r = (u16*)p;
        p += ((elems * 2 + 255) / 256) * 256;
        return r;
    };
    // --- alive through attention ---
    u16* WoT  = alloc((size_t)2048 * 2048);
    u16* qbuf = alloc((size_t)4096 * 2048);   // q proj; reused as Y
    u16* Qr   = alloc((size_t)4096 * 2048);
    u16* Kr   = alloc((size_t)4096 * 512);
    u16* Vt   = alloc((size_t)4096 * 512);    // [B, NKV, HD, sigma(L)]
    // --- dead once attention starts (Opart overlays this region) ---
    char* pdead = p;
    u16* WqT  = alloc((size_t)2048 * 2048);   // [WqT|WckvT] must be adjacent
    u16* WckvT= alloc((size_t)1024 * 2048);   // fused (Wc@Wk)^T ; (Wc@Wv)^T
    u16* WkT  = alloc((size_t)512 * 512);     // [WkT|WvT] adjacent (stacked A)
    u16* WvT  = alloc((size_t)512 * 512);
    u16* Wcb  = alloc((size_t)2048 * 512);    // Wc as bf16, non-transposed
    u16* Xb   = alloc((size_t)4096 * 2048);
    u16* kvbuf= alloc((size_t)4096 * 1024);   // [k(512) | v(512)] per token
    // heavy-tile partials: 512 slots x 4 heads x 32 q x 128 d fp32 (~33 MB)
    float* Opart = (float*)pdead;
    float* lpart = (float*)(pdead + (size_t)512 * 4 * 32 * 128 * 4);

    // converts (x + Wc fused into one launch)
    cvt2_kernel<<<(2097152 + 262144) / 256, 256, 0, stream>>>(
        x, Xb, 2097152, Wc, Wcb, 262144);
    cvt_transpose2_kernel<<<dim3(64, 64, 2), 256, 0, stream>>>(Wq, WqT, Wo, WoT, 2048, 2048);
    cvt_transpose2_kernel<<<dim3(16, 16, 2), 256, 0, stream>>>(Wk, WkT, Wv, WvT, 512, 512);

    // weight fusion: WckvT[1024x2048] = [WkT;WvT] @ Wcb^T-form (2.1 GF)
    gemm_bt<1><<<dim3(16, 8), 256, 0, stream>>>(WkT, Wcb, WckvT, 1024, 2048, 512);

    // mega projection: [q|k|v] = Xb @ [WqT|WckvT]^T, N=3072, 768 blocks
    gemm_bt_split<<<dim3(24, 32), 256, 0, stream>>>(Xb, WqT, qbuf, kvbuf,
                                                    4096, 3072, 2048, 2048, 2048, 1024);

    // fused rope(q) + rope(k) + V transpose (one launch)
    prep_qkv<<<NRQ_ + NRK_ + 2048, 256, 0, stream>>>(qbuf, Qr, kvbuf, Kr, Vt);

    // attention (grid 512 = 2 blocks/CU all-resident) + heavy combine
    attn_mfma<<<dim3(512), 256, 0, stream>>>(Qr, Kr, Vt, amask, qbuf, Opart, lpart);
    attn_combine<<<dim3(1024), 256, 0, stream>>>(Opart, lpart, qbuf);

    // output projection (fp32 out)
    gemm_bt<0><<<dim3(16, 32), 256, 0, stream>>>(qbuf, WoT, out, 4096, 2048, 2048);
}